// Round 1
// baseline (1620.063 us; speedup 1.0000x reference)
//
#include <hip/hip_runtime.h>

typedef short short8_t __attribute__((ext_vector_type(8)));
typedef float f32x4 __attribute__((ext_vector_type(4)));
typedef unsigned int uint32;
typedef unsigned short ushort16;

#define EPS_BN 1e-5f

__device__ __forceinline__ ushort16 f2bf(float f){
  uint32 u = __float_as_uint(f);
  u += 0x7fffu + ((u >> 16) & 1u);
  return (ushort16)(u >> 16);
}
__device__ __forceinline__ float bflo(uint32 u){ return __uint_as_float(u << 16); }
__device__ __forceinline__ float bfhi(uint32 u){ return __uint_as_float(u & 0xffff0000u); }

// ---------------- conversion kernels ----------------
struct WConv {
  const float* s[17];
  ushort16* d[17];
  int n[17];
};

__global__ __launch_bounds__(256) void conv_w_k(WConv a){
  int m = blockIdx.y;
  int i = (blockIdx.x * 256 + threadIdx.x) * 4;
  if (i >= a.n[m]) return;
  float4 v = *(const float4*)(a.s[m] + i);
  uint2 p;
  p.x = (uint32)f2bf(v.x) | ((uint32)f2bf(v.y) << 16);
  p.y = (uint32)f2bf(v.z) | ((uint32)f2bf(v.w) << 16);
  *(uint2*)(a.d[m] + i) = p;
}

__global__ __launch_bounds__(256) void conv2_k(const float* __restrict__ a, const float* __restrict__ b,
                                               ushort16* __restrict__ da, ushort16* __restrict__ db, int n){
  const float* s = blockIdx.y ? b : a;
  ushort16* d = blockIdx.y ? db : da;
  int i = (blockIdx.x * 256 + threadIdx.x) * 4;
  if (i >= n) return;
  float4 v = *(const float4*)(s + i);
  uint2 p;
  p.x = (uint32)f2bf(v.x) | ((uint32)f2bf(v.y) << 16);
  p.y = (uint32)f2bf(v.z) | ((uint32)f2bf(v.w) << 16);
  *(uint2*)(d + i) = p;
}

// ---------------- CSR build ----------------
__global__ void hist_k(const int* __restrict__ dst, int* __restrict__ cnt, int E){
  int i = blockIdx.x * blockDim.x + threadIdx.x;
  int stride = gridDim.x * blockDim.x;
  for (; i < E; i += stride) atomicAdd(&cnt[dst[i]], 1);
}

__global__ __launch_bounds__(1024) void scan_k(const int* __restrict__ cnt, int* __restrict__ row_off,
                                               int* __restrict__ cursor, int N){
  __shared__ int wsum[17];
  int tid = threadIdx.x;
  int lane = tid & 63, wv = tid >> 6;
  int base = 0;
  for (int c0 = 0; c0 < N; c0 += 1024){
    int i = c0 + tid;
    int v = (i < N) ? cnt[i] : 0;
    int inc = v;
    #pragma unroll
    for (int d = 1; d < 64; d <<= 1){
      int t = __shfl_up(inc, d);
      if (lane >= d) inc += t;
    }
    if (lane == 63) wsum[wv] = inc;
    __syncthreads();
    if (tid == 0){
      int run = 0;
      for (int w = 0; w < 16; w++){ int t = wsum[w]; wsum[w] = run; run += t; }
      wsum[16] = run;
    }
    __syncthreads();
    int excl = base + wsum[wv] + inc - v;
    if (i < N){ row_off[i] = excl; cursor[i] = excl; }
    base += wsum[16];
    __syncthreads();
  }
  if (tid == 0) row_off[N] = base;
}

__global__ void fill_k(const int* __restrict__ src, const int* __restrict__ dst,
                       int* __restrict__ cursor, int* __restrict__ esrc, int E){
  int i = blockIdx.x * blockDim.x + threadIdx.x;
  int stride = gridDim.x * blockDim.x;
  for (; i < E; i += stride){
    int d = dst[i];
    int p = atomicAdd(&cursor[d], 1);
    esrc[p] = src[i];
  }
}

// ---------------- fused QKV projection (bf16 MFMA, no LDS) ----------------
__global__ __launch_bounds__(256) void gemm_qkv_k(
    const ushort16* __restrict__ Xq, const ushort16* __restrict__ Xkv,
    const ushort16* __restrict__ Wq, const ushort16* __restrict__ Wk, const ushort16* __restrict__ Wv,
    ushort16* __restrict__ Qo, ushort16* __restrict__ Ko, ushort16* __restrict__ Vo, int N)
{
  int lane = threadIdx.x & 63, wv = threadIdx.x >> 6;
  int l15 = lane & 15, kq = lane >> 4;
  int rowbase = (blockIdx.x * 4 + wv) * 16;
  int row = rowbase + l15;
  int rc = row < N ? row : N - 1;
  const short8_t* aq = (const short8_t*)(Xq + (size_t)rc * 128 + kq * 8);
  const short8_t* ak = (const short8_t*)(Xkv + (size_t)rc * 128 + kq * 8);
  short8_t Aq[4], Ak[4];
  #pragma unroll
  for (int s = 0; s < 4; s++){ Aq[s] = aq[s * 4]; Ak[s] = ak[s * 4]; }
  f32x4 q[8], k[8], v[8];
  #pragma unroll
  for (int m = 0; m < 8; m++){ q[m] = (f32x4)(0.f); k[m] = (f32x4)(0.f); v[m] = (f32x4)(0.f); }
  #pragma unroll
  for (int s = 0; s < 4; s++){
    #pragma unroll
    for (int m = 0; m < 8; m++){
      size_t wo = (size_t)(m * 16 + l15) * 128 + s * 32 + kq * 8;
      q[m] = __builtin_amdgcn_mfma_f32_16x16x32_bf16(Aq[s], *(const short8_t*)(Wq + wo), q[m], 0, 0, 0);
      k[m] = __builtin_amdgcn_mfma_f32_16x16x32_bf16(Ak[s], *(const short8_t*)(Wk + wo), k[m], 0, 0, 0);
      v[m] = __builtin_amdgcn_mfma_f32_16x16x32_bf16(Ak[s], *(const short8_t*)(Wv + wo), v[m], 0, 0, 0);
    }
  }
  int r0 = rowbase + kq * 4;
  #pragma unroll
  for (int m = 0; m < 8; m++){
    int col = m * 16 + l15;
    #pragma unroll
    for (int r = 0; r < 4; r++){
      int rr = r0 + r;
      if (rr < N){
        size_t oo = (size_t)rr * 128 + col;
        Qo[oo] = f2bf(q[m][r]);
        Ko[oo] = f2bf(k[m][r]);
        Vo[oo] = f2bf(v[m][r]);
      }
    }
  }
}

// ---------------- generic GEMM: C = epi(X[NxKD] * W[MDxKD]^T + bias) ----------------
// EPI: 1=relu->bf16, 2=sigmoid->f32, 3=+res->f32, 4=gate: (1-g)*res+g*v ->f32
template<int KD, int MD, int EPI>
__global__ __launch_bounds__(256) void gemm_k(
    const ushort16* __restrict__ X, const ushort16* __restrict__ W,
    const float* __restrict__ bias, const float* __restrict__ res,
    const float* __restrict__ gate, float* __restrict__ outf,
    ushort16* __restrict__ outb, int N)
{
  constexpr int KS = KD / 32;
  constexpr int MT = MD / 16;
  int lane = threadIdx.x & 63, wv = threadIdx.x >> 6;
  int l15 = lane & 15, kq = lane >> 4;
  int rowbase = (blockIdx.x * 4 + wv) * 16;
  int row = rowbase + l15;
  int rc = row < N ? row : N - 1;
  const short8_t* ap = (const short8_t*)(X + (size_t)rc * KD + kq * 8);
  short8_t a[KS];
  #pragma unroll
  for (int s = 0; s < KS; s++) a[s] = ap[s * 4];
  f32x4 acc[MT];
  #pragma unroll
  for (int m = 0; m < MT; m++) acc[m] = (f32x4)(0.f);
  #pragma unroll
  for (int s = 0; s < KS; s++){
    #pragma unroll
    for (int m = 0; m < MT; m++){
      const short8_t* bp = (const short8_t*)(W + (size_t)(m * 16 + l15) * KD + s * 32 + kq * 8);
      acc[m] = __builtin_amdgcn_mfma_f32_16x16x32_bf16(a[s], *bp, acc[m], 0, 0, 0);
    }
  }
  int r0 = rowbase + kq * 4;
  #pragma unroll
  for (int m = 0; m < MT; m++){
    int col = m * 16 + l15;
    float bv = bias ? bias[col] : 0.f;
    #pragma unroll
    for (int r = 0; r < 4; r++){
      int rr = r0 + r;
      if (rr < N){
        float v = acc[m][r] + bv;
        if constexpr (EPI == 1) v = fmaxf(v, 0.f);
        if constexpr (EPI == 2) v = 1.f / (1.f + __expf(-v));
        if constexpr (EPI == 3) v += res[(size_t)rr * MD + col];
        if constexpr (EPI == 4){
          float g = gate[(size_t)rr * MD + col];
          float rv = res[(size_t)rr * MD + col];
          v = (1.f - g) * rv + g * v;
        }
        if (outf) outf[(size_t)rr * MD + col] = v;
        if (outb) outb[(size_t)rr * MD + col] = f2bf(v);
      }
    }
  }
}

// ---------------- edge attention (CSR, one wave per dst node) ----------------
__global__ __launch_bounds__(256) void attn_k(
    const ushort16* __restrict__ Q, const ushort16* __restrict__ K, const ushort16* __restrict__ V,
    const int* __restrict__ row_off, const int* __restrict__ esrc,
    ushort16* __restrict__ out, int col0, int N)
{
  int wv = threadIdx.x >> 6, lane = threadIdx.x & 63;
  int n = blockIdx.x * 4 + wv;
  if (n >= N) return;
  uint32 qu = *(const uint32*)(Q + (size_t)n * 128 + lane * 2);
  float qx = bflo(qu) * 0.25f;   // 1/sqrt(DH)=0.25 pre-applied
  float qy = bfhi(qu) * 0.25f;
  int e0 = row_off[n], e1 = row_off[n + 1];
  float ax = 0.f, ay = 0.f, z = 0.f;
  int s = (e0 < e1) ? esrc[e0] : 0;
  for (int e = e0; e < e1; e++){
    uint32 ku = *(const uint32*)(K + (size_t)s * 128 + lane * 2);
    uint32 vu = *(const uint32*)(V + (size_t)s * 128 + lane * 2);
    int snext = (e + 1 < e1) ? esrc[e + 1] : 0;
    float d = bflo(ku) * qx + bfhi(ku) * qy;
    d += __shfl_xor(d, 1);
    d += __shfl_xor(d, 2);
    d += __shfl_xor(d, 4);      // now all 8 lanes of this head hold the dot
    d = fminf(fmaxf(d, -5.f), 5.f);
    float sc = __expf(d);
    ax = fmaf(sc, bflo(vu), ax);
    ay = fmaf(sc, bfhi(vu), ay);
    z += sc;
    s = snext;
  }
  float rz = 1.f / z;
  uint32 o = (uint32)f2bf(ax * rz) | ((uint32)f2bf(ay * rz) << 16);
  *(uint32*)(out + (size_t)n * 256 + col0 + lane * 2) = o;
}

// ---------------- BatchNorm ----------------
__global__ __launch_bounds__(256) void bn_stats_k(const float* __restrict__ x, float* __restrict__ stats, int N){
  int col = threadIdx.x & 127;
  int half = threadIdx.x >> 7;
  int r0 = blockIdx.x * 128;
  int rend = r0 + 128 < N ? r0 + 128 : N;
  float s = 0.f, s2 = 0.f;
  for (int r = r0 + half; r < rend; r += 2){
    float v = x[(size_t)r * 128 + col];
    s += v; s2 += v * v;
  }
  __shared__ float ls[256], ls2[256];
  ls[threadIdx.x] = s; ls2[threadIdx.x] = s2;
  __syncthreads();
  if (threadIdx.x < 128){
    atomicAdd(&stats[col], ls[threadIdx.x] + ls[threadIdx.x + 128]);
    atomicAdd(&stats[128 + col], ls2[threadIdx.x] + ls2[threadIdx.x + 128]);
  }
}

__global__ __launch_bounds__(256) void bn_apply_k(
    const float4* __restrict__ x, const float* __restrict__ stats,
    const float* __restrict__ gamma, const float* __restrict__ beta,
    float4* __restrict__ outf, ushort16* __restrict__ outb, int total4, float invN)
{
  int i = blockIdx.x * 256 + threadIdx.x;
  if (i >= total4) return;
  float4 v = x[i];
  int c0 = (i * 4) & 127;
  float o[4];
  float xv[4] = {v.x, v.y, v.z, v.w};
  #pragma unroll
  for (int j = 0; j < 4; j++){
    int c = c0 + j;
    float m = stats[c] * invN;
    float var = stats[128 + c] * invN - m * m;
    float rstd = rsqrtf(var + EPS_BN);
    o[j] = (xv[j] - m) * rstd * gamma[c] + beta[c];
  }
  outf[i] = make_float4(o[0], o[1], o[2], o[3]);
  if (outb){
    uint2 p;
    p.x = (uint32)f2bf(o[0]) | ((uint32)f2bf(o[1]) << 16);
    p.y = (uint32)f2bf(o[2]) | ((uint32)f2bf(o[3]) << 16);
    *(uint2*)(outb + (size_t)i * 4) = p;
  }
}

// ---------------- host ----------------
extern "C" void kernel_launch(void* const* d_in, const int* in_sizes, int n_in,
                              void* d_out, int out_size, void* d_ws, size_t ws_size,
                              hipStream_t stream) {
  const float* h   = (const float*)d_in[0];
  const float* sv  = (const float*)d_in[1];
  const int* src   = (const int*)d_in[2];
  const int* dst   = (const int*)d_in[3];
  const int N = in_sizes[0] / 128;
  const int E = in_sizes[2];

  char* wsb = (char*)d_ws;
  size_t o = 0;
  auto take = [&](size_t bytes)->size_t{
    size_t r = o;
    o = (o + bytes + 255) & ~(size_t)255;
    return r;
  };
  size_t cnt_off    = take((size_t)N * 4);
  size_t stats_off  = take(4 * 256 * 4);
  size_t rowoff_off = take((size_t)(N + 1) * 4);
  size_t cursor_off = take((size_t)N * 4);
  size_t esrc_off   = take((size_t)E * 4);
  size_t wpool_off  = take((size_t)376832 * 2);
  size_t hbf_off    = take((size_t)N * 128 * 2);
  size_t svbf_off   = take((size_t)N * 128 * 2);
  size_t Qb_off     = take((size_t)N * 128 * 2);
  size_t Kb_off     = take((size_t)N * 128 * 2);
  size_t Vb_off     = take((size_t)N * 128 * 2);
  size_t cath_off   = take((size_t)N * 256 * 2);
  size_t catsv_off  = take((size_t)N * 256 * 2);
  size_t X_off      = take((size_t)N * 128 * 4);
  size_t R_off      = take((size_t)N * 128 * 4);
  size_t G_off      = take((size_t)N * 128 * 4);

  int*    cnt     = (int*)(wsb + cnt_off);
  float*  stats   = (float*)(wsb + stats_off);
  int*    row_off = (int*)(wsb + rowoff_off);
  int*    cursor  = (int*)(wsb + cursor_off);
  int*    esrc    = (int*)(wsb + esrc_off);
  ushort16* wpool = (ushort16*)(wsb + wpool_off);
  ushort16* h_bf  = (ushort16*)(wsb + hbf_off);
  ushort16* sv_bf = (ushort16*)(wsb + svbf_off);
  ushort16* Qb    = (ushort16*)(wsb + Qb_off);
  ushort16* Kb    = (ushort16*)(wsb + Kb_off);
  ushort16* Vb    = (ushort16*)(wsb + Vb_off);
  ushort16* cat_h = (ushort16*)(wsb + cath_off);
  ushort16* cat_sv= (ushort16*)(wsb + catsv_off);
  float*  Xb      = (float*)(wsb + X_off);
  float*  Rb      = (float*)(wsb + R_off);
  float*  Gb      = (float*)(wsb + G_off);

  // bf16 weight pool offsets (elements)
  ushort16* Wq_sv = wpool + 0 * 16384;
  ushort16* Wk_sv = wpool + 1 * 16384;
  ushort16* Wv_sv = wpool + 2 * 16384;
  ushort16* Wq_cv = wpool + 3 * 16384;
  ushort16* Wk_cv = wpool + 4 * 16384;
  ushort16* Wv_cv = wpool + 5 * 16384;
  ushort16* Wq_sh = wpool + 6 * 16384;
  ushort16* Wk_sh = wpool + 7 * 16384;
  ushort16* Wv_sh = wpool + 8 * 16384;
  ushort16* Wg1b  = wpool + 147456;
  ushort16* Wg2b  = wpool + 163840;
  ushort16* Wob   = wpool + 180224;
  ushort16* Wohb  = wpool + 212992;
  ushort16* W1b   = wpool + 245760;
  ushort16* W2b   = wpool + 278528;
  ushort16* W1hb  = wpool + 311296;
  ushort16* W2hb  = wpool + 344064;

  // fp32 biases / BN params straight from inputs
  const float* bo   = (const float*)d_in[14];
  const float* bo_h = (const float*)d_in[16];
  const float* b1   = (const float*)d_in[18];
  const float* b2   = (const float*)d_in[20];
  const float* b1h  = (const float*)d_in[22];
  const float* b2h  = (const float*)d_in[24];
  const float* bg1  = (const float*)d_in[26];
  const float* bg2  = (const float*)d_in[28];
  const float* gbn1  = (const float*)d_in[29];
  const float* bbn1  = (const float*)d_in[30];
  const float* gbn2  = (const float*)d_in[31];
  const float* bbn2  = (const float*)d_in[32];
  const float* gbn1h = (const float*)d_in[33];
  const float* bbn1h = (const float*)d_in[34];
  const float* gbn2h = (const float*)d_in[35];
  const float* bbn2h = (const float*)d_in[36];

  float* out_h  = (float*)d_out;
  float* out_sv = out_h + (size_t)N * 128;

  // zero cnt + stats (contiguous region at ws start)
  hipMemsetAsync(wsb, 0, stats_off + 4 * 256 * 4, stream);

  // weight conversion
  WConv wc;
  int widx_in[17] = {4,5,6,7,8,9,10,11,12, 25,27, 13,15,17,19,21,23};
  size_t wdst[17] = {0,16384,32768,49152,65536,81920,98304,114688,131072,
                     147456,163840, 180224,212992,245760,278528,311296,344064};
  int wn[17] = {16384,16384,16384,16384,16384,16384,16384,16384,16384,
                16384,16384, 32768,32768,32768,32768,32768,32768};
  for (int i = 0; i < 17; i++){
    wc.s[i] = (const float*)d_in[widx_in[i]];
    wc.d[i] = wpool + wdst[i];
    wc.n[i] = wn[i];
  }
  conv_w_k<<<dim3(32, 17), 256, 0, stream>>>(wc);

  int nelem = N * 128;
  conv2_k<<<dim3((nelem / 4 + 255) / 256, 2), 256, 0, stream>>>(h, sv, h_bf, sv_bf, nelem);

  // CSR build
  hist_k<<<2048, 256, 0, stream>>>(dst, cnt, E);
  scan_k<<<1, 1024, 0, stream>>>(cnt, row_off, cursor, N);
  fill_k<<<2048, 256, 0, stream>>>(src, dst, cursor, esrc, E);

  const int GB = (N + 63) / 64;      // gemm blocks
  const int AB = (N + 3) / 4;        // attn blocks
  const int SB = (N + 127) / 128;    // bn_stats blocks
  const int T4 = nelem / 4;
  const int APB = (T4 + 255) / 256;  // bn_apply blocks
  const float invN = 1.f / (float)N;

  // attn1: self(h)
  gemm_qkv_k<<<GB, 256, 0, stream>>>(h_bf, h_bf, Wq_sv, Wk_sv, Wv_sv, Qb, Kb, Vb, N);
  attn_k<<<AB, 256, 0, stream>>>(Qb, Kb, Vb, row_off, esrc, cat_h, 0, N);
  // attn2: cross(h; sv)
  gemm_qkv_k<<<GB, 256, 0, stream>>>(h_bf, sv_bf, Wq_cv, Wk_cv, Wv_cv, Qb, Kb, Vb, N);
  attn_k<<<AB, 256, 0, stream>>>(Qb, Kb, Vb, row_off, esrc, cat_h, 128, N);
  // attn3: self(sv)
  gemm_qkv_k<<<GB, 256, 0, stream>>>(sv_bf, sv_bf, Wq_sh, Wk_sh, Wv_sh, Qb, Kb, Vb, N);
  attn_k<<<AB, 256, 0, stream>>>(Qb, Kb, Vb, row_off, esrc, cat_sv, 0, N);
  // attn4: cross(sv; h)
  gemm_qkv_k<<<GB, 256, 0, stream>>>(sv_bf, h_bf, Wq_cv, Wk_cv, Wv_cv, Qb, Kb, Vb, N);
  attn_k<<<AB, 256, 0, stream>>>(Qb, Kb, Vb, row_off, esrc, cat_sv, 128, N);

  // ---- h branch ----
  // x1 = h + cat_h @ Wo^T + bo
  gemm_k<256,128,3><<<GB, 256, 0, stream>>>(cat_h, Wob, bo, h, nullptr, Xb, nullptr, N);
  bn_stats_k<<<SB, 256, 0, stream>>>(Xb, stats, N);
  bn_apply_k<<<APB, 256, 0, stream>>>((const float4*)Xb, stats, gbn1, bbn1, (float4*)Rb, Qb, T4, invN);
  // u = relu(h1 @ W1^T + b1)   (bf16, into cat_h region)
  gemm_k<128,256,1><<<GB, 256, 0, stream>>>(Qb, W1b, b1, nullptr, nullptr, nullptr, cat_h, N);
  // x2 = h1 + u @ W2^T + b2
  gemm_k<256,128,3><<<GB, 256, 0, stream>>>(cat_h, W2b, b2, Rb, nullptr, Xb, nullptr, N);
  bn_stats_k<<<SB, 256, 0, stream>>>(Xb, stats + 256, N);
  bn_apply_k<<<APB, 256, 0, stream>>>((const float4*)Xb, stats + 256, gbn2, bbn2, (float4*)out_h, nullptr, T4, invN);

  // ---- sv branch ----
  // g1 = sigmoid(h @ Wg1^T + bg1)
  gemm_k<128,128,2><<<GB, 256, 0, stream>>>(h_bf, Wg1b, bg1, nullptr, nullptr, Gb, nullptr, N);
  // x = (1-g1)*sv + g1*(cat_sv @ Wo_h^T + bo_h)
  gemm_k<256,128,4><<<GB, 256, 0, stream>>>(cat_sv, Wohb, bo_h, sv, Gb, Xb, nullptr, N);
  bn_stats_k<<<SB, 256, 0, stream>>>(Xb, stats + 512, N);
  bn_apply_k<<<APB, 256, 0, stream>>>((const float4*)Xb, stats + 512, gbn1h, bbn1h, (float4*)Rb, Kb, T4, invN);
  // uh = relu(sv1 @ W1h^T + b1h)  (bf16, into cat_sv region)
  gemm_k<128,256,1><<<GB, 256, 0, stream>>>(Kb, W1hb, b1h, nullptr, nullptr, nullptr, cat_sv, N);
  // g2 = sigmoid(h @ Wg2^T + bg2)
  gemm_k<128,128,2><<<GB, 256, 0, stream>>>(h_bf, Wg2b, bg2, nullptr, nullptr, Gb, nullptr, N);
  // x = (1-g2)*sv1 + g2*(uh @ W2h^T + b2h)
  gemm_k<256,128,4><<<GB, 256, 0, stream>>>(cat_sv, W2hb, b2h, Rb, Gb, Xb, nullptr, N);
  bn_stats_k<<<SB, 256, 0, stream>>>(Xb, stats + 768, N);
  bn_apply_k<<<APB, 256, 0, stream>>>((const float4*)Xb, stats + 768, gbn2h, bbn2h, (float4*)out_sv, nullptr, T4, invN);
}

// Round 3
// 1580.345 us; speedup vs baseline: 1.0251x; 1.0251x over previous
//
#include <hip/hip_runtime.h>

typedef _Float16 f16x8 __attribute__((ext_vector_type(8)));
typedef _Float16 f16x2 __attribute__((ext_vector_type(2)));
typedef __fp16 fp16x2_raw __attribute__((ext_vector_type(2)));
typedef float f32x4 __attribute__((ext_vector_type(4)));
typedef unsigned int uint32;
typedef unsigned short ushort16;

#define EPS_BN 1e-5f

__device__ __forceinline__ uint32 pk16(float a, float b){
  fp16x2_raw h = __builtin_amdgcn_cvt_pkrtz(a, b);
  return *(uint32*)&h;
}
__device__ __forceinline__ ushort16 f2h(float f){
  _Float16 h = (_Float16)f;
  union { _Float16 h; ushort16 u; } c; c.h = h; return c.u;
}

#if __has_builtin(__builtin_amdgcn_fdot2)
__device__ __forceinline__ float fdot2f(f16x2 a, f16x2 b, float c){
  return __builtin_amdgcn_fdot2(*(fp16x2_raw*)&a, *(fp16x2_raw*)&b, c, false);
}
#else
__device__ __forceinline__ float fdot2f(f16x2 a, f16x2 b, float c){
  return fmaf((float)a.x, (float)b.x, fmaf((float)a.y, (float)b.y, c));
}
#endif

// ---------------- conversion kernels ----------------
struct WConv {
  const float* s[17];
  ushort16* d[17];
  int n[17];
};

__global__ __launch_bounds__(256) void conv_w_k(WConv a){
  int m = blockIdx.y;
  int i = (blockIdx.x * 256 + threadIdx.x) * 4;
  if (i >= a.n[m]) return;
  float4 v = *(const float4*)(a.s[m] + i);
  uint2 p;
  p.x = pk16(v.x, v.y);
  p.y = pk16(v.z, v.w);
  *(uint2*)(a.d[m] + i) = p;
}

__global__ __launch_bounds__(256) void conv2_k(const float* __restrict__ a, const float* __restrict__ b,
                                               ushort16* __restrict__ da, ushort16* __restrict__ db, int n){
  const float* s = blockIdx.y ? b : a;
  ushort16* d = blockIdx.y ? db : da;
  int i = (blockIdx.x * 256 + threadIdx.x) * 4;
  if (i >= n) return;
  float4 v = *(const float4*)(s + i);
  uint2 p;
  p.x = pk16(v.x, v.y);
  p.y = pk16(v.z, v.w);
  *(uint2*)(d + i) = p;
}

// ---------------- CSR build ----------------
__global__ void hist_k(const int* __restrict__ dst, int* __restrict__ cnt, int E){
  int i = blockIdx.x * blockDim.x + threadIdx.x;
  int stride = gridDim.x * blockDim.x;
  for (; i < E; i += stride) atomicAdd(&cnt[dst[i]], 1);
}

__global__ __launch_bounds__(1024) void scan_k(const int* __restrict__ cnt, int* __restrict__ row_off,
                                               int* __restrict__ cursor, int N){
  __shared__ int wsum[17];
  int tid = threadIdx.x;
  int lane = tid & 63, wv = tid >> 6;
  int base = 0;
  for (int c0 = 0; c0 < N; c0 += 1024){
    int i = c0 + tid;
    int v = (i < N) ? cnt[i] : 0;
    int inc = v;
    #pragma unroll
    for (int d = 1; d < 64; d <<= 1){
      int t = __shfl_up(inc, d);
      if (lane >= d) inc += t;
    }
    if (lane == 63) wsum[wv] = inc;
    __syncthreads();
    if (tid == 0){
      int run = 0;
      for (int w = 0; w < 16; w++){ int t = wsum[w]; wsum[w] = run; run += t; }
      wsum[16] = run;
    }
    __syncthreads();
    int excl = base + wsum[wv] + inc - v;
    if (i < N){ row_off[i] = excl; cursor[i] = excl; }
    base += wsum[16];
    __syncthreads();
  }
  if (tid == 0) row_off[N] = base;
}

__global__ void fill_k(const int* __restrict__ src, const int* __restrict__ dst,
                       int* __restrict__ cursor, int* __restrict__ esrc, int E){
  int i = blockIdx.x * blockDim.x + threadIdx.x;
  int stride = gridDim.x * blockDim.x;
  for (; i < E; i += stride){
    int d = dst[i];
    int p = atomicAdd(&cursor[d], 1);
    esrc[p] = src[i];
  }
}

// ---------------- fused QKV projection (f16 MFMA) ----------------
// Writes Q row-major (128 f16/node) and KV interleaved:
// node row = 32 x 16B blocks, block j = [K[4j..4j+3] | V[4j..4j+3]]
__global__ __launch_bounds__(256) void gemm_qkv_k(
    const ushort16* __restrict__ Xq, const ushort16* __restrict__ Xkv,
    const ushort16* __restrict__ Wq, const ushort16* __restrict__ Wk, const ushort16* __restrict__ Wv,
    ushort16* __restrict__ Qo, ushort16* __restrict__ KVo, int N)
{
  int lane = threadIdx.x & 63, wv = threadIdx.x >> 6;
  int l15 = lane & 15, kq = lane >> 4;
  int rowbase = (blockIdx.x * 4 + wv) * 16;
  int row = rowbase + l15;
  int rc = row < N ? row : N - 1;
  const f16x8* aq = (const f16x8*)(Xq + (size_t)rc * 128 + kq * 8);
  const f16x8* ak = (const f16x8*)(Xkv + (size_t)rc * 128 + kq * 8);
  f16x8 Aq[4], Ak[4];
  #pragma unroll
  for (int s = 0; s < 4; s++){ Aq[s] = aq[s * 4]; Ak[s] = ak[s * 4]; }
  f32x4 q[8], k[8], v[8];
  #pragma unroll
  for (int m = 0; m < 8; m++){ q[m] = (f32x4)(0.f); k[m] = (f32x4)(0.f); v[m] = (f32x4)(0.f); }
  #pragma unroll
  for (int s = 0; s < 4; s++){
    #pragma unroll
    for (int m = 0; m < 8; m++){
      size_t wo = (size_t)(m * 16 + l15) * 128 + s * 32 + kq * 8;
      q[m] = __builtin_amdgcn_mfma_f32_16x16x32_f16(Aq[s], *(const f16x8*)(Wq + wo), q[m], 0, 0, 0);
      k[m] = __builtin_amdgcn_mfma_f32_16x16x32_f16(Ak[s], *(const f16x8*)(Wk + wo), k[m], 0, 0, 0);
      v[m] = __builtin_amdgcn_mfma_f32_16x16x32_f16(Ak[s], *(const f16x8*)(Wv + wo), v[m], 0, 0, 0);
    }
  }
  int r0 = rowbase + kq * 4;
  #pragma unroll
  for (int m = 0; m < 8; m++){
    int col = m * 16 + l15;
    int kvcol = (col >> 2) * 8 + (col & 3);
    #pragma unroll
    for (int r = 0; r < 4; r++){
      int rr = r0 + r;
      if (rr < N){
        Qo[(size_t)rr * 128 + col] = f2h(q[m][r]);
        size_t kvbase = (size_t)rr * 256 + kvcol;
        KVo[kvbase]     = f2h(k[m][r]);
        KVo[kvbase + 4] = f2h(v[m][r]);
      }
    }
  }
}

// ---------------- generic GEMM: C = epi(X[NxKD] * W[MDxKD]^T + bias) ----------------
// EPI: 1=relu->f16, 2=sigmoid->f32, 3=+res->f32, 4=gate: (1-g)*res+g*v ->f32
template<int KD, int MD, int EPI, int GS>
__global__ __launch_bounds__(256) void gemm_k(
    const ushort16* __restrict__ X, const ushort16* __restrict__ W,
    const float* __restrict__ bias, const float* __restrict__ bias2,
    const float* __restrict__ res, const float* __restrict__ gate,
    float* __restrict__ outf, ushort16* __restrict__ outb, int N)
{
  constexpr int KS = KD / 32;
  constexpr int MT = MD / 16;
  int lane = threadIdx.x & 63, wv = threadIdx.x >> 6;
  int l15 = lane & 15, kq = lane >> 4;
  int rowbase = (blockIdx.x * 4 + wv) * 16;
  int row = rowbase + l15;
  int rc = row < N ? row : N - 1;
  const f16x8* ap = (const f16x8*)(X + (size_t)rc * KD + kq * 8);
  f16x8 a[KS];
  #pragma unroll
  for (int s = 0; s < KS; s++) a[s] = ap[s * 4];
  f32x4 acc[MT];
  #pragma unroll
  for (int m = 0; m < MT; m++) acc[m] = (f32x4)(0.f);
  #pragma unroll
  for (int s = 0; s < KS; s++){
    #pragma unroll
    for (int m = 0; m < MT; m++){
      const f16x8* bp = (const f16x8*)(W + (size_t)(m * 16 + l15) * KD + s * 32 + kq * 8);
      acc[m] = __builtin_amdgcn_mfma_f32_16x16x32_f16(a[s], *bp, acc[m], 0, 0, 0);
    }
  }
  int r0 = rowbase + kq * 4;
  #pragma unroll
  for (int m = 0; m < MT; m++){
    int col = m * 16 + l15;
    float bv;
    if (bias2 && col >= 128) bv = bias2[col - 128];
    else bv = bias ? bias[col] : 0.f;
    #pragma unroll
    for (int r = 0; r < 4; r++){
      int rr = r0 + r;
      if (rr < N){
        float v = acc[m][r] + bv;
        if constexpr (EPI == 1) v = fmaxf(v, 0.f);
        if constexpr (EPI == 2) v = 1.f / (1.f + __expf(-v));
        if constexpr (EPI == 3) v += res[(size_t)rr * MD + col];
        if constexpr (EPI == 4){
          float g = gate[(size_t)rr * GS + col];
          float rv = res[(size_t)rr * MD + col];
          v = (1.f - g) * rv + g * v;
        }
        if (outf) outf[(size_t)rr * MD + col] = v;
        if (outb) outb[(size_t)rr * MD + col] = f2h(v);
      }
    }
  }
}

// ---------------- fused dual-attention (self+cross for one cat buffer) ----------------
// one wave per dst node; half-wave h processes edges e0+h, e0+h+2, ...
// lane j (0..31) owns dims 4j..4j+3; head = 16 dims = 4 lanes -> shfl_xor 1,2
__global__ __launch_bounds__(256) void attn2_k(
    const ushort16* __restrict__ Qa, const uint4* __restrict__ KVa,
    const ushort16* __restrict__ Qb, const uint4* __restrict__ KVb,
    const int* __restrict__ row_off, const int* __restrict__ esrc,
    ushort16* __restrict__ cat, int N)
{
  int wv = threadIdx.x >> 6, lane = threadIdx.x & 63;
  int n = blockIdx.x * 4 + wv;
  if (n >= N) return;
  int h = lane >> 5, j = lane & 31;
  uint2 qau = *(const uint2*)(Qa + (size_t)n * 128 + j * 4);
  uint2 qbu = *(const uint2*)(Qb + (size_t)n * 128 + j * 4);
  f16x2 qa01 = *(f16x2*)&qau.x, qa23 = *(f16x2*)&qau.y;
  f16x2 qb01 = *(f16x2*)&qbu.x, qb23 = *(f16x2*)&qbu.y;
  int e0 = row_off[n], e1 = row_off[n + 1];
  int deg = e1 - e0;
  int itmax = (deg + 1) >> 1;
  float a0 = 0.f, a1 = 0.f, a2 = 0.f, a3 = 0.f, za = 0.f;
  float b0 = 0.f, b1 = 0.f, b2 = 0.f, b3 = 0.f, zb = 0.f;
  int e = e0 + h;
  int s = (e < e1) ? esrc[e] : -1;
  int sc = s < 0 ? 0 : s;
  uint4 ka = KVa[(size_t)sc * 32 + j];
  uint4 kb = KVb[(size_t)sc * 32 + j];
  for (int it = 0; it < itmax; ++it){
    int e2 = e + 2;
    int s2 = (e2 < e1) ? esrc[e2] : -1;
    int s2c = s2 < 0 ? 0 : s2;
    uint4 ka2 = KVa[(size_t)s2c * 32 + j];
    uint4 kb2 = KVb[(size_t)s2c * 32 + j];
    if (s >= 0){
      float da = fdot2f(*(f16x2*)&ka.x, qa01, fdot2f(*(f16x2*)&ka.y, qa23, 0.f));
      float db = fdot2f(*(f16x2*)&kb.x, qb01, fdot2f(*(f16x2*)&kb.y, qb23, 0.f));
      da += __shfl_xor(da, 1); da += __shfl_xor(da, 2);
      db += __shfl_xor(db, 1); db += __shfl_xor(db, 2);
      float sa = __expf(fminf(fmaxf(da * 0.25f, -5.f), 5.f));
      float sb = __expf(fminf(fmaxf(db * 0.25f, -5.f), 5.f));
      f16x2 va01 = *(f16x2*)&ka.z, va23 = *(f16x2*)&ka.w;
      f16x2 vb01 = *(f16x2*)&kb.z, vb23 = *(f16x2*)&kb.w;
      a0 = fmaf(sa, (float)va01.x, a0); a1 = fmaf(sa, (float)va01.y, a1);
      a2 = fmaf(sa, (float)va23.x, a2); a3 = fmaf(sa, (float)va23.y, a3);
      za += sa;
      b0 = fmaf(sb, (float)vb01.x, b0); b1 = fmaf(sb, (float)vb01.y, b1);
      b2 = fmaf(sb, (float)vb23.x, b2); b3 = fmaf(sb, (float)vb23.y, b3);
      zb += sb;
    }
    e = e2; s = s2; ka = ka2; kb = kb2;
  }
  a0 += __shfl_xor(a0, 32); a1 += __shfl_xor(a1, 32);
  a2 += __shfl_xor(a2, 32); a3 += __shfl_xor(a3, 32);
  za += __shfl_xor(za, 32);
  b0 += __shfl_xor(b0, 32); b1 += __shfl_xor(b1, 32);
  b2 += __shfl_xor(b2, 32); b3 += __shfl_xor(b3, 32);
  zb += __shfl_xor(zb, 32);
  uint2 o;
  if (h == 0){
    float rz = __builtin_amdgcn_rcpf(za);
    o.x = pk16(a0 * rz, a1 * rz);
    o.y = pk16(a2 * rz, a3 * rz);
    *(uint2*)(cat + (size_t)n * 256 + j * 4) = o;
  } else {
    float rz = __builtin_amdgcn_rcpf(zb);
    o.x = pk16(b0 * rz, b1 * rz);
    o.y = pk16(b2 * rz, b3 * rz);
    *(uint2*)(cat + (size_t)n * 256 + 128 + j * 4) = o;
  }
}

// ---------------- BatchNorm ----------------
__global__ __launch_bounds__(256) void bn_stats_k(const float* __restrict__ x, float* __restrict__ stats, int N){
  int col = threadIdx.x & 127;
  int half = threadIdx.x >> 7;
  int r0 = blockIdx.x * 128;
  int rend = r0 + 128 < N ? r0 + 128 : N;
  float s = 0.f, s2 = 0.f;
  for (int r = r0 + half; r < rend; r += 2){
    float v = x[(size_t)r * 128 + col];
    s += v; s2 += v * v;
  }
  __shared__ float ls[256], ls2[256];
  ls[threadIdx.x] = s; ls2[threadIdx.x] = s2;
  __syncthreads();
  if (threadIdx.x < 128){
    atomicAdd(&stats[col], ls[threadIdx.x] + ls[threadIdx.x + 128]);
    atomicAdd(&stats[128 + col], ls2[threadIdx.x] + ls2[threadIdx.x + 128]);
  }
}

__global__ __launch_bounds__(256) void bn_apply_k(
    const float4* __restrict__ x, const float* __restrict__ stats,
    const float* __restrict__ gamma, const float* __restrict__ beta,
    float4* __restrict__ outf, ushort16* __restrict__ outb, int total4, float invN)
{
  int i = blockIdx.x * 256 + threadIdx.x;
  if (i >= total4) return;
  float4 v = x[i];
  int c0 = (i * 4) & 127;
  float o[4];
  float xv[4] = {v.x, v.y, v.z, v.w};
  #pragma unroll
  for (int j = 0; j < 4; j++){
    int c = c0 + j;
    float m = stats[c] * invN;
    float var = stats[128 + c] * invN - m * m;
    float rstd = rsqrtf(var + EPS_BN);
    o[j] = (xv[j] - m) * rstd * gamma[c] + beta[c];
  }
  outf[i] = make_float4(o[0], o[1], o[2], o[3]);
  if (outb){
    uint2 p;
    p.x = pk16(o[0], o[1]);
    p.y = pk16(o[2], o[3]);
    *(uint2*)(outb + (size_t)i * 4) = p;
  }
}

// ---------------- host ----------------
extern "C" void kernel_launch(void* const* d_in, const int* in_sizes, int n_in,
                              void* d_out, int out_size, void* d_ws, size_t ws_size,
                              hipStream_t stream) {
  const float* h   = (const float*)d_in[0];
  const float* sv  = (const float*)d_in[1];
  const int* src   = (const int*)d_in[2];
  const int* dst   = (const int*)d_in[3];
  const int N = in_sizes[0] / 128;
  const int E = in_sizes[2];

  char* wsb = (char*)d_ws;
  size_t o = 0;
  auto take = [&](size_t bytes)->size_t{
    size_t r = o;
    o = (o + bytes + 255) & ~(size_t)255;
    return r;
  };
  size_t cnt_off    = take((size_t)N * 4);
  size_t stats_off  = take(4 * 256 * 4);
  size_t rowoff_off = take((size_t)(N + 1) * 4);
  size_t cursor_off = take((size_t)N * 4);
  size_t esrc_off   = take((size_t)E * 4);
  size_t wpool_off  = take((size_t)376832 * 2);
  size_t hf_off     = take((size_t)N * 128 * 2);
  size_t svf_off    = take((size_t)N * 128 * 2);
  size_t cath_off   = take((size_t)N * 256 * 2);
  size_t catsv_off  = take((size_t)N * 256 * 2);
  size_t X_off      = take((size_t)N * 128 * 4);   // also KV1 (N*256 f16 = same bytes)
  size_t R_off      = take((size_t)N * 128 * 4);   // also KV2
  size_t G_off      = take((size_t)N * 256 * 4);   // gates f32 N x 256; also Q1/Q2 f16
  size_t h1_off     = take((size_t)N * 128 * 2);
  size_t sv1_off    = take((size_t)N * 128 * 2);

  int*    cnt     = (int*)(wsb + cnt_off);
  float*  stats   = (float*)(wsb + stats_off);
  int*    row_off = (int*)(wsb + rowoff_off);
  int*    cursor  = (int*)(wsb + cursor_off);
  int*    esrc    = (int*)(wsb + esrc_off);
  ushort16* wpool = (ushort16*)(wsb + wpool_off);
  ushort16* h_f   = (ushort16*)(wsb + hf_off);
  ushort16* sv_f  = (ushort16*)(wsb + svf_off);
  ushort16* cat_h = (ushort16*)(wsb + cath_off);
  ushort16* cat_sv= (ushort16*)(wsb + catsv_off);
  float*  Xb      = (float*)(wsb + X_off);
  float*  Rb      = (float*)(wsb + R_off);
  float*  Gb      = (float*)(wsb + G_off);
  ushort16* h1b   = (ushort16*)(wsb + h1_off);
  ushort16* sv1b  = (ushort16*)(wsb + sv1_off);

  // attention staging overlays (used strictly before Xb/Rb/Gb are written)
  ushort16* KV1 = (ushort16*)(wsb + X_off);
  ushort16* KV2 = (ushort16*)(wsb + R_off);
  ushort16* Q1  = (ushort16*)(wsb + G_off);
  ushort16* Q2  = (ushort16*)(wsb + G_off + (size_t)N * 128 * 2);

  // f16 weight pool offsets (elements)
  ushort16* Wq_sv = wpool + 0 * 16384;
  ushort16* Wk_sv = wpool + 1 * 16384;
  ushort16* Wv_sv = wpool + 2 * 16384;
  ushort16* Wq_cv = wpool + 3 * 16384;
  ushort16* Wk_cv = wpool + 4 * 16384;
  ushort16* Wv_cv = wpool + 5 * 16384;
  ushort16* Wq_sh = wpool + 6 * 16384;
  ushort16* Wk_sh = wpool + 7 * 16384;
  ushort16* Wv_sh = wpool + 8 * 16384;
  ushort16* Wgb   = wpool + 147456;   // [Wg1;Wg2] stacked 256x128
  ushort16* Wob   = wpool + 180224;
  ushort16* Wohb  = wpool + 212992;
  ushort16* W1b   = wpool + 245760;
  ushort16* W2b   = wpool + 278528;
  ushort16* W1hb  = wpool + 311296;
  ushort16* W2hb  = wpool + 344064;

  const float* bo   = (const float*)d_in[14];
  const float* bo_h = (const float*)d_in[16];
  const float* b1   = (const float*)d_in[18];
  const float* b2   = (const float*)d_in[20];
  const float* b1h  = (const float*)d_in[22];
  const float* b2h  = (const float*)d_in[24];
  const float* bg1  = (const float*)d_in[26];
  const float* bg2  = (const float*)d_in[28];
  const float* gbn1  = (const float*)d_in[29];
  const float* bbn1  = (const float*)d_in[30];
  const float* gbn2  = (const float*)d_in[31];
  const float* bbn2  = (const float*)d_in[32];
  const float* gbn1h = (const float*)d_in[33];
  const float* bbn1h = (const float*)d_in[34];
  const float* gbn2h = (const float*)d_in[35];
  const float* bbn2h = (const float*)d_in[36];

  float* out_h  = (float*)d_out;
  float* out_sv = out_h + (size_t)N * 128;

  hipMemsetAsync(wsb, 0, stats_off + 4 * 256 * 4, stream);

  WConv wc;
  int widx_in[17] = {4,5,6,7,8,9,10,11,12, 25,27, 13,15,17,19,21,23};
  size_t wdst[17] = {0,16384,32768,49152,65536,81920,98304,114688,131072,
                     147456,163840, 180224,212992,245760,278528,311296,344064};
  int wn[17] = {16384,16384,16384,16384,16384,16384,16384,16384,16384,
                16384,16384, 32768,32768,32768,32768,32768,32768};
  for (int i = 0; i < 17; i++){
    wc.s[i] = (const float*)d_in[widx_in[i]];
    wc.d[i] = wpool + wdst[i];
    wc.n[i] = wn[i];
  }
  conv_w_k<<<dim3(32, 17), 256, 0, stream>>>(wc);

  int nelem = N * 128;
  conv2_k<<<dim3((nelem / 4 + 255) / 256, 2), 256, 0, stream>>>(h, sv, h_f, sv_f, nelem);

  hist_k<<<2048, 256, 0, stream>>>(dst, cnt, E);
  scan_k<<<1, 1024, 0, stream>>>(cnt, row_off, cursor, N);
  fill_k<<<2048, 256, 0, stream>>>(src, dst, cursor, esrc, E);

  const int GB = (N + 63) / 64;
  const int AB = (N + 3) / 4;
  const int SB = (N + 127) / 128;
  const int T4 = nelem / 4;
  const int APB = (T4 + 255) / 256;
  const float invN = 1.f / (float)N;

  // h-branch attention pair: self(h) + cross(h; sv)
  gemm_qkv_k<<<GB, 256, 0, stream>>>(h_f, h_f, Wq_sv, Wk_sv, Wv_sv, Q1, KV1, N);
  gemm_qkv_k<<<GB, 256, 0, stream>>>(h_f, sv_f, Wq_cv, Wk_cv, Wv_cv, Q2, KV2, N);
  attn2_k<<<AB, 256, 0, stream>>>(Q1, (const uint4*)KV1, Q2, (const uint4*)KV2, row_off, esrc, cat_h, N);
  // sv-branch attention pair: self(sv) + cross(sv; h)
  gemm_qkv_k<<<GB, 256, 0, stream>>>(sv_f, sv_f, Wq_sh, Wk_sh, Wv_sh, Q1, KV1, N);
  gemm_qkv_k<<<GB, 256, 0, stream>>>(sv_f, h_f, Wq_cv, Wk_cv, Wv_cv, Q2, KV2, N);
  attn2_k<<<AB, 256, 0, stream>>>(Q1, (const uint4*)KV1, Q2, (const uint4*)KV2, row_off, esrc, cat_sv, N);

  // ---- h branch ----
  gemm_k<256,128,3,128><<<GB, 256, 0, stream>>>(cat_h, Wob, bo, nullptr, h, nullptr, Xb, nullptr, N);
  bn_stats_k<<<SB, 256, 0, stream>>>(Xb, stats, N);
  bn_apply_k<<<APB, 256, 0, stream>>>((const float4*)Xb, stats, gbn1, bbn1, (float4*)Rb, h1b, T4, invN);
  gemm_k<128,256,1,128><<<GB, 256, 0, stream>>>(h1b, W1b, b1, nullptr, nullptr, nullptr, nullptr, cat_h, N);
  gemm_k<256,128,3,128><<<GB, 256, 0, stream>>>(cat_h, W2b, b2, nullptr, Rb, nullptr, Xb, nullptr, N);
  bn_stats_k<<<SB, 256, 0, stream>>>(Xb, stats + 256, N);
  bn_apply_k<<<APB, 256, 0, stream>>>((const float4*)Xb, stats + 256, gbn2, bbn2, (float4*)out_h, nullptr, T4, invN);

  // ---- sv branch ----
  gemm_k<128,256,2,128><<<GB, 256, 0, stream>>>(h_f, Wgb, bg1, bg2, nullptr, nullptr, Gb, nullptr, N);
  gemm_k<256,128,4,256><<<GB, 256, 0, stream>>>(cat_sv, Wohb, bo_h, nullptr, sv, Gb, Xb, nullptr, N);
  bn_stats_k<<<SB, 256, 0, stream>>>(Xb, stats + 512, N);
  bn_apply_k<<<APB, 256, 0, stream>>>((const float4*)Xb, stats + 512, gbn1h, bbn1h, (float4*)Rb, sv1b, T4, invN);
  gemm_k<128,256,1,128><<<GB, 256, 0, stream>>>(sv1b, W1hb, b1h, nullptr, nullptr, nullptr, nullptr, cat_sv, N);
  gemm_k<128,128,2,128><<<GB, 256, 0, stream>>>(h_f, Wgb, bg1, nullptr, nullptr, nullptr, nullptr, nullptr, 0); // no-op guard (never executed rows)
  gemm_k<256,128,4,256><<<GB, 256, 0, stream>>>(cat_sv, W2hb, b2h, nullptr, Rb, Gb + 128, Xb, nullptr, N);
  bn_stats_k<<<SB, 256, 0, stream>>>(Xb, stats + 768, N);
  bn_apply_k<<<APB, 256, 0, stream>>>((const float4*)Xb, stats + 768, gbn2h, bbn2h, (float4*)out_sv, nullptr, T4, invN);
}

// Round 4
// 1342.685 us; speedup vs baseline: 1.2066x; 1.1770x over previous
//
#include <hip/hip_runtime.h>

typedef _Float16 f16x8 __attribute__((ext_vector_type(8)));
typedef _Float16 f16x2 __attribute__((ext_vector_type(2)));
typedef __fp16 fp16x2_raw __attribute__((ext_vector_type(2)));
typedef float f32x4 __attribute__((ext_vector_type(4)));
typedef unsigned int uint32;
typedef unsigned short ushort16;

#define EPS_BN 1e-5f

__device__ __forceinline__ uint32 pk16(float a, float b){
  fp16x2_raw h = __builtin_amdgcn_cvt_pkrtz(a, b);
  return *(uint32*)&h;
}
__device__ __forceinline__ ushort16 f2h(float f){
  _Float16 h = (_Float16)f;
  union { _Float16 h; ushort16 u; } c; c.h = h; return c.u;
}

#if __has_builtin(__builtin_amdgcn_fdot2)
__device__ __forceinline__ float fdot2f(f16x2 a, f16x2 b, float c){
  return __builtin_amdgcn_fdot2(*(fp16x2_raw*)&a, *(fp16x2_raw*)&b, c, false);
}
#else
__device__ __forceinline__ float fdot2f(f16x2 a, f16x2 b, float c){
  return fmaf((float)a.x, (float)b.x, fmaf((float)a.y, (float)b.y, c));
}
#endif

// ---------------- weight conversion: f32 row-major -> f16 MFMA-fragment-linear ----------------
// Fragment (s, m, lane) holds W[row=m*16+(lane&15)][k=s*32+(lane>>4)*8 .. +7],
// stored contiguously at dst + ((s*MT+m)*64+lane)*8. B-loads in GEMMs become
// coalesced wave-uniform streams.
struct WEnt { const float* s; const float* s2; ushort16* d; int KD, MD, nfrag; };
struct WConv { WEnt e[16]; };

__global__ __launch_bounds__(256) void conv_w_k(WConv a){
  WEnt t = a.e[blockIdx.y];
  int fid = blockIdx.x * 256 + threadIdx.x;
  if (fid >= t.nfrag) return;
  int lane = fid & 63, sm = fid >> 6;
  int MT = t.MD >> 4;
  int s = sm / MT, m = sm - s * MT;
  int row = m * 16 + (lane & 15);
  int col = s * 32 + (lane >> 4) * 8;
  const float* sp = t.s;
  if (t.s2 && row >= 128){ sp = t.s2; row -= 128; }
  const float* p = sp + (size_t)row * t.KD + col;
  uint4 o;
  o.x = pk16(p[0], p[1]); o.y = pk16(p[2], p[3]);
  o.z = pk16(p[4], p[5]); o.w = pk16(p[6], p[7]);
  *(uint4*)(t.d + (size_t)fid * 8) = o;
}

__global__ __launch_bounds__(256) void conv2_k(const float* __restrict__ a, const float* __restrict__ b,
                                               ushort16* __restrict__ da, ushort16* __restrict__ db, int n){
  const float* s = blockIdx.y ? b : a;
  ushort16* d = blockIdx.y ? db : da;
  int i = (blockIdx.x * 256 + threadIdx.x) * 4;
  if (i >= n) return;
  float4 v = *(const float4*)(s + i);
  uint2 p;
  p.x = pk16(v.x, v.y);
  p.y = pk16(v.z, v.w);
  *(uint2*)(d + i) = p;
}

// ---------------- CSR build ----------------
__global__ void hist_k(const int* __restrict__ dst, int* __restrict__ cnt, int E){
  int i = blockIdx.x * blockDim.x + threadIdx.x;
  int stride = gridDim.x * blockDim.x;
  for (; i < E; i += stride) atomicAdd(&cnt[dst[i]], 1);
}

__global__ __launch_bounds__(1024) void scan_k(const int* __restrict__ cnt, int* __restrict__ row_off,
                                               int* __restrict__ cursor, int N){
  __shared__ int wsum[17];
  int tid = threadIdx.x;
  int lane = tid & 63, wv = tid >> 6;
  int base = 0;
  for (int c0 = 0; c0 < N; c0 += 1024){
    int i = c0 + tid;
    int v = (i < N) ? cnt[i] : 0;
    int inc = v;
    #pragma unroll
    for (int d = 1; d < 64; d <<= 1){
      int t = __shfl_up(inc, d);
      if (lane >= d) inc += t;
    }
    if (lane == 63) wsum[wv] = inc;
    __syncthreads();
    if (tid == 0){
      int run = 0;
      for (int w = 0; w < 16; w++){ int t = wsum[w]; wsum[w] = run; run += t; }
      wsum[16] = run;
    }
    __syncthreads();
    int excl = base + wsum[wv] + inc - v;
    if (i < N){ row_off[i] = excl; cursor[i] = excl; }
    base += wsum[16];
    __syncthreads();
  }
  if (tid == 0) row_off[N] = base;
}

__global__ void fill_k(const int* __restrict__ src, const int* __restrict__ dst,
                       int* __restrict__ cursor, int* __restrict__ esrc, int E){
  int i = blockIdx.x * blockDim.x + threadIdx.x;
  int stride = gridDim.x * blockDim.x;
  for (; i < E; i += stride){
    int d = dst[i];
    int p = atomicAdd(&cursor[d], 1);
    esrc[p] = src[i];
  }
}

// ---------------- fused QKV projection (f16 MFMA, swizzled weights) ----------------
__global__ __launch_bounds__(256) void gemm_qkv_k(
    const ushort16* __restrict__ Xq, const ushort16* __restrict__ Xkv,
    const ushort16* __restrict__ Wq, const ushort16* __restrict__ Wk, const ushort16* __restrict__ Wv,
    ushort16* __restrict__ Qo, ushort16* __restrict__ KVo, int N)
{
  int lane = threadIdx.x & 63, wv = threadIdx.x >> 6;
  int l15 = lane & 15, kq = lane >> 4;
  int rowbase = (blockIdx.x * 4 + wv) * 16;
  int row = rowbase + l15;
  int rc = row < N ? row : N - 1;
  const f16x8* aq = (const f16x8*)(Xq + (size_t)rc * 128 + kq * 8);
  const f16x8* ak = (const f16x8*)(Xkv + (size_t)rc * 128 + kq * 8);
  f16x8 Aq[4], Ak[4];
  #pragma unroll
  for (int s = 0; s < 4; s++){ Aq[s] = aq[s * 4]; Ak[s] = ak[s * 4]; }
  const f16x8* Wqf = (const f16x8*)Wq;
  const f16x8* Wkf = (const f16x8*)Wk;
  const f16x8* Wvf = (const f16x8*)Wv;
  f32x4 q[8], k[8], v[8];
  #pragma unroll
  for (int m = 0; m < 8; m++){ q[m] = (f32x4)(0.f); k[m] = (f32x4)(0.f); v[m] = (f32x4)(0.f); }
  #pragma unroll
  for (int s = 0; s < 4; s++){
    #pragma unroll
    for (int m = 0; m < 8; m++){
      int fi = (s * 8 + m) * 64 + lane;
      q[m] = __builtin_amdgcn_mfma_f32_16x16x32_f16(Aq[s], Wqf[fi], q[m], 0, 0, 0);
      k[m] = __builtin_amdgcn_mfma_f32_16x16x32_f16(Ak[s], Wkf[fi], k[m], 0, 0, 0);
      v[m] = __builtin_amdgcn_mfma_f32_16x16x32_f16(Ak[s], Wvf[fi], v[m], 0, 0, 0);
    }
  }
  int r0 = rowbase + kq * 4;
  #pragma unroll
  for (int m = 0; m < 8; m++){
    int col = m * 16 + l15;
    int kvcol = (col >> 2) * 8 + (col & 3);
    #pragma unroll
    for (int r = 0; r < 4; r++){
      int rr = r0 + r;
      if (rr < N){
        Qo[(size_t)rr * 128 + col] = f2h(q[m][r]);
        size_t kvbase = (size_t)rr * 256 + kvcol;
        KVo[kvbase]     = f2h(k[m][r]);
        KVo[kvbase + 4] = f2h(v[m][r]);
      }
    }
  }
}

// ---------------- generic GEMM: C = epi(X[NxKD] * W[MDxKD]^T + bias), swizzled W ----------------
// EPI: 1=relu->f16, 2=sigmoid->f32, 3=+res->f32, 4=gate: (1-g)*res+g*v ->f32
template<int KD, int MD, int EPI, int GS>
__global__ __launch_bounds__(256) void gemm_k(
    const ushort16* __restrict__ X, const ushort16* __restrict__ W,
    const float* __restrict__ bias, const float* __restrict__ bias2,
    const float* __restrict__ res, const float* __restrict__ gate,
    float* __restrict__ outf, ushort16* __restrict__ outb, int N)
{
  constexpr int KS = KD / 32;
  constexpr int MT = MD / 16;
  int lane = threadIdx.x & 63, wv = threadIdx.x >> 6;
  int l15 = lane & 15, kq = lane >> 4;
  int rowbase = (blockIdx.x * 4 + wv) * 16;
  int row = rowbase + l15;
  int rc = row < N ? row : N - 1;
  const f16x8* ap = (const f16x8*)(X + (size_t)rc * KD + kq * 8);
  f16x8 a[KS];
  #pragma unroll
  for (int s = 0; s < KS; s++) a[s] = ap[s * 4];
  const f16x8* Wf = (const f16x8*)W;
  f32x4 acc[MT];
  #pragma unroll
  for (int m = 0; m < MT; m++) acc[m] = (f32x4)(0.f);
  #pragma unroll
  for (int s = 0; s < KS; s++){
    #pragma unroll
    for (int m = 0; m < MT; m++){
      acc[m] = __builtin_amdgcn_mfma_f32_16x16x32_f16(a[s], Wf[(s * MT + m) * 64 + lane], acc[m], 0, 0, 0);
    }
  }
  int r0 = rowbase + kq * 4;
  #pragma unroll
  for (int m = 0; m < MT; m++){
    int col = m * 16 + l15;
    float bv;
    if (bias2 && col >= 128) bv = bias2[col - 128];
    else bv = bias ? bias[col] : 0.f;
    #pragma unroll
    for (int r = 0; r < 4; r++){
      int rr = r0 + r;
      if (rr < N){
        float v = acc[m][r] + bv;
        if constexpr (EPI == 1) v = fmaxf(v, 0.f);
        if constexpr (EPI == 2) v = 1.f / (1.f + __expf(-v));
        if constexpr (EPI == 3) v += res[(size_t)rr * MD + col];
        if constexpr (EPI == 4){
          float g = gate[(size_t)rr * GS + col];
          float rv = res[(size_t)rr * MD + col];
          v = (1.f - g) * rv + g * v;
        }
        if (outf) outf[(size_t)rr * MD + col] = v;
        if (outb) outb[(size_t)rr * MD + col] = f2h(v);
      }
    }
  }
}

// ---------------- fused dual-attention (self+cross for one cat buffer) ----------------
__global__ __launch_bounds__(256) void attn2_k(
    const ushort16* __restrict__ Qa, const uint4* __restrict__ KVa,
    const ushort16* __restrict__ Qb, const uint4* __restrict__ KVb,
    const int* __restrict__ row_off, const int* __restrict__ esrc,
    ushort16* __restrict__ cat, int N)
{
  int wv = threadIdx.x >> 6, lane = threadIdx.x & 63;
  int n = blockIdx.x * 4 + wv;
  if (n >= N) return;
  int h = lane >> 5, j = lane & 31;
  uint2 qau = *(const uint2*)(Qa + (size_t)n * 128 + j * 4);
  uint2 qbu = *(const uint2*)(Qb + (size_t)n * 128 + j * 4);
  f16x2 qa01 = *(f16x2*)&qau.x, qa23 = *(f16x2*)&qau.y;
  f16x2 qb01 = *(f16x2*)&qbu.x, qb23 = *(f16x2*)&qbu.y;
  int e0 = row_off[n], e1 = row_off[n + 1];
  int deg = e1 - e0;
  int itmax = (deg + 1) >> 1;
  float a0 = 0.f, a1 = 0.f, a2 = 0.f, a3 = 0.f, za = 0.f;
  float b0 = 0.f, b1 = 0.f, b2 = 0.f, b3 = 0.f, zb = 0.f;
  int e = e0 + h;
  int s = (e < e1) ? esrc[e] : -1;
  int sc = s < 0 ? 0 : s;
  uint4 ka = KVa[(size_t)sc * 32 + j];
  uint4 kb = KVb[(size_t)sc * 32 + j];
  for (int it = 0; it < itmax; ++it){
    int e2 = e + 2;
    int s2 = (e2 < e1) ? esrc[e2] : -1;
    int s2c = s2 < 0 ? 0 : s2;
    uint4 ka2 = KVa[(size_t)s2c * 32 + j];
    uint4 kb2 = KVb[(size_t)s2c * 32 + j];
    if (s >= 0){
      float da = fdot2f(*(f16x2*)&ka.x, qa01, fdot2f(*(f16x2*)&ka.y, qa23, 0.f));
      float db = fdot2f(*(f16x2*)&kb.x, qb01, fdot2f(*(f16x2*)&kb.y, qb23, 0.f));
      da += __shfl_xor(da, 1); da += __shfl_xor(da, 2);
      db += __shfl_xor(db, 1); db += __shfl_xor(db, 2);
      float sa = __expf(fminf(fmaxf(da * 0.25f, -5.f), 5.f));
      float sb = __expf(fminf(fmaxf(db * 0.25f, -5.f), 5.f));
      f16x2 va01 = *(f16x2*)&ka.z, va23 = *(f16x2*)&ka.w;
      f16x2 vb01 = *(f16x2*)&kb.z, vb23 = *(f16x2*)&kb.w;
      a0 = fmaf(sa, (float)va01.x, a0); a1 = fmaf(sa, (float)va01.y, a1);
      a2 = fmaf(sa, (float)va23.x, a2); a3 = fmaf(sa, (float)va23.y, a3);
      za += sa;
      b0 = fmaf(sb, (float)vb01.x, b0); b1 = fmaf(sb, (float)vb01.y, b1);
      b2 = fmaf(sb, (float)vb23.x, b2); b3 = fmaf(sb, (float)vb23.y, b3);
      zb += sb;
    }
    e = e2; s = s2; ka = ka2; kb = kb2;
  }
  a0 += __shfl_xor(a0, 32); a1 += __shfl_xor(a1, 32);
  a2 += __shfl_xor(a2, 32); a3 += __shfl_xor(a3, 32);
  za += __shfl_xor(za, 32);
  b0 += __shfl_xor(b0, 32); b1 += __shfl_xor(b1, 32);
  b2 += __shfl_xor(b2, 32); b3 += __shfl_xor(b3, 32);
  zb += __shfl_xor(zb, 32);
  uint2 o;
  if (h == 0){
    float rz = __builtin_amdgcn_rcpf(za);
    o.x = pk16(a0 * rz, a1 * rz);
    o.y = pk16(a2 * rz, a3 * rz);
    *(uint2*)(cat + (size_t)n * 256 + j * 4) = o;
  } else {
    float rz = __builtin_amdgcn_rcpf(zb);
    o.x = pk16(b0 * rz, b1 * rz);
    o.y = pk16(b2 * rz, b3 * rz);
    *(uint2*)(cat + (size_t)n * 256 + 128 + j * 4) = o;
  }
}

// ---------------- BatchNorm ----------------
__global__ __launch_bounds__(256) void bn_stats_k(const float* __restrict__ x, float* __restrict__ stats, int N){
  int col = threadIdx.x & 127;
  int half = threadIdx.x >> 7;
  int r0 = blockIdx.x * 128;
  int rend = r0 + 128 < N ? r0 + 128 : N;
  float s = 0.f, s2 = 0.f;
  for (int r = r0 + half; r < rend; r += 2){
    float v = x[(size_t)r * 128 + col];
    s += v; s2 += v * v;
  }
  __shared__ float ls[256], ls2[256];
  ls[threadIdx.x] = s; ls2[threadIdx.x] = s2;
  __syncthreads();
  if (threadIdx.x < 128){
    atomicAdd(&stats[col], ls[threadIdx.x] + ls[threadIdx.x + 128]);
    atomicAdd(&stats[128 + col], ls2[threadIdx.x] + ls2[threadIdx.x + 128]);
  }
}

__global__ __launch_bounds__(256) void bn_apply_k(
    const float4* __restrict__ x, const float* __restrict__ stats,
    const float* __restrict__ gamma, const float* __restrict__ beta,
    float4* __restrict__ outf, ushort16* __restrict__ outb, int total4, float invN)
{
  int i = blockIdx.x * 256 + threadIdx.x;
  if (i >= total4) return;
  float4 v = x[i];
  int c0 = (i * 4) & 127;
  float o[4];
  float xv[4] = {v.x, v.y, v.z, v.w};
  #pragma unroll
  for (int j = 0; j < 4; j++){
    int c = c0 + j;
    float m = stats[c] * invN;
    float var = stats[128 + c] * invN - m * m;
    float rstd = rsqrtf(var + EPS_BN);
    o[j] = (xv[j] - m) * rstd * gamma[c] + beta[c];
  }
  outf[i] = make_float4(o[0], o[1], o[2], o[3]);
  if (outb){
    uint2 p;
    p.x = pk16(o[0], o[1]);
    p.y = pk16(o[2], o[3]);
    *(uint2*)(outb + (size_t)i * 4) = p;
  }
}

// ---------------- host ----------------
extern "C" void kernel_launch(void* const* d_in, const int* in_sizes, int n_in,
                              void* d_out, int out_size, void* d_ws, size_t ws_size,
                              hipStream_t stream) {
  const float* h   = (const float*)d_in[0];
  const float* sv  = (const float*)d_in[1];
  const int* src   = (const int*)d_in[2];
  const int* dst   = (const int*)d_in[3];
  const int N = in_sizes[0] / 128;
  const int E = in_sizes[2];

  char* wsb = (char*)d_ws;
  size_t o = 0;
  auto take = [&](size_t bytes)->size_t{
    size_t r = o;
    o = (o + bytes + 255) & ~(size_t)255;
    return r;
  };
  size_t cnt_off    = take((size_t)N * 4);
  size_t stats_off  = take(4 * 256 * 4);
  size_t rowoff_off = take((size_t)(N + 1) * 4);
  size_t cursor_off = take((size_t)N * 4);
  size_t esrc_off   = take((size_t)E * 4);
  size_t wpool_off  = take((size_t)376832 * 2);
  size_t hf_off     = take((size_t)N * 128 * 2);
  size_t svf_off    = take((size_t)N * 128 * 2);
  size_t cath_off   = take((size_t)N * 256 * 2);
  size_t catsv_off  = take((size_t)N * 256 * 2);
  size_t X_off      = take((size_t)N * 128 * 4);   // also KV1 (N*256 f16 = same bytes)
  size_t R_off      = take((size_t)N * 128 * 4);   // also KV2
  size_t G_off      = take((size_t)N * 256 * 4);   // gates f32 N x 256; also Q1/Q2 f16
  size_t h1_off     = take((size_t)N * 128 * 2);
  size_t sv1_off    = take((size_t)N * 128 * 2);

  int*    cnt     = (int*)(wsb + cnt_off);
  float*  stats   = (float*)(wsb + stats_off);
  int*    row_off = (int*)(wsb + rowoff_off);
  int*    cursor  = (int*)(wsb + cursor_off);
  int*    esrc    = (int*)(wsb + esrc_off);
  ushort16* wpool = (ushort16*)(wsb + wpool_off);
  ushort16* h_f   = (ushort16*)(wsb + hf_off);
  ushort16* sv_f  = (ushort16*)(wsb + svf_off);
  ushort16* cat_h = (ushort16*)(wsb + cath_off);
  ushort16* cat_sv= (ushort16*)(wsb + catsv_off);
  float*  Xb      = (float*)(wsb + X_off);
  float*  Rb      = (float*)(wsb + R_off);
  float*  Gb      = (float*)(wsb + G_off);
  ushort16* h1b   = (ushort16*)(wsb + h1_off);
  ushort16* sv1b  = (ushort16*)(wsb + sv1_off);

  // attention staging overlays (used strictly before Xb/Rb/Gb are written)
  ushort16* KV1 = (ushort16*)(wsb + X_off);
  ushort16* KV2 = (ushort16*)(wsb + R_off);
  ushort16* Q1  = (ushort16*)(wsb + G_off);
  ushort16* Q2  = (ushort16*)(wsb + G_off + (size_t)N * 128 * 2);

  // f16 swizzled weight pool offsets (elements)
  ushort16* Wq_sv = wpool + 0 * 16384;
  ushort16* Wk_sv = wpool + 1 * 16384;
  ushort16* Wv_sv = wpool + 2 * 16384;
  ushort16* Wq_cv = wpool + 3 * 16384;
  ushort16* Wk_cv = wpool + 4 * 16384;
  ushort16* Wv_cv = wpool + 5 * 16384;
  ushort16* Wq_sh = wpool + 6 * 16384;
  ushort16* Wk_sh = wpool + 7 * 16384;
  ushort16* Wv_sh = wpool + 8 * 16384;
  ushort16* Wgb   = wpool + 147456;   // [Wg1;Wg2] stacked 256x128
  ushort16* Wob   = wpool + 180224;
  ushort16* Wohb  = wpool + 212992;
  ushort16* W1b   = wpool + 245760;
  ushort16* W2b   = wpool + 278528;
  ushort16* W1hb  = wpool + 311296;
  ushort16* W2hb  = wpool + 344064;

  const float* bo   = (const float*)d_in[14];
  const float* bo_h = (const float*)d_in[16];
  const float* b1   = (const float*)d_in[18];
  const float* b2   = (const float*)d_in[20];
  const float* b1h  = (const float*)d_in[22];
  const float* b2h  = (const float*)d_in[24];
  const float* bg1  = (const float*)d_in[26];
  const float* bg2  = (const float*)d_in[28];
  const float* gbn1  = (const float*)d_in[29];
  const float* bbn1  = (const float*)d_in[30];
  const float* gbn2  = (const float*)d_in[31];
  const float* bbn2  = (const float*)d_in[32];
  const float* gbn1h = (const float*)d_in[33];
  const float* bbn1h = (const float*)d_in[34];
  const float* gbn2h = (const float*)d_in[35];
  const float* bbn2h = (const float*)d_in[36];

  float* out_h  = (float*)d_out;
  float* out_sv = out_h + (size_t)N * 128;

  hipMemsetAsync(wsb, 0, stats_off + 4 * 256 * 4, stream);

  // weight conversion (fragment-linear swizzle)
  WConv wc;
  {
    auto set = [&](int i, int din, int din2, size_t dstoff, int KD, int MD){
      wc.e[i].s  = (const float*)d_in[din];
      wc.e[i].s2 = (din2 >= 0) ? (const float*)d_in[din2] : nullptr;
      wc.e[i].d  = wpool + dstoff;
      wc.e[i].KD = KD; wc.e[i].MD = MD;
      wc.e[i].nfrag = KD * MD / 8;
    };
    for (int i = 0; i < 9; i++) set(i, 4 + i, -1, (size_t)i * 16384, 128, 128);
    set(9,  25, 27, 147456, 128, 256);  // [Wg1;Wg2]
    set(10, 13, -1, 180224, 256, 128);  // Wo
    set(11, 15, -1, 212992, 256, 128);  // Wo_h
    set(12, 17, -1, 245760, 128, 256);  // W1
    set(13, 19, -1, 278528, 256, 128);  // W2
    set(14, 21, -1, 311296, 128, 256);  // W1h
    set(15, 23, -1, 344064, 256, 128);  // W2h
  }
  conv_w_k<<<dim3(16, 16), 256, 0, stream>>>(wc);

  int nelem = N * 128;
  conv2_k<<<dim3((nelem / 4 + 255) / 256, 2), 256, 0, stream>>>(h, sv, h_f, sv_f, nelem);

  hist_k<<<2048, 256, 0, stream>>>(dst, cnt, E);
  scan_k<<<1, 1024, 0, stream>>>(cnt, row_off, cursor, N);
  fill_k<<<2048, 256, 0, stream>>>(src, dst, cursor, esrc, E);

  const int GB = (N + 63) / 64;
  const int AB = (N + 3) / 4;
  const int SB = (N + 127) / 128;
  const int T4 = nelem / 4;
  const int APB = (T4 + 255) / 256;
  const float invN = 1.f / (float)N;

  // h-branch attention pair: self(h) + cross(h; sv)
  gemm_qkv_k<<<GB, 256, 0, stream>>>(h_f, h_f, Wq_sv, Wk_sv, Wv_sv, Q1, KV1, N);
  gemm_qkv_k<<<GB, 256, 0, stream>>>(h_f, sv_f, Wq_cv, Wk_cv, Wv_cv, Q2, KV2, N);
  attn2_k<<<AB, 256, 0, stream>>>(Q1, (const uint4*)KV1, Q2, (const uint4*)KV2, row_off, esrc, cat_h, N);
  // sv-branch attention pair: self(sv) + cross(sv; h)
  gemm_qkv_k<<<GB, 256, 0, stream>>>(sv_f, sv_f, Wq_sh, Wk_sh, Wv_sh, Q1, KV1, N);
  gemm_qkv_k<<<GB, 256, 0, stream>>>(sv_f, h_f, Wq_cv, Wk_cv, Wv_cv, Q2, KV2, N);
  attn2_k<<<AB, 256, 0, stream>>>(Q1, (const uint4*)KV1, Q2, (const uint4*)KV2, row_off, esrc, cat_sv, N);

  // ---- h branch ----
  gemm_k<256,128,3,128><<<GB, 256, 0, stream>>>(cat_h, Wob, bo, nullptr, h, nullptr, Xb, nullptr, N);
  bn_stats_k<<<SB, 256, 0, stream>>>(Xb, stats, N);
  bn_apply_k<<<APB, 256, 0, stream>>>((const float4*)Xb, stats, gbn1, bbn1, (float4*)Rb, h1b, T4, invN);
  gemm_k<128,256,1,128><<<GB, 256, 0, stream>>>(h1b, W1b, b1, nullptr, nullptr, nullptr, nullptr, cat_h, N);
  gemm_k<256,128,3,128><<<GB, 256, 0, stream>>>(cat_h, W2b, b2, nullptr, Rb, nullptr, Xb, nullptr, N);
  bn_stats_k<<<SB, 256, 0, stream>>>(Xb, stats + 256, N);
  bn_apply_k<<<APB, 256, 0, stream>>>((const float4*)Xb, stats + 256, gbn2, bbn2, (float4*)out_h, nullptr, T4, invN);

  // ---- sv branch ----
  gemm_k<128,256,2,128><<<GB, 256, 0, stream>>>(h_f, Wgb, bg1, bg2, nullptr, nullptr, Gb, nullptr, N);
  gemm_k<256,128,4,256><<<GB, 256, 0, stream>>>(cat_sv, Wohb, bo_h, nullptr, sv, Gb, Xb, nullptr, N);
  bn_stats_k<<<SB, 256, 0, stream>>>(Xb, stats + 512, N);
  bn_apply_k<<<APB, 256, 0, stream>>>((const float4*)Xb, stats + 512, gbn1h, bbn1h, (float4*)Rb, sv1b, T4, invN);
  gemm_k<128,256,1,128><<<GB, 256, 0, stream>>>(sv1b, W1hb, b1h, nullptr, nullptr, nullptr, nullptr, cat_sv, N);
  gemm_k<256,128,4,256><<<GB, 256, 0, stream>>>(cat_sv, W2hb, b2h, nullptr, Rb, Gb + 128, Xb, nullptr, N);
  bn_stats_k<<<SB, 256, 0, stream>>>(Xb, stats + 768, N);
  bn_apply_k<<<APB, 256, 0, stream>>>((const float4*)Xb, stats + 768, gbn2h, bbn2h, (float4*)out_sv, nullptr, T4, invN);
}

// Round 6
// 1164.477 us; speedup vs baseline: 1.3912x; 1.1530x over previous
//
#include <hip/hip_runtime.h>

typedef _Float16 f16x8 __attribute__((ext_vector_type(8)));
typedef _Float16 f16x2 __attribute__((ext_vector_type(2)));
typedef __fp16 fp16x2_raw __attribute__((ext_vector_type(2)));
typedef float f32x4 __attribute__((ext_vector_type(4)));
typedef float f32x2 __attribute__((ext_vector_type(2)));
typedef unsigned int uint32;
typedef unsigned short ushort16;

#define EPS_BN 1e-5f

__device__ __forceinline__ uint32 pk16(float a, float b){
  fp16x2_raw h = __builtin_amdgcn_cvt_pkrtz(a, b);
  return *(uint32*)&h;
}
__device__ __forceinline__ ushort16 f2h(float f){
  _Float16 h = (_Float16)f;
  union { _Float16 h; ushort16 u; } c; c.h = h; return c.u;
}
__device__ __forceinline__ unsigned char f2fp8(float f){
  uint32 p = __builtin_amdgcn_cvt_pk_fp8_f32(f, f, 0, false);
  return (unsigned char)(p & 0xff);
}
__device__ __forceinline__ f32x2 fp8pair_lo(uint32 w){
  return __builtin_amdgcn_cvt_pk_f32_fp8(w, false);
}
__device__ __forceinline__ f32x2 fp8pair_hi(uint32 w){
  return __builtin_amdgcn_cvt_pk_f32_fp8(w, true);
}

// ---------------- weight conversion: f32 row-major -> f16 MFMA-fragment-linear ----------------
struct WEnt { const float* s; const float* s2; ushort16* d; int KD, MD, nfrag; };
struct WConv { WEnt e[16]; };

__global__ __launch_bounds__(256) void conv_w_k(WConv a){
  WEnt t = a.e[blockIdx.y];
  int fid = blockIdx.x * 256 + threadIdx.x;
  if (fid >= t.nfrag) return;
  int lane = fid & 63, sm = fid >> 6;
  int MT = t.MD >> 4;
  int s = sm / MT, m = sm - s * MT;
  int row = m * 16 + (lane & 15);
  int col = s * 32 + (lane >> 4) * 8;
  const float* sp = t.s;
  if (t.s2 && row >= 128){ sp = t.s2; row -= 128; }
  const float* p = sp + (size_t)row * t.KD + col;
  uint4 o;
  o.x = pk16(p[0], p[1]); o.y = pk16(p[2], p[3]);
  o.z = pk16(p[4], p[5]); o.w = pk16(p[6], p[7]);
  *(uint4*)(t.d + (size_t)fid * 8) = o;
}

__global__ __launch_bounds__(256) void conv2_k(const float* __restrict__ a, const float* __restrict__ b,
                                               ushort16* __restrict__ da, ushort16* __restrict__ db, int n){
  const float* s = blockIdx.y ? b : a;
  ushort16* d = blockIdx.y ? db : da;
  int i = (blockIdx.x * 256 + threadIdx.x) * 4;
  if (i >= n) return;
  float4 v = *(const float4*)(s + i);
  uint2 p;
  p.x = pk16(v.x, v.y);
  p.y = pk16(v.z, v.w);
  *(uint2*)(d + i) = p;
}

// ---------------- CSR build ----------------
__global__ void hist_k(const int* __restrict__ dst, int* __restrict__ cnt, int E){
  int i = blockIdx.x * blockDim.x + threadIdx.x;
  int stride = gridDim.x * blockDim.x;
  for (; i < E; i += stride) atomicAdd(&cnt[dst[i]], 1);
}

// parallel scan: stage 1 = per-block (1024 elems) totals
__global__ __launch_bounds__(256) void scan_part_k(const int* __restrict__ cnt, int* __restrict__ bsum, int N){
  int tid = threadIdx.x, lane = tid & 63, wv = tid >> 6;
  int base = blockIdx.x * 1024 + tid * 4;
  int ts = 0;
  #pragma unroll
  for (int j = 0; j < 4; j++) if (base + j < N) ts += cnt[base + j];
  #pragma unroll
  for (int d = 1; d < 64; d <<= 1) ts += __shfl_xor(ts, d);
  __shared__ int wt[4];
  if (lane == 0) wt[wv] = ts;
  __syncthreads();
  if (tid == 0) bsum[blockIdx.x] = wt[0] + wt[1] + wt[2] + wt[3];
}

// stage 2: exclusive scan of block totals (<=64 blocks)
__global__ __launch_bounds__(64) void scan_top_k(int* __restrict__ bsum, int nb){
  int tid = threadIdx.x;
  int v = (tid < nb) ? bsum[tid] : 0;
  int inc = v;
  #pragma unroll
  for (int d = 1; d < 64; d <<= 1){
    int t = __shfl_up(inc, d);
    if (tid >= d) inc += t;
  }
  if (tid < nb) bsum[tid] = inc - v;
}

// stage 3: write row_off/cursor
__global__ __launch_bounds__(256) void scan_out_k(const int* __restrict__ cnt, const int* __restrict__ bsum,
                                                  int* __restrict__ row_off, int* __restrict__ cursor,
                                                  int N, int E){
  int tid = threadIdx.x, lane = tid & 63, wv = tid >> 6;
  int base = blockIdx.x * 1024 + tid * 4;
  int c[4]; int ts = 0;
  #pragma unroll
  for (int j = 0; j < 4; j++){ c[j] = (base + j < N) ? cnt[base + j] : 0; ts += c[j]; }
  int inc = ts;
  #pragma unroll
  for (int d = 1; d < 64; d <<= 1){
    int t = __shfl_up(inc, d);
    if (lane >= d) inc += t;
  }
  int wexcl = inc - ts;
  __shared__ int wt[4];
  if (lane == 63) wt[wv] = inc;
  __syncthreads();
  int woff = 0;
  for (int w = 0; w < 4; w++) if (w < wv) woff += wt[w];
  int off = bsum[blockIdx.x] + woff + wexcl;
  #pragma unroll
  for (int j = 0; j < 4; j++){
    if (base + j < N){ row_off[base + j] = off; cursor[base + j] = off; off += c[j]; }
  }
  if (blockIdx.x == 0 && tid == 0) row_off[N] = E;
}

__global__ void fill_k(const int* __restrict__ src, const int* __restrict__ dst,
                       int* __restrict__ cursor, int* __restrict__ esrc, int E){
  int i = blockIdx.x * blockDim.x + threadIdx.x;
  int stride = gridDim.x * blockDim.x;
  for (; i < E; i += stride){
    int d = dst[i];
    int p = atomicAdd(&cursor[d], 1);
    esrc[p] = src[i];
  }
}

// ---------------- fused QKV projection (f16 MFMA, swizzled weights) ----------------
// Q: f16 row-major; K: fp8-e4m3 row-major (128 B/row); V: f16 row-major (256 B/row)
__global__ __launch_bounds__(256) void gemm_qkv_k(
    const ushort16* __restrict__ Xq, const ushort16* __restrict__ Xkv,
    const ushort16* __restrict__ Wq, const ushort16* __restrict__ Wk, const ushort16* __restrict__ Wv,
    ushort16* __restrict__ Qo, unsigned char* __restrict__ K8, ushort16* __restrict__ V16, int N)
{
  int lane = threadIdx.x & 63, wv = threadIdx.x >> 6;
  int l15 = lane & 15, kq = lane >> 4;
  int rowbase = (blockIdx.x * 4 + wv) * 16;
  int row = rowbase + l15;
  int rc = row < N ? row : N - 1;
  const f16x8* aq = (const f16x8*)(Xq + (size_t)rc * 128 + kq * 8);
  const f16x8* ak = (const f16x8*)(Xkv + (size_t)rc * 128 + kq * 8);
  f16x8 Aq[4], Ak[4];
  #pragma unroll
  for (int s = 0; s < 4; s++){ Aq[s] = aq[s * 4]; Ak[s] = ak[s * 4]; }
  const f16x8* Wqf = (const f16x8*)Wq;
  const f16x8* Wkf = (const f16x8*)Wk;
  const f16x8* Wvf = (const f16x8*)Wv;
  f32x4 q[8], k[8], v[8];
  #pragma unroll
  for (int m = 0; m < 8; m++){ q[m] = (f32x4)(0.f); k[m] = (f32x4)(0.f); v[m] = (f32x4)(0.f); }
  #pragma unroll
  for (int s = 0; s < 4; s++){
    #pragma unroll
    for (int m = 0; m < 8; m++){
      int fi = (s * 8 + m) * 64 + lane;
      q[m] = __builtin_amdgcn_mfma_f32_16x16x32_f16(Aq[s], Wqf[fi], q[m], 0, 0, 0);
      k[m] = __builtin_amdgcn_mfma_f32_16x16x32_f16(Ak[s], Wkf[fi], k[m], 0, 0, 0);
      v[m] = __builtin_amdgcn_mfma_f32_16x16x32_f16(Ak[s], Wvf[fi], v[m], 0, 0, 0);
    }
  }
  int r0 = rowbase + kq * 4;
  #pragma unroll
  for (int m = 0; m < 8; m++){
    int col = m * 16 + l15;
    #pragma unroll
    for (int r = 0; r < 4; r++){
      int rr = r0 + r;
      if (rr < N){
        Qo[(size_t)rr * 128 + col]  = f2h(q[m][r]);
        V16[(size_t)rr * 128 + col] = f2h(v[m][r]);
        K8[(size_t)rr * 128 + col]  = f2fp8(k[m][r]);
      }
    }
  }
}

// ---------------- generic GEMM: C = epi(X[NxKD] * W[MDxKD]^T + bias), swizzled W ----------------
// EPI: 1=relu->f16, 2=sigmoid->f32, 3=+res->f32, 4=gate: (1-g)*res+g*v ->f32
// ST=1: also accumulate per-column sum/sumsq into stats[0..255] via atomics
template<int KD, int MD, int EPI, int GS, int ST>
__global__ __launch_bounds__(256) void gemm_k(
    const ushort16* __restrict__ X, const ushort16* __restrict__ W,
    const float* __restrict__ bias, const float* __restrict__ bias2,
    const float* __restrict__ res, const float* __restrict__ gate,
    float* __restrict__ outf, ushort16* __restrict__ outb,
    float* __restrict__ stats, int N)
{
  constexpr int KS = KD / 32;
  constexpr int MT = MD / 16;
  int lane = threadIdx.x & 63, wv = threadIdx.x >> 6;
  int l15 = lane & 15, kq = lane >> 4;
  int rowbase = (blockIdx.x * 4 + wv) * 16;
  int row = rowbase + l15;
  int rc = row < N ? row : N - 1;
  const f16x8* ap = (const f16x8*)(X + (size_t)rc * KD + kq * 8);
  f16x8 a[KS];
  #pragma unroll
  for (int s = 0; s < KS; s++) a[s] = ap[s * 4];
  const f16x8* Wf = (const f16x8*)W;
  f32x4 acc[MT];
  #pragma unroll
  for (int m = 0; m < MT; m++) acc[m] = (f32x4)(0.f);
  #pragma unroll
  for (int s = 0; s < KS; s++){
    #pragma unroll
    for (int m = 0; m < MT; m++){
      acc[m] = __builtin_amdgcn_mfma_f32_16x16x32_f16(a[s], Wf[(s * MT + m) * 64 + lane], acc[m], 0, 0, 0);
    }
  }
  float ps[MT], ps2[MT];
  if constexpr (ST){
    #pragma unroll
    for (int m = 0; m < MT; m++){ ps[m] = 0.f; ps2[m] = 0.f; }
  }
  int r0 = rowbase + kq * 4;
  #pragma unroll
  for (int m = 0; m < MT; m++){
    int col = m * 16 + l15;
    float bv;
    if (bias2 && col >= 128) bv = bias2[col - 128];
    else bv = bias ? bias[col] : 0.f;
    #pragma unroll
    for (int r = 0; r < 4; r++){
      int rr = r0 + r;
      if (rr < N){
        float v = acc[m][r] + bv;
        if constexpr (EPI == 1) v = fmaxf(v, 0.f);
        if constexpr (EPI == 2) v = 1.f / (1.f + __expf(-v));
        if constexpr (EPI == 3) v += res[(size_t)rr * MD + col];
        if constexpr (EPI == 4){
          float g = gate[(size_t)rr * GS + col];
          float rv = res[(size_t)rr * MD + col];
          v = (1.f - g) * rv + g * v;
        }
        if (outf) outf[(size_t)rr * MD + col] = v;
        if (outb) outb[(size_t)rr * MD + col] = f2h(v);
        if constexpr (ST){ ps[m] += v; ps2[m] += v * v; }
      }
    }
  }
  if constexpr (ST){
    __shared__ float sst[4][128];
    __shared__ float sst2[4][128];
    #pragma unroll
    for (int m = 0; m < MT; m++){
      float s = ps[m], s2 = ps2[m];
      s  += __shfl_xor(s, 16);  s  += __shfl_xor(s, 32);
      s2 += __shfl_xor(s2, 16); s2 += __shfl_xor(s2, 32);
      if (lane < 16){ sst[wv][m * 16 + l15] = s; sst2[wv][m * 16 + l15] = s2; }
    }
    __syncthreads();
    int tid = threadIdx.x;
    if (tid < 128){
      atomicAdd(&stats[tid], sst[0][tid] + sst[1][tid] + sst[2][tid] + sst[3][tid]);
    } else {
      int c = tid - 128;
      atomicAdd(&stats[tid], sst2[0][c] + sst2[1][c] + sst2[2][c] + sst2[3][c]);
    }
  }
}

// ---------------- fused dual-attention (fp8 K, f16 V) ----------------
__global__ __launch_bounds__(256) void attn2_k(
    const ushort16* __restrict__ Qa, const unsigned char* __restrict__ K8a, const ushort16* __restrict__ V16a,
    const ushort16* __restrict__ Qb, const unsigned char* __restrict__ K8b, const ushort16* __restrict__ V16b,
    const int* __restrict__ row_off, const int* __restrict__ esrc,
    ushort16* __restrict__ cat, int N)
{
  int wv = threadIdx.x >> 6, lane = threadIdx.x & 63;
  int n = blockIdx.x * 4 + wv;
  if (n >= N) return;
  int h = lane >> 5, j = lane & 31;
  uint2 qau = *(const uint2*)(Qa + (size_t)n * 128 + j * 4);
  uint2 qbu = *(const uint2*)(Qb + (size_t)n * 128 + j * 4);
  f16x2 qa01 = *(f16x2*)&qau.x, qa23 = *(f16x2*)&qau.y;
  f16x2 qb01 = *(f16x2*)&qbu.x, qb23 = *(f16x2*)&qbu.y;
  float qa0 = (float)qa01.x * 0.25f, qa1 = (float)qa01.y * 0.25f;
  float qa2 = (float)qa23.x * 0.25f, qa3 = (float)qa23.y * 0.25f;
  float qb0 = (float)qb01.x * 0.25f, qb1 = (float)qb01.y * 0.25f;
  float qb2 = (float)qb23.x * 0.25f, qb3 = (float)qb23.y * 0.25f;
  int e0 = row_off[n], e1 = row_off[n + 1];
  int deg = e1 - e0;
  int itmax = (deg + 1) >> 1;
  float a0 = 0.f, a1 = 0.f, a2 = 0.f, a3 = 0.f, za = 0.f;
  float b0 = 0.f, b1 = 0.f, b2 = 0.f, b3 = 0.f, zb = 0.f;
  int e = e0 + h;
  int s = (e < e1) ? esrc[e] : -1;
  int sc = s < 0 ? 0 : s;
  uint32 kwa = *(const uint32*)(K8a + (size_t)sc * 128 + j * 4);
  uint32 kwb = *(const uint32*)(K8b + (size_t)sc * 128 + j * 4);
  uint2  vwa = *(const uint2*)(V16a + (size_t)sc * 128 + j * 4);
  uint2  vwb = *(const uint2*)(V16b + (size_t)sc * 128 + j * 4);
  for (int it = 0; it < itmax; ++it){
    int e2 = e + 2;
    int s2 = (e2 < e1) ? esrc[e2] : -1;
    int s2c = s2 < 0 ? 0 : s2;
    uint32 kwa2 = *(const uint32*)(K8a + (size_t)s2c * 128 + j * 4);
    uint32 kwb2 = *(const uint32*)(K8b + (size_t)s2c * 128 + j * 4);
    uint2  vwa2 = *(const uint2*)(V16a + (size_t)s2c * 128 + j * 4);
    uint2  vwb2 = *(const uint2*)(V16b + (size_t)s2c * 128 + j * 4);
    if (s >= 0){
      f32x2 ka01 = fp8pair_lo(kwa), ka23 = fp8pair_hi(kwa);
      f32x2 kb01 = fp8pair_lo(kwb), kb23 = fp8pair_hi(kwb);
      float da = fmaf(ka01.x, qa0, fmaf(ka01.y, qa1, fmaf(ka23.x, qa2, ka23.y * qa3)));
      float db = fmaf(kb01.x, qb0, fmaf(kb01.y, qb1, fmaf(kb23.x, qb2, kb23.y * qb3)));
      da += __shfl_xor(da, 1); da += __shfl_xor(da, 2);
      db += __shfl_xor(db, 1); db += __shfl_xor(db, 2);
      float sa = __expf(fminf(fmaxf(da, -5.f), 5.f));
      float sb = __expf(fminf(fmaxf(db, -5.f), 5.f));
      f16x2 va01 = *(f16x2*)&vwa.x, va23 = *(f16x2*)&vwa.y;
      f16x2 vb01 = *(f16x2*)&vwb.x, vb23 = *(f16x2*)&vwb.y;
      a0 = fmaf(sa, (float)va01.x, a0); a1 = fmaf(sa, (float)va01.y, a1);
      a2 = fmaf(sa, (float)va23.x, a2); a3 = fmaf(sa, (float)va23.y, a3);
      za += sa;
      b0 = fmaf(sb, (float)vb01.x, b0); b1 = fmaf(sb, (float)vb01.y, b1);
      b2 = fmaf(sb, (float)vb23.x, b2); b3 = fmaf(sb, (float)vb23.y, b3);
      zb += sb;
    }
    e = e2; s = s2;
    kwa = kwa2; kwb = kwb2; vwa = vwa2; vwb = vwb2;
  }
  a0 += __shfl_xor(a0, 32); a1 += __shfl_xor(a1, 32);
  a2 += __shfl_xor(a2, 32); a3 += __shfl_xor(a3, 32);
  za += __shfl_xor(za, 32);
  b0 += __shfl_xor(b0, 32); b1 += __shfl_xor(b1, 32);
  b2 += __shfl_xor(b2, 32); b3 += __shfl_xor(b3, 32);
  zb += __shfl_xor(zb, 32);
  uint2 o;
  if (h == 0){
    float rz = __builtin_amdgcn_rcpf(za);
    o.x = pk16(a0 * rz, a1 * rz);
    o.y = pk16(a2 * rz, a3 * rz);
    *(uint2*)(cat + (size_t)n * 256 + j * 4) = o;
  } else {
    float rz = __builtin_amdgcn_rcpf(zb);
    o.x = pk16(b0 * rz, b1 * rz);
    o.y = pk16(b2 * rz, b3 * rz);
    *(uint2*)(cat + (size_t)n * 256 + 128 + j * 4) = o;
  }
}

// ---------------- BatchNorm apply ----------------
__global__ __launch_bounds__(256) void bn_apply_k(
    const float4* __restrict__ x, const float* __restrict__ stats,
    const float* __restrict__ gamma, const float* __restrict__ beta,
    float4* __restrict__ outf, ushort16* __restrict__ outb, int total4, float invN)
{
  int i = blockIdx.x * 256 + threadIdx.x;
  if (i >= total4) return;
  float4 v = x[i];
  int c0 = (i * 4) & 127;
  float o[4];
  float xv[4] = {v.x, v.y, v.z, v.w};
  #pragma unroll
  for (int j = 0; j < 4; j++){
    int c = c0 + j;
    float m = stats[c] * invN;
    float var = stats[128 + c] * invN - m * m;
    float rstd = rsqrtf(var + EPS_BN);
    o[j] = (xv[j] - m) * rstd * gamma[c] + beta[c];
  }
  outf[i] = make_float4(o[0], o[1], o[2], o[3]);
  if (outb){
    uint2 p;
    p.x = pk16(o[0], o[1]);
    p.y = pk16(o[2], o[3]);
    *(uint2*)(outb + (size_t)i * 4) = p;
  }
}

// ---------------- host ----------------
extern "C" void kernel_launch(void* const* d_in, const int* in_sizes, int n_in,
                              void* d_out, int out_size, void* d_ws, size_t ws_size,
                              hipStream_t stream) {
  const float* h   = (const float*)d_in[0];
  const float* sv  = (const float*)d_in[1];
  const int* src   = (const int*)d_in[2];
  const int* dst   = (const int*)d_in[3];
  const int N = in_sizes[0] / 128;
  const int E = in_sizes[2];

  char* wsb = (char*)d_ws;
  size_t o = 0;
  auto take = [&](size_t bytes)->size_t{
    size_t r = o;
    o = (o + bytes + 255) & ~(size_t)255;
    return r;
  };
  size_t cnt_off    = take((size_t)N * 4);
  size_t stats_off  = take(4 * 256 * 4);
  size_t rowoff_off = take((size_t)(N + 1) * 4);
  size_t cursor_off = take((size_t)N * 4);
  size_t bsum_off   = take(256 * 4);
  size_t esrc_off   = take((size_t)E * 4);
  size_t wpool_off  = take((size_t)376832 * 2);
  size_t hf_off     = take((size_t)N * 128 * 2);
  size_t svf_off    = take((size_t)N * 128 * 2);
  size_t cath_off   = take((size_t)N * 256 * 2);
  size_t catsv_off  = take((size_t)N * 256 * 2);
  size_t X_off      = take((size_t)N * 128 * 4);   // also K8_1 + V16_1
  size_t R_off      = take((size_t)N * 128 * 4);   // also K8_2 + V16_2
  size_t G_off      = take((size_t)N * 256 * 4);   // gates f32 N x 256; also Q1/Q2 f16
  size_t h1_off     = take((size_t)N * 128 * 2);
  size_t sv1_off    = take((size_t)N * 128 * 2);

  int*    cnt     = (int*)(wsb + cnt_off);
  float*  stats   = (float*)(wsb + stats_off);
  int*    row_off = (int*)(wsb + rowoff_off);
  int*    cursor  = (int*)(wsb + cursor_off);
  int*    bsum    = (int*)(wsb + bsum_off);
  int*    esrc    = (int*)(wsb + esrc_off);
  ushort16* wpool = (ushort16*)(wsb + wpool_off);
  ushort16* h_f   = (ushort16*)(wsb + hf_off);
  ushort16* sv_f  = (ushort16*)(wsb + svf_off);
  ushort16* cat_h = (ushort16*)(wsb + cath_off);
  ushort16* cat_sv= (ushort16*)(wsb + catsv_off);
  float*  Xb      = (float*)(wsb + X_off);
  float*  Rb      = (float*)(wsb + R_off);
  float*  Gb      = (float*)(wsb + G_off);
  ushort16* h1b   = (ushort16*)(wsb + h1_off);
  ushort16* sv1b  = (ushort16*)(wsb + sv1_off);

  // attention staging overlays (dead before Xb/Rb/Gb are written)
  unsigned char* K8_1 = (unsigned char*)(wsb + X_off);
  ushort16*      V16_1 = (ushort16*)(wsb + X_off + (size_t)N * 128);
  unsigned char* K8_2 = (unsigned char*)(wsb + R_off);
  ushort16*      V16_2 = (ushort16*)(wsb + R_off + (size_t)N * 128);
  ushort16* Q1  = (ushort16*)(wsb + G_off);
  ushort16* Q2  = (ushort16*)(wsb + G_off + (size_t)N * 128 * 2);

  // f16 swizzled weight pool offsets (elements)
  ushort16* Wq_sv = wpool + 0 * 16384;
  ushort16* Wk_sv = wpool + 1 * 16384;
  ushort16* Wv_sv = wpool + 2 * 16384;
  ushort16* Wq_cv = wpool + 3 * 16384;
  ushort16* Wk_cv = wpool + 4 * 16384;
  ushort16* Wv_cv = wpool + 5 * 16384;
  ushort16* Wq_sh = wpool + 6 * 16384;
  ushort16* Wk_sh = wpool + 7 * 16384;
  ushort16* Wv_sh = wpool + 8 * 16384;
  ushort16* Wgb   = wpool + 147456;   // [Wg1;Wg2] stacked 256x128
  ushort16* Wob   = wpool + 180224;
  ushort16* Wohb  = wpool + 212992;
  ushort16* W1b   = wpool + 245760;
  ushort16* W2b   = wpool + 278528;
  ushort16* W1hb  = wpool + 311296;
  ushort16* W2hb  = wpool + 344064;

  const float* bo   = (const float*)d_in[14];
  const float* bo_h = (const float*)d_in[16];
  const float* b1   = (const float*)d_in[18];
  const float* b2   = (const float*)d_in[20];
  const float* b1h  = (const float*)d_in[22];
  const float* b2h  = (const float*)d_in[24];
  const float* bg1  = (const float*)d_in[26];
  const float* bg2  = (const float*)d_in[28];
  const float* gbn1  = (const float*)d_in[29];
  const float* bbn1  = (const float*)d_in[30];
  const float* gbn2  = (const float*)d_in[31];
  const float* bbn2  = (const float*)d_in[32];
  const float* gbn1h = (const float*)d_in[33];
  const float* bbn1h = (const float*)d_in[34];
  const float* gbn2h = (const float*)d_in[35];
  const float* bbn2h = (const float*)d_in[36];

  float* out_h  = (float*)d_out;
  float* out_sv = out_h + (size_t)N * 128;

  hipMemsetAsync(wsb, 0, stats_off + 4 * 256 * 4, stream);

  // weight conversion (fragment-linear swizzle)
  WConv wc;
  {
    auto set = [&](int i, int din, int din2, size_t dstoff, int KD, int MD){
      wc.e[i].s  = (const float*)d_in[din];
      wc.e[i].s2 = (din2 >= 0) ? (const float*)d_in[din2] : nullptr;
      wc.e[i].d  = wpool + dstoff;
      wc.e[i].KD = KD; wc.e[i].MD = MD;
      wc.e[i].nfrag = KD * MD / 8;
    };
    for (int i = 0; i < 9; i++) set(i, 4 + i, -1, (size_t)i * 16384, 128, 128);
    set(9,  25, 27, 147456, 128, 256);  // [Wg1;Wg2]
    set(10, 13, -1, 180224, 256, 128);  // Wo
    set(11, 15, -1, 212992, 256, 128);  // Wo_h
    set(12, 17, -1, 245760, 128, 256);  // W1
    set(13, 19, -1, 278528, 256, 128);  // W2
    set(14, 21, -1, 311296, 128, 256);  // W1h
    set(15, 23, -1, 344064, 256, 128);  // W2h
  }
  conv_w_k<<<dim3(16, 16), 256, 0, stream>>>(wc);

  int nelem = N * 128;
  conv2_k<<<dim3((nelem / 4 + 255) / 256, 2), 256, 0, stream>>>(h, sv, h_f, sv_f, nelem);

  const int NB = (N + 1023) / 1024;
  hist_k<<<2048, 256, 0, stream>>>(dst, cnt, E);
  scan_part_k<<<NB, 256, 0, stream>>>(cnt, bsum, N);
  scan_top_k<<<1, 64, 0, stream>>>(bsum, NB);
  scan_out_k<<<NB, 256, 0, stream>>>(cnt, bsum, row_off, cursor, N, E);
  fill_k<<<2048, 256, 0, stream>>>(src, dst, cursor, esrc, E);

  const int GB = (N + 63) / 64;
  const int AB = (N + 3) / 4;
  const int T4 = nelem / 4;
  const int APB = (T4 + 255) / 256;
  const float invN = 1.f / (float)N;

  // h-branch attention pair: self(h) + cross(h; sv)
  gemm_qkv_k<<<GB, 256, 0, stream>>>(h_f, h_f, Wq_sv, Wk_sv, Wv_sv, Q1, K8_1, V16_1, N);
  gemm_qkv_k<<<GB, 256, 0, stream>>>(h_f, sv_f, Wq_cv, Wk_cv, Wv_cv, Q2, K8_2, V16_2, N);
  attn2_k<<<AB, 256, 0, stream>>>(Q1, K8_1, V16_1, Q2, K8_2, V16_2, row_off, esrc, cat_h, N);
  // sv-branch attention pair: self(sv) + cross(sv; h)
  gemm_qkv_k<<<GB, 256, 0, stream>>>(sv_f, sv_f, Wq_sh, Wk_sh, Wv_sh, Q1, K8_1, V16_1, N);
  gemm_qkv_k<<<GB, 256, 0, stream>>>(sv_f, h_f, Wq_cv, Wk_cv, Wv_cv, Q2, K8_2, V16_2, N);
  attn2_k<<<AB, 256, 0, stream>>>(Q1, K8_1, V16_1, Q2, K8_2, V16_2, row_off, esrc, cat_sv, N);

  // ---- h branch ----
  gemm_k<256,128,3,128,1><<<GB, 256, 0, stream>>>(cat_h, Wob, bo, nullptr, h, nullptr, Xb, nullptr, stats, N);
  bn_apply_k<<<APB, 256, 0, stream>>>((const float4*)Xb, stats, gbn1, bbn1, (float4*)Rb, h1b, T4, invN);
  gemm_k<128,256,1,128,0><<<GB, 256, 0, stream>>>(h1b, W1b, b1, nullptr, nullptr, nullptr, nullptr, cat_h, nullptr, N);
  gemm_k<256,128,3,128,1><<<GB, 256, 0, stream>>>(cat_h, W2b, b2, nullptr, Rb, nullptr, Xb, nullptr, stats + 256, N);
  bn_apply_k<<<APB, 256, 0, stream>>>((const float4*)Xb, stats + 256, gbn2, bbn2, (float4*)out_h, nullptr, T4, invN);

  // ---- sv branch ----
  gemm_k<128,256,2,128,0><<<GB, 256, 0, stream>>>(h_f, Wgb, bg1, bg2, nullptr, nullptr, Gb, nullptr, nullptr, N);
  gemm_k<256,128,4,256,1><<<GB, 256, 0, stream>>>(cat_sv, Wohb, bo_h, nullptr, sv, Gb, Xb, nullptr, stats + 512, N);
  bn_apply_k<<<APB, 256, 0, stream>>>((const float4*)Xb, stats + 512, gbn1h, bbn1h, (float4*)Rb, sv1b, T4, invN);
  gemm_k<128,256,1,128,0><<<GB, 256, 0, stream>>>(sv1b, W1hb, b1h, nullptr, nullptr, nullptr, nullptr, cat_sv, nullptr, N);
  gemm_k<256,128,4,256,1><<<GB, 256, 0, stream>>>(cat_sv, W2hb, b2h, nullptr, Rb, Gb + 128, Xb, nullptr, stats + 768, N);
  bn_apply_k<<<APB, 256, 0, stream>>>((const float4*)Xb, stats + 768, gbn2h, bbn2h, (float4*)out_sv, nullptr, T4, invN);
}

// Round 7
// 1083.077 us; speedup vs baseline: 1.4958x; 1.0752x over previous
//
#include <hip/hip_runtime.h>

typedef _Float16 f16x8 __attribute__((ext_vector_type(8)));
typedef _Float16 f16x2 __attribute__((ext_vector_type(2)));
typedef __fp16 fp16x2_raw __attribute__((ext_vector_type(2)));
typedef float f32x4 __attribute__((ext_vector_type(4)));
typedef float f32x2 __attribute__((ext_vector_type(2)));
typedef unsigned int uint32;
typedef unsigned short ushort16;
typedef unsigned char uchar;

#define EPS_BN 1e-5f

__device__ __forceinline__ uint32 pk16(float a, float b){
  fp16x2_raw h = __builtin_amdgcn_cvt_pkrtz(a, b);
  return *(uint32*)&h;
}
__device__ __forceinline__ ushort16 f2h(float f){
  _Float16 h = (_Float16)f;
  union { _Float16 h; ushort16 u; } c; c.h = h; return c.u;
}
__device__ __forceinline__ uchar f2fp8(float f){
  uint32 p = __builtin_amdgcn_cvt_pk_fp8_f32(f, f, 0, false);
  return (uchar)(p & 0xff);
}
__device__ __forceinline__ f32x2 fp8pair_lo(uint32 w){
  return __builtin_amdgcn_cvt_pk_f32_fp8(w, false);
}
__device__ __forceinline__ f32x2 fp8pair_hi(uint32 w){
  return __builtin_amdgcn_cvt_pk_f32_fp8(w, true);
}

// ---------------- weight conversion: f32 row-major -> f16 MFMA-fragment-linear ----------------
struct WEnt { const float* s; const float* s2; ushort16* d; int KD, MD, nfrag; };
struct WConv { WEnt e[16]; };

__global__ __launch_bounds__(256) void conv_w_k(WConv a){
  WEnt t = a.e[blockIdx.y];
  int fid = blockIdx.x * 256 + threadIdx.x;
  if (fid >= t.nfrag) return;
  int lane = fid & 63, sm = fid >> 6;
  int MT = t.MD >> 4;
  int s = sm / MT, m = sm - s * MT;
  int row = m * 16 + (lane & 15);
  int col = s * 32 + (lane >> 4) * 8;
  const float* sp = t.s;
  if (t.s2 && row >= 128){ sp = t.s2; row -= 128; }
  const float* p = sp + (size_t)row * t.KD + col;
  uint4 o;
  o.x = pk16(p[0], p[1]); o.y = pk16(p[2], p[3]);
  o.z = pk16(p[4], p[5]); o.w = pk16(p[6], p[7]);
  *(uint4*)(t.d + (size_t)fid * 8) = o;
}

__global__ __launch_bounds__(256) void conv2_k(const float* __restrict__ a, const float* __restrict__ b,
                                               ushort16* __restrict__ da, ushort16* __restrict__ db, int n){
  const float* s = blockIdx.y ? b : a;
  ushort16* d = blockIdx.y ? db : da;
  int i = (blockIdx.x * 256 + threadIdx.x) * 4;
  if (i >= n) return;
  float4 v = *(const float4*)(s + i);
  uint2 p;
  p.x = pk16(v.x, v.y);
  p.y = pk16(v.z, v.w);
  *(uint2*)(d + i) = p;
}

// ---------------- CSR build ----------------
__global__ void hist_k(const int* __restrict__ dst, int* __restrict__ cnt, int E){
  int i = blockIdx.x * blockDim.x + threadIdx.x;
  int stride = gridDim.x * blockDim.x;
  for (; i < E; i += stride) atomicAdd(&cnt[dst[i]], 1);
}

__global__ __launch_bounds__(256) void scan_part_k(const int* __restrict__ cnt, int* __restrict__ bsum, int N){
  int tid = threadIdx.x, lane = tid & 63, wv = tid >> 6;
  int base = blockIdx.x * 1024 + tid * 4;
  int ts = 0;
  #pragma unroll
  for (int j = 0; j < 4; j++) if (base + j < N) ts += cnt[base + j];
  #pragma unroll
  for (int d = 1; d < 64; d <<= 1) ts += __shfl_xor(ts, d);
  __shared__ int wt[4];
  if (lane == 0) wt[wv] = ts;
  __syncthreads();
  if (tid == 0) bsum[blockIdx.x] = wt[0] + wt[1] + wt[2] + wt[3];
}

__global__ __launch_bounds__(64) void scan_top_k(int* __restrict__ bsum, int nb){
  int tid = threadIdx.x;
  int v = (tid < nb) ? bsum[tid] : 0;
  int inc = v;
  #pragma unroll
  for (int d = 1; d < 64; d <<= 1){
    int t = __shfl_up(inc, d);
    if (tid >= d) inc += t;
  }
  if (tid < nb) bsum[tid] = inc - v;
}

__global__ __launch_bounds__(256) void scan_out_k(const int* __restrict__ cnt, const int* __restrict__ bsum,
                                                  int* __restrict__ row_off, int* __restrict__ cursor,
                                                  int N, int E){
  int tid = threadIdx.x, lane = tid & 63, wv = tid >> 6;
  int base = blockIdx.x * 1024 + tid * 4;
  int c[4]; int ts = 0;
  #pragma unroll
  for (int j = 0; j < 4; j++){ c[j] = (base + j < N) ? cnt[base + j] : 0; ts += c[j]; }
  int inc = ts;
  #pragma unroll
  for (int d = 1; d < 64; d <<= 1){
    int t = __shfl_up(inc, d);
    if (lane >= d) inc += t;
  }
  int wexcl = inc - ts;
  __shared__ int wt[4];
  if (lane == 63) wt[wv] = inc;
  __syncthreads();
  int woff = 0;
  for (int w = 0; w < 4; w++) if (w < wv) woff += wt[w];
  int off = bsum[blockIdx.x] + woff + wexcl;
  #pragma unroll
  for (int j = 0; j < 4; j++){
    if (base + j < N){ row_off[base + j] = off; cursor[base + j] = off; off += c[j]; }
  }
  if (blockIdx.x == 0 && tid == 0) row_off[N] = E;
}

__global__ void fill_k(const int* __restrict__ src, const int* __restrict__ dst,
                       int* __restrict__ cursor, int* __restrict__ esrc, int E){
  int i = blockIdx.x * blockDim.x + threadIdx.x;
  int stride = gridDim.x * blockDim.x;
  for (; i < E; i += stride){
    int d = dst[i];
    int p = atomicAdd(&cursor[d], 1);
    esrc[p] = src[i];
  }
}

// ---------------- fused QKV projection ----------------
// Q: f16 row-major. K/V interleaved dual-stream rows:
//  K8ab: row 256 B, group g=col>>2: bytes g*8 + st*4 + (col&3)   (fp8)
//  V16ab: row 256 ushorts, same formula in ushort units          (f16)
__global__ __launch_bounds__(256) void gemm_qkv_k(
    const ushort16* __restrict__ Xq, const ushort16* __restrict__ Xkv,
    const ushort16* __restrict__ Wq, const ushort16* __restrict__ Wk, const ushort16* __restrict__ Wv,
    ushort16* __restrict__ Qo, uchar* __restrict__ K8ab, ushort16* __restrict__ V16ab,
    int st, int N)
{
  int lane = threadIdx.x & 63, wv = threadIdx.x >> 6;
  int l15 = lane & 15, kq = lane >> 4;
  int rowbase = (blockIdx.x * 4 + wv) * 16;
  int row = rowbase + l15;
  int rc = row < N ? row : N - 1;
  const f16x8* aq = (const f16x8*)(Xq + (size_t)rc * 128 + kq * 8);
  const f16x8* ak = (const f16x8*)(Xkv + (size_t)rc * 128 + kq * 8);
  f16x8 Aq[4], Ak[4];
  #pragma unroll
  for (int s = 0; s < 4; s++){ Aq[s] = aq[s * 4]; Ak[s] = ak[s * 4]; }
  const f16x8* Wqf = (const f16x8*)Wq;
  const f16x8* Wkf = (const f16x8*)Wk;
  const f16x8* Wvf = (const f16x8*)Wv;
  f32x4 q[8], k[8], v[8];
  #pragma unroll
  for (int m = 0; m < 8; m++){ q[m] = (f32x4)(0.f); k[m] = (f32x4)(0.f); v[m] = (f32x4)(0.f); }
  #pragma unroll
  for (int s = 0; s < 4; s++){
    #pragma unroll
    for (int m = 0; m < 8; m++){
      int fi = (s * 8 + m) * 64 + lane;
      q[m] = __builtin_amdgcn_mfma_f32_16x16x32_f16(Aq[s], Wqf[fi], q[m], 0, 0, 0);
      k[m] = __builtin_amdgcn_mfma_f32_16x16x32_f16(Ak[s], Wkf[fi], k[m], 0, 0, 0);
      v[m] = __builtin_amdgcn_mfma_f32_16x16x32_f16(Ak[s], Wvf[fi], v[m], 0, 0, 0);
    }
  }
  int r0 = rowbase + kq * 4;
  #pragma unroll
  for (int m = 0; m < 8; m++){
    int col = m * 16 + l15;
    int kv = (col >> 2) * 8 + st * 4 + (col & 3);
    #pragma unroll
    for (int r = 0; r < 4; r++){
      int rr = r0 + r;
      if (rr < N){
        Qo[(size_t)rr * 128 + col] = f2h(q[m][r]);
        K8ab[(size_t)rr * 256 + kv] = f2fp8(k[m][r]);
        V16ab[(size_t)rr * 256 + kv] = f2h(v[m][r]);
      }
    }
  }
}

// ---------------- generic GEMM, swizzled W, f16 in/out ----------------
// EPI: 1=relu, 2=sigmoid, 3=+res(f16), 4=gate w/ res(f16), 5=+BN(res), 6=gate w/ BN(res)
// ABN=1: apply BN to A on load (astats/ag/ab). ST=1: accumulate column stats.
template<int KD, int MD, int EPI, int ABN, int ST, int GS>
__global__ __launch_bounds__(256) void gemm_k(
    const ushort16* __restrict__ X, const ushort16* __restrict__ W,
    const float* __restrict__ bias, const float* __restrict__ bias2,
    const ushort16* __restrict__ resb, const ushort16* __restrict__ gatep,
    const float* __restrict__ rstats, const float* __restrict__ rg, const float* __restrict__ rb,
    const float* __restrict__ astats, const float* __restrict__ ag, const float* __restrict__ ab,
    ushort16* __restrict__ outb, float* __restrict__ stats_out, int N, float invN)
{
  constexpr int KS = KD / 32;
  constexpr int MT = MD / 16;
  int lane = threadIdx.x & 63, wv = threadIdx.x >> 6;
  int l15 = lane & 15, kq = lane >> 4;
  int rowbase = (blockIdx.x * 4 + wv) * 16;
  int row = rowbase + l15;
  int rc = row < N ? row : N - 1;
  const f16x8* ap = (const f16x8*)(X + (size_t)rc * KD + kq * 8);
  f16x8 a[KS];
  #pragma unroll
  for (int s = 0; s < KS; s++) a[s] = ap[s * 4];
  if constexpr (ABN){
    #pragma unroll
    for (int s = 0; s < KS; s++){
      #pragma unroll
      for (int j = 0; j < 8; j++){
        int c = s * 32 + kq * 8 + j;
        float mm = astats[c] * invN;
        float var = astats[128 + c] * invN - mm * mm;
        float rs = rsqrtf(var + EPS_BN);
        float scc = rs * ag[c];
        float shh = ab[c] - mm * scc;
        a[s][j] = (_Float16)((float)a[s][j] * scc + shh);
      }
    }
  }
  const f16x8* Wf = (const f16x8*)W;
  f32x4 acc[MT];
  #pragma unroll
  for (int m = 0; m < MT; m++) acc[m] = (f32x4)(0.f);
  #pragma unroll
  for (int s = 0; s < KS; s++){
    #pragma unroll
    for (int m = 0; m < MT; m++){
      acc[m] = __builtin_amdgcn_mfma_f32_16x16x32_f16(a[s], Wf[(s * MT + m) * 64 + lane], acc[m], 0, 0, 0);
    }
  }
  float ps[MT], ps2[MT];
  if constexpr (ST){
    #pragma unroll
    for (int m = 0; m < MT; m++){ ps[m] = 0.f; ps2[m] = 0.f; }
  }
  int r0 = rowbase + kq * 4;
  #pragma unroll
  for (int m = 0; m < MT; m++){
    int col = m * 16 + l15;
    float bv;
    if (bias2 && col >= 128) bv = bias2[col - 128];
    else bv = bias[col];
    float sc = 0.f, sh = 0.f;
    if constexpr (EPI == 5 || EPI == 6){
      float mm = rstats[col] * invN;
      float var = rstats[128 + col] * invN - mm * mm;
      float rs = rsqrtf(var + EPS_BN);
      sc = rs * rg[col]; sh = rb[col] - mm * sc;
    }
    #pragma unroll
    for (int r = 0; r < 4; r++){
      int rr = r0 + r;
      if (rr < N){
        float v = acc[m][r] + bv;
        if constexpr (EPI == 1) v = fmaxf(v, 0.f);
        if constexpr (EPI == 2) v = 1.f / (1.f + __expf(-v));
        if constexpr (EPI == 3){
          union { ushort16 u; _Float16 h; } cv; cv.u = resb[(size_t)rr * 128 + col];
          v += (float)cv.h;
        }
        if constexpr (EPI == 5){
          union { ushort16 u; _Float16 h; } cv; cv.u = resb[(size_t)rr * 128 + col];
          v += (float)cv.h * sc + sh;
        }
        if constexpr (EPI == 4 || EPI == 6){
          union { ushort16 u; _Float16 h; } gv; gv.u = gatep[(size_t)rr * GS + col];
          union { ushort16 u; _Float16 h; } cv; cv.u = resb[(size_t)rr * 128 + col];
          float g = (float)gv.h;
          float rv = (float)cv.h;
          if constexpr (EPI == 6) rv = rv * sc + sh;
          v = (1.f - g) * rv + g * v;
        }
        outb[(size_t)rr * MD + col] = f2h(v);
        if constexpr (ST){ ps[m] += v; ps2[m] += v * v; }
      }
    }
  }
  if constexpr (ST){
    __shared__ float sst[4][128];
    __shared__ float sst2[4][128];
    #pragma unroll
    for (int m = 0; m < MT; m++){
      float s = ps[m], s2 = ps2[m];
      s  += __shfl_xor(s, 16);  s  += __shfl_xor(s, 32);
      s2 += __shfl_xor(s2, 16); s2 += __shfl_xor(s2, 32);
      if (lane < 16){ sst[wv][m * 16 + l15] = s; sst2[wv][m * 16 + l15] = s2; }
    }
    __syncthreads();
    int tid = threadIdx.x;
    if (tid < 128){
      atomicAdd(&stats_out[tid], sst[0][tid] + sst[1][tid] + sst[2][tid] + sst[3][tid]);
    } else {
      int c = tid - 128;
      atomicAdd(&stats_out[tid], sst2[0][c] + sst2[1][c] + sst2[2][c] + sst2[3][c]);
    }
  }
}

// ---------------- fused dual-attention (interleaved fp8 K / f16 V) ----------------
__global__ __launch_bounds__(256) void attn2_k(
    const ushort16* __restrict__ Qa, const ushort16* __restrict__ Qb,
    const uchar* __restrict__ K8ab, const uchar* __restrict__ V16ab,
    const int* __restrict__ row_off, const int* __restrict__ esrc,
    ushort16* __restrict__ cat, int N)
{
  int wv = threadIdx.x >> 6, lane = threadIdx.x & 63;
  int n = blockIdx.x * 4 + wv;
  if (n >= N) return;
  int h = lane >> 5, j = lane & 31;
  uint2 qau = *(const uint2*)(Qa + (size_t)n * 128 + j * 4);
  uint2 qbu = *(const uint2*)(Qb + (size_t)n * 128 + j * 4);
  f16x2 qa01 = *(f16x2*)&qau.x, qa23 = *(f16x2*)&qau.y;
  f16x2 qb01 = *(f16x2*)&qbu.x, qb23 = *(f16x2*)&qbu.y;
  float qa0 = (float)qa01.x * 0.25f, qa1 = (float)qa01.y * 0.25f;
  float qa2 = (float)qa23.x * 0.25f, qa3 = (float)qa23.y * 0.25f;
  float qb0 = (float)qb01.x * 0.25f, qb1 = (float)qb01.y * 0.25f;
  float qb2 = (float)qb23.x * 0.25f, qb3 = (float)qb23.y * 0.25f;
  int e0 = row_off[n], e1 = row_off[n + 1];
  int deg = e1 - e0;
  int itmax = (deg + 1) >> 1;
  float a0 = 0.f, a1 = 0.f, a2 = 0.f, a3 = 0.f, za = 0.f;
  float b0 = 0.f, b1 = 0.f, b2 = 0.f, b3 = 0.f, zb = 0.f;
  int e = e0 + h;
  int s = (e < e1) ? esrc[e] : -1;
  int sc = s < 0 ? 0 : s;
  uint2 kw = *(const uint2*)(K8ab + (size_t)sc * 256 + j * 8);
  uint4 vw = *(const uint4*)(V16ab + (size_t)sc * 512 + j * 16);
  for (int it = 0; it < itmax; ++it){
    int e2 = e + 2;
    int s2 = (e2 < e1) ? esrc[e2] : -1;
    int s2c = s2 < 0 ? 0 : s2;
    uint2 kw2 = *(const uint2*)(K8ab + (size_t)s2c * 256 + j * 8);
    uint4 vw2 = *(const uint4*)(V16ab + (size_t)s2c * 512 + j * 16);
    if (s >= 0){
      f32x2 ka01 = fp8pair_lo(kw.x), ka23 = fp8pair_hi(kw.x);
      f32x2 kb01 = fp8pair_lo(kw.y), kb23 = fp8pair_hi(kw.y);
      float da = fmaf(ka01.x, qa0, fmaf(ka01.y, qa1, fmaf(ka23.x, qa2, ka23.y * qa3)));
      float db = fmaf(kb01.x, qb0, fmaf(kb01.y, qb1, fmaf(kb23.x, qb2, kb23.y * qb3)));
      da += __shfl_xor(da, 1); da += __shfl_xor(da, 2);
      db += __shfl_xor(db, 1); db += __shfl_xor(db, 2);
      float sa = __expf(fminf(fmaxf(da, -5.f), 5.f));
      float sb = __expf(fminf(fmaxf(db, -5.f), 5.f));
      f16x2 va01 = *(f16x2*)&vw.x, va23 = *(f16x2*)&vw.y;
      f16x2 vb01 = *(f16x2*)&vw.z, vb23 = *(f16x2*)&vw.w;
      a0 = fmaf(sa, (float)va01.x, a0); a1 = fmaf(sa, (float)va01.y, a1);
      a2 = fmaf(sa, (float)va23.x, a2); a3 = fmaf(sa, (float)va23.y, a3);
      za += sa;
      b0 = fmaf(sb, (float)vb01.x, b0); b1 = fmaf(sb, (float)vb01.y, b1);
      b2 = fmaf(sb, (float)vb23.x, b2); b3 = fmaf(sb, (float)vb23.y, b3);
      zb += sb;
    }
    e = e2; s = s2; kw = kw2; vw = vw2;
  }
  a0 += __shfl_xor(a0, 32); a1 += __shfl_xor(a1, 32);
  a2 += __shfl_xor(a2, 32); a3 += __shfl_xor(a3, 32);
  za += __shfl_xor(za, 32);
  b0 += __shfl_xor(b0, 32); b1 += __shfl_xor(b1, 32);
  b2 += __shfl_xor(b2, 32); b3 += __shfl_xor(b3, 32);
  zb += __shfl_xor(zb, 32);
  uint2 o;
  if (h == 0){
    float rz = __builtin_amdgcn_rcpf(za);
    o.x = pk16(a0 * rz, a1 * rz);
    o.y = pk16(a2 * rz, a3 * rz);
    *(uint2*)(cat + (size_t)n * 256 + j * 4) = o;
  } else {
    float rz = __builtin_amdgcn_rcpf(zb);
    o.x = pk16(b0 * rz, b1 * rz);
    o.y = pk16(b2 * rz, b3 * rz);
    *(uint2*)(cat + (size_t)n * 256 + 128 + j * 4) = o;
  }
}

// ---------------- BatchNorm apply (f16 in, f32 out) ----------------
__global__ __launch_bounds__(256) void bn_apply_k(
    const ushort16* __restrict__ x, const float* __restrict__ stats,
    const float* __restrict__ gamma, const float* __restrict__ beta,
    float* __restrict__ outf, int total4, float invN)
{
  int i = blockIdx.x * 256 + threadIdx.x;
  if (i >= total4) return;
  uint2 xp = *(const uint2*)(x + (size_t)i * 4);
  f16x2 x01 = *(f16x2*)&xp.x, x23 = *(f16x2*)&xp.y;
  float xv[4] = {(float)x01.x, (float)x01.y, (float)x23.x, (float)x23.y};
  int c0 = (i * 4) & 127;
  float o[4];
  #pragma unroll
  for (int j = 0; j < 4; j++){
    int c = c0 + j;
    float m = stats[c] * invN;
    float var = stats[128 + c] * invN - m * m;
    float rstd = rsqrtf(var + EPS_BN);
    o[j] = (xv[j] - m) * rstd * gamma[c] + beta[c];
  }
  *(float4*)(outf + (size_t)i * 4) = make_float4(o[0], o[1], o[2], o[3]);
}

// ---------------- host ----------------
extern "C" void kernel_launch(void* const* d_in, const int* in_sizes, int n_in,
                              void* d_out, int out_size, void* d_ws, size_t ws_size,
                              hipStream_t stream) {
  const float* h   = (const float*)d_in[0];
  const float* sv  = (const float*)d_in[1];
  const int* src   = (const int*)d_in[2];
  const int* dst   = (const int*)d_in[3];
  const int N = in_sizes[0] / 128;
  const int E = in_sizes[2];

  char* wsb = (char*)d_ws;
  size_t o = 0;
  auto take = [&](size_t bytes)->size_t{
    size_t r = o;
    o = (o + bytes + 255) & ~(size_t)255;
    return r;
  };
  size_t cnt_off    = take((size_t)N * 4);
  size_t stats_off  = take(4 * 256 * 4);
  size_t rowoff_off = take((size_t)(N + 1) * 4);
  size_t cursor_off = take((size_t)N * 4);
  size_t bsum_off   = take(256 * 4);
  size_t esrc_off   = take((size_t)E * 4);
  size_t wpool_off  = take((size_t)376832 * 2);
  size_t hf_off     = take((size_t)N * 128 * 2);
  size_t svf_off    = take((size_t)N * 128 * 2);
  size_t cath_off   = take((size_t)N * 256 * 2);
  size_t catsv_off  = take((size_t)N * 256 * 2);
  size_t K8_off     = take((size_t)N * 256);       // dual-stream fp8 K
  size_t V16_off    = take((size_t)N * 512);       // dual-stream f16 V
  size_t Q1_off     = take((size_t)N * 128 * 2);
  size_t Q2_off     = take((size_t)N * 128 * 2);
  size_t X1_off     = take((size_t)N * 128 * 2);   // x1 / sv-x1 (f16)
  size_t X2_off     = take((size_t)N * 128 * 2);   // x2 / sv-x2 (f16)
  size_t G_off      = take((size_t)N * 256 * 2);   // gates f16 N x 256

  int*    cnt     = (int*)(wsb + cnt_off);
  float*  stats   = (float*)(wsb + stats_off);
  int*    row_off = (int*)(wsb + rowoff_off);
  int*    cursor  = (int*)(wsb + cursor_off);
  int*    bsum    = (int*)(wsb + bsum_off);
  int*    esrc    = (int*)(wsb + esrc_off);
  ushort16* wpool = (ushort16*)(wsb + wpool_off);
  ushort16* h_f   = (ushort16*)(wsb + hf_off);
  ushort16* sv_f  = (ushort16*)(wsb + svf_off);
  ushort16* cat_h = (ushort16*)(wsb + cath_off);
  ushort16* cat_sv= (ushort16*)(wsb + catsv_off);
  uchar*    K8ab  = (uchar*)(wsb + K8_off);
  ushort16* V16ab = (ushort16*)(wsb + V16_off);
  ushort16* Q1    = (ushort16*)(wsb + Q1_off);
  ushort16* Q2    = (ushort16*)(wsb + Q2_off);
  ushort16* Xb1   = (ushort16*)(wsb + X1_off);
  ushort16* Xb2   = (ushort16*)(wsb + X2_off);
  ushort16* Gb16  = (ushort16*)(wsb + G_off);

  // f16 swizzled weight pool offsets (elements)
  ushort16* Wq_sv = wpool + 0 * 16384;
  ushort16* Wk_sv = wpool + 1 * 16384;
  ushort16* Wv_sv = wpool + 2 * 16384;
  ushort16* Wq_cv = wpool + 3 * 16384;
  ushort16* Wk_cv = wpool + 4 * 16384;
  ushort16* Wv_cv = wpool + 5 * 16384;
  ushort16* Wq_sh = wpool + 6 * 16384;
  ushort16* Wk_sh = wpool + 7 * 16384;
  ushort16* Wv_sh = wpool + 8 * 16384;
  ushort16* Wgb   = wpool + 147456;   // [Wg1;Wg2] stacked 256x128
  ushort16* Wob   = wpool + 180224;
  ushort16* Wohb  = wpool + 212992;
  ushort16* W1b   = wpool + 245760;
  ushort16* W2b   = wpool + 278528;
  ushort16* W1hb  = wpool + 311296;
  ushort16* W2hb  = wpool + 344064;

  const float* bo   = (const float*)d_in[14];
  const float* bo_h = (const float*)d_in[16];
  const float* b1   = (const float*)d_in[18];
  const float* b2   = (const float*)d_in[20];
  const float* b1h  = (const float*)d_in[22];
  const float* b2h  = (const float*)d_in[24];
  const float* bg1  = (const float*)d_in[26];
  const float* bg2  = (const float*)d_in[28];
  const float* gbn1  = (const float*)d_in[29];
  const float* bbn1  = (const float*)d_in[30];
  const float* gbn2  = (const float*)d_in[31];
  const float* bbn2  = (const float*)d_in[32];
  const float* gbn1h = (const float*)d_in[33];
  const float* bbn1h = (const float*)d_in[34];
  const float* gbn2h = (const float*)d_in[35];
  const float* bbn2h = (const float*)d_in[36];

  float* out_h  = (float*)d_out;
  float* out_sv = out_h + (size_t)N * 128;

  (void)hipMemsetAsync(wsb, 0, stats_off + 4 * 256 * 4, stream);

  WConv wc;
  {
    auto set = [&](int i, int din, int din2, size_t dstoff, int KD, int MD){
      wc.e[i].s  = (const float*)d_in[din];
      wc.e[i].s2 = (din2 >= 0) ? (const float*)d_in[din2] : nullptr;
      wc.e[i].d  = wpool + dstoff;
      wc.e[i].KD = KD; wc.e[i].MD = MD;
      wc.e[i].nfrag = KD * MD / 8;
    };
    for (int i = 0; i < 9; i++) set(i, 4 + i, -1, (size_t)i * 16384, 128, 128);
    set(9,  25, 27, 147456, 128, 256);  // [Wg1;Wg2]
    set(10, 13, -1, 180224, 256, 128);  // Wo
    set(11, 15, -1, 212992, 256, 128);  // Wo_h
    set(12, 17, -1, 245760, 128, 256);  // W1
    set(13, 19, -1, 278528, 256, 128);  // W2
    set(14, 21, -1, 311296, 128, 256);  // W1h
    set(15, 23, -1, 344064, 256, 128);  // W2h
  }
  conv_w_k<<<dim3(16, 16), 256, 0, stream>>>(wc);

  int nelem = N * 128;
  conv2_k<<<dim3((nelem / 4 + 255) / 256, 2), 256, 0, stream>>>(h, sv, h_f, sv_f, nelem);

  const int NB = (N + 1023) / 1024;
  hist_k<<<2048, 256, 0, stream>>>(dst, cnt, E);
  scan_part_k<<<NB, 256, 0, stream>>>(cnt, bsum, N);
  scan_top_k<<<1, 64, 0, stream>>>(bsum, NB);
  scan_out_k<<<NB, 256, 0, stream>>>(cnt, bsum, row_off, cursor, N, E);
  fill_k<<<2048, 256, 0, stream>>>(src, dst, cursor, esrc, E);

  const int GB = (N + 63) / 64;
  const int AB = (N + 3) / 4;
  const int T4 = nelem / 4;
  const int APB = (T4 + 255) / 256;
  const float invN = 1.f / (float)N;

  // h-branch attention pair: self(h) + cross(h; sv)
  gemm_qkv_k<<<GB, 256, 0, stream>>>(h_f, h_f, Wq_sv, Wk_sv, Wv_sv, Q1, K8ab, V16ab, 0, N);
  gemm_qkv_k<<<GB, 256, 0, stream>>>(h_f, sv_f, Wq_cv, Wk_cv, Wv_cv, Q2, K8ab, V16ab, 1, N);
  attn2_k<<<AB, 256, 0, stream>>>(Q1, Q2, K8ab, (const uchar*)V16ab, row_off, esrc, cat_h, N);
  // sv-branch attention pair: self(sv) + cross(sv; h)
  gemm_qkv_k<<<GB, 256, 0, stream>>>(sv_f, sv_f, Wq_sh, Wk_sh, Wv_sh, Q1, K8ab, V16ab, 0, N);
  gemm_qkv_k<<<GB, 256, 0, stream>>>(sv_f, h_f, Wq_cv, Wk_cv, Wv_cv, Q2, K8ab, V16ab, 1, N);
  attn2_k<<<AB, 256, 0, stream>>>(Q1, Q2, K8ab, (const uchar*)V16ab, row_off, esrc, cat_sv, N);

  // ---- h branch ----
  // x1 = h + cat_h@Wo^T + bo  -> Xb1 f16 + stats0
  gemm_k<256,128,3,0,1,256><<<GB, 256, 0, stream>>>(cat_h, Wob, bo, nullptr, h_f, nullptr,
      nullptr, nullptr, nullptr, nullptr, nullptr, nullptr, Xb1, stats, N, invN);
  // u = relu(BN(Xb1)@W1^T + b1) -> cat_h
  gemm_k<128,256,1,1,0,256><<<GB, 256, 0, stream>>>(Xb1, W1b, b1, nullptr, nullptr, nullptr,
      nullptr, nullptr, nullptr, stats, gbn1, bbn1, cat_h, nullptr, N, invN);
  // x2 = BN(Xb1) + u@W2^T + b2 -> Xb2 + stats1
  gemm_k<256,128,5,0,1,256><<<GB, 256, 0, stream>>>(cat_h, W2b, b2, nullptr, Xb1, nullptr,
      stats, gbn1, bbn1, nullptr, nullptr, nullptr, Xb2, stats + 256, N, invN);
  bn_apply_k<<<APB, 256, 0, stream>>>(Xb2, stats + 256, gbn2, bbn2, out_h, T4, invN);

  // ---- sv branch ----
  // gates = sigmoid(h@[Wg1;Wg2]^T + [bg1;bg2]) -> Gb16 (N x 256)
  gemm_k<128,256,2,0,0,256><<<GB, 256, 0, stream>>>(h_f, Wgb, bg1, bg2, nullptr, nullptr,
      nullptr, nullptr, nullptr, nullptr, nullptr, nullptr, Gb16, nullptr, N, invN);
  // svx1 = (1-g1)*sv + g1*(cat_sv@Wo_h^T + bo_h) -> Xb1 + stats2
  gemm_k<256,128,4,0,1,256><<<GB, 256, 0, stream>>>(cat_sv, Wohb, bo_h, nullptr, sv_f, Gb16,
      nullptr, nullptr, nullptr, nullptr, nullptr, nullptr, Xb1, stats + 512, N, invN);
  // uh = relu(BN(Xb1)@W1h^T + b1h) -> cat_sv
  gemm_k<128,256,1,1,0,256><<<GB, 256, 0, stream>>>(Xb1, W1hb, b1h, nullptr, nullptr, nullptr,
      nullptr, nullptr, nullptr, stats + 512, gbn1h, bbn1h, cat_sv, nullptr, N, invN);
  // svx2 = (1-g2)*BN(Xb1) + g2*(uh@W2h^T + b2h) -> Xb2 + stats3
  gemm_k<256,128,6,0,1,256><<<GB, 256, 0, stream>>>(cat_sv, W2hb, b2h, nullptr, Xb1, Gb16 + 128,
      stats + 512, gbn1h, bbn1h, nullptr, nullptr, nullptr, Xb2, stats + 768, N, invN);
  bn_apply_k<<<APB, 256, 0, stream>>>(Xb2, stats + 768, gbn2h, bbn2h, out_sv, T4, invN);
}

// Round 8
// 932.245 us; speedup vs baseline: 1.7378x; 1.1618x over previous
//
#include <hip/hip_runtime.h>

typedef _Float16 f16x8 __attribute__((ext_vector_type(8)));
typedef _Float16 f16x2 __attribute__((ext_vector_type(2)));
typedef __fp16 fp16x2_raw __attribute__((ext_vector_type(2)));
typedef float f32x4 __attribute__((ext_vector_type(4)));
typedef float f32x2 __attribute__((ext_vector_type(2)));
typedef unsigned int uint32;
typedef unsigned short ushort16;
typedef unsigned char uchar;

#define EPS_BN 1e-5f

__device__ __forceinline__ uint32 pk16(float a, float b){
  fp16x2_raw h = __builtin_amdgcn_cvt_pkrtz(a, b);
  return *(uint32*)&h;
}
__device__ __forceinline__ ushort16 f2h(float f){
  _Float16 h = (_Float16)f;
  union { _Float16 h; ushort16 u; } c; c.h = h; return c.u;
}
__device__ __forceinline__ uchar f2fp8(float f){
  uint32 p = __builtin_amdgcn_cvt_pk_fp8_f32(f, f, 0, false);
  return (uchar)(p & 0xff);
}
__device__ __forceinline__ f32x2 fp8pair_lo(uint32 w){
  return __builtin_amdgcn_cvt_pk_f32_fp8(w, false);
}
__device__ __forceinline__ f32x2 fp8pair_hi(uint32 w){
  return __builtin_amdgcn_cvt_pk_f32_fp8(w, true);
}

// ---------------- weight conversion: f32 row-major -> f16 MFMA-fragment-linear ----------------
struct WEnt { const float* s; const float* s2; ushort16* d; int KD, MD, nfrag; };
struct WConv { WEnt e[16]; };

__global__ __launch_bounds__(256) void conv_w_k(WConv a){
  WEnt t = a.e[blockIdx.y];
  int fid = blockIdx.x * 256 + threadIdx.x;
  if (fid >= t.nfrag) return;
  int lane = fid & 63, sm = fid >> 6;
  int MT = t.MD >> 4;
  int s = sm / MT, m = sm - s * MT;
  int row = m * 16 + (lane & 15);
  int col = s * 32 + (lane >> 4) * 8;
  const float* sp = t.s;
  if (t.s2 && row >= 128){ sp = t.s2; row -= 128; }
  const float* p = sp + (size_t)row * t.KD + col;
  uint4 o;
  o.x = pk16(p[0], p[1]); o.y = pk16(p[2], p[3]);
  o.z = pk16(p[4], p[5]); o.w = pk16(p[6], p[7]);
  *(uint4*)(t.d + (size_t)fid * 8) = o;
}

__global__ __launch_bounds__(256) void conv2_k(const float* __restrict__ a, const float* __restrict__ b,
                                               ushort16* __restrict__ da, ushort16* __restrict__ db, int n){
  const float* s = blockIdx.y ? b : a;
  ushort16* d = blockIdx.y ? db : da;
  int i = (blockIdx.x * 256 + threadIdx.x) * 4;
  if (i >= n) return;
  float4 v = *(const float4*)(s + i);
  uint2 p;
  p.x = pk16(v.x, v.y);
  p.y = pk16(v.z, v.w);
  *(uint2*)(d + i) = p;
}

// ---------------- CSR build ----------------
__global__ void hist_k(const int* __restrict__ dst, int* __restrict__ cnt, int E){
  int i = blockIdx.x * blockDim.x + threadIdx.x;
  int stride = gridDim.x * blockDim.x;
  for (; i < E; i += stride) atomicAdd(&cnt[dst[i]], 1);
}

__global__ __launch_bounds__(256) void scan_part_k(const int* __restrict__ cnt, int* __restrict__ bsum, int N){
  int tid = threadIdx.x, lane = tid & 63, wv = tid >> 6;
  int base = blockIdx.x * 1024 + tid * 4;
  int ts = 0;
  #pragma unroll
  for (int j = 0; j < 4; j++) if (base + j < N) ts += cnt[base + j];
  #pragma unroll
  for (int d = 1; d < 64; d <<= 1) ts += __shfl_xor(ts, d);
  __shared__ int wt[4];
  if (lane == 0) wt[wv] = ts;
  __syncthreads();
  if (tid == 0) bsum[blockIdx.x] = wt[0] + wt[1] + wt[2] + wt[3];
}

__global__ __launch_bounds__(64) void scan_top_k(int* __restrict__ bsum, int nb){
  int tid = threadIdx.x;
  int v = (tid < nb) ? bsum[tid] : 0;
  int inc = v;
  #pragma unroll
  for (int d = 1; d < 64; d <<= 1){
    int t = __shfl_up(inc, d);
    if (tid >= d) inc += t;
  }
  if (tid < nb) bsum[tid] = inc - v;
}

__global__ __launch_bounds__(256) void scan_out_k(const int* __restrict__ cnt, const int* __restrict__ bsum,
                                                  int* __restrict__ row_off, int* __restrict__ cursor,
                                                  int N, int E){
  int tid = threadIdx.x, lane = tid & 63, wv = tid >> 6;
  int base = blockIdx.x * 1024 + tid * 4;
  int c[4]; int ts = 0;
  #pragma unroll
  for (int j = 0; j < 4; j++){ c[j] = (base + j < N) ? cnt[base + j] : 0; ts += c[j]; }
  int inc = ts;
  #pragma unroll
  for (int d = 1; d < 64; d <<= 1){
    int t = __shfl_up(inc, d);
    if (lane >= d) inc += t;
  }
  int wexcl = inc - ts;
  __shared__ int wt[4];
  if (lane == 63) wt[wv] = inc;
  __syncthreads();
  int woff = 0;
  for (int w = 0; w < 4; w++) if (w < wv) woff += wt[w];
  int off = bsum[blockIdx.x] + woff + wexcl;
  #pragma unroll
  for (int j = 0; j < 4; j++){
    if (base + j < N){ row_off[base + j] = off; cursor[base + j] = off; off += c[j]; }
  }
  if (blockIdx.x == 0 && tid == 0) row_off[N] = E;
}

__global__ void fill_k(const int* __restrict__ src, const int* __restrict__ dst,
                       int* __restrict__ cursor, int* __restrict__ esrc, int E){
  int i = blockIdx.x * blockDim.x + threadIdx.x;
  int stride = gridDim.x * blockDim.x;
  for (; i < E; i += stride){
    int d = dst[i];
    int p = atomicAdd(&cursor[d], 1);
    esrc[p] = src[i];
  }
}

// ---------------- fused QKV projection, LDS-staged coalesced stores ----------------
// Q: f16 row-major (256 B/row); K,V: fp8 row-major (128 B/row each)
__global__ __launch_bounds__(256) void gemm_qkv_k(
    const ushort16* __restrict__ Xq, const ushort16* __restrict__ Xkv,
    const ushort16* __restrict__ Wq, const ushort16* __restrict__ Wk, const ushort16* __restrict__ Wv,
    ushort16* __restrict__ Qo, uchar* __restrict__ K8, uchar* __restrict__ V8, int N)
{
  __shared__ _Float16 Qs[4][16 * 136];
  __shared__ uchar Ks[4][16 * 136];
  __shared__ uchar Vs[4][16 * 136];
  int lane = threadIdx.x & 63, wv = threadIdx.x >> 6;
  int l15 = lane & 15, kq = lane >> 4;
  int rowbase = (blockIdx.x * 4 + wv) * 16;
  int row = rowbase + l15;
  int rc = row < N ? row : N - 1;
  const f16x8* aq = (const f16x8*)(Xq + (size_t)rc * 128 + kq * 8);
  const f16x8* ak = (const f16x8*)(Xkv + (size_t)rc * 128 + kq * 8);
  f16x8 Aq[4], Ak[4];
  #pragma unroll
  for (int s = 0; s < 4; s++){ Aq[s] = aq[s * 4]; Ak[s] = ak[s * 4]; }
  const f16x8* Wqf = (const f16x8*)Wq;
  const f16x8* Wkf = (const f16x8*)Wk;
  const f16x8* Wvf = (const f16x8*)Wv;
  f32x4 q[8], k[8], v[8];
  #pragma unroll
  for (int m = 0; m < 8; m++){ q[m] = (f32x4)(0.f); k[m] = (f32x4)(0.f); v[m] = (f32x4)(0.f); }
  #pragma unroll
  for (int s = 0; s < 4; s++){
    #pragma unroll
    for (int m = 0; m < 8; m++){
      int fi = (s * 8 + m) * 64 + lane;
      q[m] = __builtin_amdgcn_mfma_f32_16x16x32_f16(Aq[s], Wqf[fi], q[m], 0, 0, 0);
      k[m] = __builtin_amdgcn_mfma_f32_16x16x32_f16(Ak[s], Wkf[fi], k[m], 0, 0, 0);
      v[m] = __builtin_amdgcn_mfma_f32_16x16x32_f16(Ak[s], Wvf[fi], v[m], 0, 0, 0);
    }
  }
  // stage into per-wave LDS (C-layout -> row-linear); same-wave cross-lane, no barrier needed
  #pragma unroll
  for (int m = 0; m < 8; m++){
    int col = m * 16 + l15;
    #pragma unroll
    for (int r = 0; r < 4; r++){
      int lrow = kq * 4 + r;
      Qs[wv][lrow * 136 + col] = (_Float16)q[m][r];
      Ks[wv][lrow * 136 + col] = f2fp8(k[m][r]);
      Vs[wv][lrow * 136 + col] = f2fp8(v[m][r]);
    }
  }
  // coalesced stores: Q 4 passes x 16B/lane; K/V 4 passes x 8B/lane
  #pragma unroll
  for (int p = 0; p < 4; p++){
    int lrow = p * 4 + (lane >> 4);
    int rr = rowbase + lrow;
    int col8 = l15 * 8;
    if (rr < N){
      uint4 qv = *(uint4*)&Qs[wv][lrow * 136 + col8];
      *(uint4*)(Qo + (size_t)rr * 128 + col8) = qv;
      uint2 kv = *(uint2*)&Ks[wv][lrow * 136 + col8];
      *(uint2*)(K8 + (size_t)rr * 128 + col8) = kv;
      uint2 vv = *(uint2*)&Vs[wv][lrow * 136 + col8];
      *(uint2*)(V8 + (size_t)rr * 128 + col8) = vv;
    }
  }
}

// ---------------- generic GEMM, swizzled W, f16 in/out, LDS-staged stores ----------------
// EPI: 1=relu, 2=sigmoid, 3=+res(f16), 4=gate w/ res(f16), 5=+BN(res), 6=gate w/ BN(res)
// ABN=1: apply BN to A on load. ST=1: accumulate column stats.
template<int KD, int MD, int EPI, int ABN, int ST, int GS>
__global__ __launch_bounds__(256) void gemm_k(
    const ushort16* __restrict__ X, const ushort16* __restrict__ W,
    const float* __restrict__ bias, const float* __restrict__ bias2,
    const ushort16* __restrict__ resb, const ushort16* __restrict__ gatep,
    const float* __restrict__ rstats, const float* __restrict__ rg, const float* __restrict__ rb,
    const float* __restrict__ astats, const float* __restrict__ ag, const float* __restrict__ ab,
    ushort16* __restrict__ outb, float* __restrict__ stats_out, int N, float invN)
{
  constexpr int KS = KD / 32;
  constexpr int MT = MD / 16;
  constexpr int LSTR = MD + 8;
  __shared__ _Float16 Os[4][16 * LSTR];
  int lane = threadIdx.x & 63, wv = threadIdx.x >> 6;
  int l15 = lane & 15, kq = lane >> 4;
  int rowbase = (blockIdx.x * 4 + wv) * 16;
  int row = rowbase + l15;
  int rc = row < N ? row : N - 1;
  const f16x8* ap = (const f16x8*)(X + (size_t)rc * KD + kq * 8);
  f16x8 a[KS];
  #pragma unroll
  for (int s = 0; s < KS; s++) a[s] = ap[s * 4];
  if constexpr (ABN){
    #pragma unroll
    for (int s = 0; s < KS; s++){
      #pragma unroll
      for (int j = 0; j < 8; j++){
        int c = s * 32 + kq * 8 + j;
        float mm = astats[c] * invN;
        float var = astats[128 + c] * invN - mm * mm;
        float rs = rsqrtf(var + EPS_BN);
        float scc = rs * ag[c];
        float shh = ab[c] - mm * scc;
        a[s][j] = (_Float16)((float)a[s][j] * scc + shh);
      }
    }
  }
  const f16x8* Wf = (const f16x8*)W;
  f32x4 acc[MT];
  #pragma unroll
  for (int m = 0; m < MT; m++) acc[m] = (f32x4)(0.f);
  #pragma unroll
  for (int s = 0; s < KS; s++){
    #pragma unroll
    for (int m = 0; m < MT; m++){
      acc[m] = __builtin_amdgcn_mfma_f32_16x16x32_f16(a[s], Wf[(s * MT + m) * 64 + lane], acc[m], 0, 0, 0);
    }
  }
  float ps[MT], ps2[MT];
  if constexpr (ST){
    #pragma unroll
    for (int m = 0; m < MT; m++){ ps[m] = 0.f; ps2[m] = 0.f; }
  }
  int r0 = rowbase + kq * 4;
  #pragma unroll
  for (int m = 0; m < MT; m++){
    int col = m * 16 + l15;
    float bv;
    if (bias2 && col >= 128) bv = bias2[col - 128];
    else bv = bias[col];
    float sc = 0.f, sh = 0.f;
    if constexpr (EPI == 5 || EPI == 6){
      float mm = rstats[col] * invN;
      float var = rstats[128 + col] * invN - mm * mm;
      float rs = rsqrtf(var + EPS_BN);
      sc = rs * rg[col]; sh = rb[col] - mm * sc;
    }
    #pragma unroll
    for (int r = 0; r < 4; r++){
      int rr = r0 + r;
      float v;
      {
        int rrc = rr < N ? rr : N - 1;
        v = acc[m][r] + bv;
        if constexpr (EPI == 1) v = fmaxf(v, 0.f);
        if constexpr (EPI == 2) v = 1.f / (1.f + __expf(-v));
        if constexpr (EPI == 3){
          union { ushort16 u; _Float16 h; } cv; cv.u = resb[(size_t)rrc * 128 + col];
          v += (float)cv.h;
        }
        if constexpr (EPI == 5){
          union { ushort16 u; _Float16 h; } cv; cv.u = resb[(size_t)rrc * 128 + col];
          v += (float)cv.h * sc + sh;
        }
        if constexpr (EPI == 4 || EPI == 6){
          union { ushort16 u; _Float16 h; } gv; gv.u = gatep[(size_t)rrc * GS + col];
          union { ushort16 u; _Float16 h; } cv; cv.u = resb[(size_t)rrc * 128 + col];
          float g = (float)gv.h;
          float rv = (float)cv.h;
          if constexpr (EPI == 6) rv = rv * sc + sh;
          v = (1.f - g) * rv + g * v;
        }
      }
      Os[wv][(kq * 4 + r) * LSTR + col] = (_Float16)v;
      if constexpr (ST){
        if (rr < N){ ps[m] += v; ps2[m] += v * v; }
      }
    }
  }
  // coalesced stores from LDS
  if constexpr (MD == 128){
    #pragma unroll
    for (int p = 0; p < 4; p++){
      int lrow = p * 4 + (lane >> 4);
      int rr = rowbase + lrow;
      int col8 = l15 * 8;
      if (rr < N){
        uint4 ov = *(uint4*)&Os[wv][lrow * LSTR + col8];
        *(uint4*)(outb + (size_t)rr * MD + col8) = ov;
      }
    }
  } else {
    #pragma unroll
    for (int p = 0; p < 8; p++){
      int lrow = p * 2 + (lane >> 5);
      int rr = rowbase + lrow;
      int col8 = (lane & 31) * 8;
      if (rr < N){
        uint4 ov = *(uint4*)&Os[wv][lrow * LSTR + col8];
        *(uint4*)(outb + (size_t)rr * MD + col8) = ov;
      }
    }
  }
  if constexpr (ST){
    __shared__ float sst[4][128];
    __shared__ float sst2[4][128];
    #pragma unroll
    for (int m = 0; m < MT; m++){
      float s = ps[m], s2 = ps2[m];
      s  += __shfl_xor(s, 16);  s  += __shfl_xor(s, 32);
      s2 += __shfl_xor(s2, 16); s2 += __shfl_xor(s2, 32);
      if (lane < 16){ sst[wv][m * 16 + l15] = s; sst2[wv][m * 16 + l15] = s2; }
    }
    __syncthreads();
    int tid = threadIdx.x;
    if (tid < 128){
      atomicAdd(&stats_out[tid], sst[0][tid] + sst[1][tid] + sst[2][tid] + sst[3][tid]);
    } else {
      int c = tid - 128;
      atomicAdd(&stats_out[tid], sst2[0][c] + sst2[1][c] + sst2[2][c] + sst2[3][c]);
    }
  }
}

// ---------------- fused dual-attention (fp8 K, fp8 V) ----------------
__global__ __launch_bounds__(256) void attn2_k(
    const ushort16* __restrict__ Qa, const ushort16* __restrict__ Qb,
    const uchar* __restrict__ K8a, const uchar* __restrict__ V8a,
    const uchar* __restrict__ K8b, const uchar* __restrict__ V8b,
    const int* __restrict__ row_off, const int* __restrict__ esrc,
    ushort16* __restrict__ cat, int N)
{
  int wv = threadIdx.x >> 6, lane = threadIdx.x & 63;
  int n = blockIdx.x * 4 + wv;
  if (n >= N) return;
  int h = lane >> 5, j = lane & 31;
  uint2 qau = *(const uint2*)(Qa + (size_t)n * 128 + j * 4);
  uint2 qbu = *(const uint2*)(Qb + (size_t)n * 128 + j * 4);
  f16x2 qa01 = *(f16x2*)&qau.x, qa23 = *(f16x2*)&qau.y;
  f16x2 qb01 = *(f16x2*)&qbu.x, qb23 = *(f16x2*)&qbu.y;
  float qa0 = (float)qa01.x * 0.25f, qa1 = (float)qa01.y * 0.25f;
  float qa2 = (float)qa23.x * 0.25f, qa3 = (float)qa23.y * 0.25f;
  float qb0 = (float)qb01.x * 0.25f, qb1 = (float)qb01.y * 0.25f;
  float qb2 = (float)qb23.x * 0.25f, qb3 = (float)qb23.y * 0.25f;
  int e0 = row_off[n], e1 = row_off[n + 1];
  int deg = e1 - e0;
  int itmax = (deg + 1) >> 1;
  float a0 = 0.f, a1 = 0.f, a2 = 0.f, a3 = 0.f, za = 0.f;
  float b0 = 0.f, b1 = 0.f, b2 = 0.f, b3 = 0.f, zb = 0.f;
  int e = e0 + h;
  int s = (e < e1) ? esrc[e] : -1;
  int sc = s < 0 ? 0 : s;
  uint32 kwa = *(const uint32*)(K8a + (size_t)sc * 128 + j * 4);
  uint32 kwb = *(const uint32*)(K8b + (size_t)sc * 128 + j * 4);
  uint32 vwa = *(const uint32*)(V8a + (size_t)sc * 128 + j * 4);
  uint32 vwb = *(const uint32*)(V8b + (size_t)sc * 128 + j * 4);
  for (int it = 0; it < itmax; ++it){
    int e2 = e + 2;
    int s2 = (e2 < e1) ? esrc[e2] : -1;
    int s2c = s2 < 0 ? 0 : s2;
    uint32 kwa2 = *(const uint32*)(K8a + (size_t)s2c * 128 + j * 4);
    uint32 kwb2 = *(const uint32*)(K8b + (size_t)s2c * 128 + j * 4);
    uint32 vwa2 = *(const uint32*)(V8a + (size_t)s2c * 128 + j * 4);
    uint32 vwb2 = *(const uint32*)(V8b + (size_t)s2c * 128 + j * 4);
    if (s >= 0){
      f32x2 ka01 = fp8pair_lo(kwa), ka23 = fp8pair_hi(kwa);
      f32x2 kb01 = fp8pair_lo(kwb), kb23 = fp8pair_hi(kwb);
      float da = fmaf(ka01.x, qa0, fmaf(ka01.y, qa1, fmaf(ka23.x, qa2, ka23.y * qa3)));
      float db = fmaf(kb01.x, qb0, fmaf(kb01.y, qb1, fmaf(kb23.x, qb2, kb23.y * qb3)));
      da += __shfl_xor(da, 1); da += __shfl_xor(da, 2);
      db += __shfl_xor(db, 1); db += __shfl_xor(db, 2);
      float sa = __expf(fminf(fmaxf(da, -5.f), 5.f));
      float sb = __expf(fminf(fmaxf(db, -5.f), 5.f));
      f32x2 va01 = fp8pair_lo(vwa), va23 = fp8pair_hi(vwa);
      f32x2 vb01 = fp8pair_lo(vwb), vb23 = fp8pair_hi(vwb);
      a0 = fmaf(sa, va01.x, a0); a1 = fmaf(sa, va01.y, a1);
      a2 = fmaf(sa, va23.x, a2); a3 = fmaf(sa, va23.y, a3);
      za += sa;
      b0 = fmaf(sb, vb01.x, b0); b1 = fmaf(sb, vb01.y, b1);
      b2 = fmaf(sb, vb23.x, b2); b3 = fmaf(sb, vb23.y, b3);
      zb += sb;
    }
    e = e2; s = s2;
    kwa = kwa2; kwb = kwb2; vwa = vwa2; vwb = vwb2;
  }
  a0 += __shfl_xor(a0, 32); a1 += __shfl_xor(a1, 32);
  a2 += __shfl_xor(a2, 32); a3 += __shfl_xor(a3, 32);
  za += __shfl_xor(za, 32);
  b0 += __shfl_xor(b0, 32); b1 += __shfl_xor(b1, 32);
  b2 += __shfl_xor(b2, 32); b3 += __shfl_xor(b3, 32);
  zb += __shfl_xor(zb, 32);
  uint2 o;
  if (h == 0){
    float rz = __builtin_amdgcn_rcpf(za);
    o.x = pk16(a0 * rz, a1 * rz);
    o.y = pk16(a2 * rz, a3 * rz);
    *(uint2*)(cat + (size_t)n * 256 + j * 4) = o;
  } else {
    float rz = __builtin_amdgcn_rcpf(zb);
    o.x = pk16(b0 * rz, b1 * rz);
    o.y = pk16(b2 * rz, b3 * rz);
    *(uint2*)(cat + (size_t)n * 256 + 128 + j * 4) = o;
  }
}

// ---------------- BatchNorm apply (f16 in, f32 out) ----------------
__global__ __launch_bounds__(256) void bn_apply_k(
    const ushort16* __restrict__ x, const float* __restrict__ stats,
    const float* __restrict__ gamma, const float* __restrict__ beta,
    float* __restrict__ outf, int total4, float invN)
{
  int i = blockIdx.x * 256 + threadIdx.x;
  if (i >= total4) return;
  uint2 xp = *(const uint2*)(x + (size_t)i * 4);
  f16x2 x01 = *(f16x2*)&xp.x, x23 = *(f16x2*)&xp.y;
  float xv[4] = {(float)x01.x, (float)x01.y, (float)x23.x, (float)x23.y};
  int c0 = (i * 4) & 127;
  float o[4];
  #pragma unroll
  for (int j = 0; j < 4; j++){
    int c = c0 + j;
    float m = stats[c] * invN;
    float var = stats[128 + c] * invN - m * m;
    float rstd = rsqrtf(var + EPS_BN);
    o[j] = (xv[j] - m) * rstd * gamma[c] + beta[c];
  }
  *(float4*)(outf + (size_t)i * 4) = make_float4(o[0], o[1], o[2], o[3]);
}

// ---------------- host ----------------
extern "C" void kernel_launch(void* const* d_in, const int* in_sizes, int n_in,
                              void* d_out, int out_size, void* d_ws, size_t ws_size,
                              hipStream_t stream) {
  const float* h   = (const float*)d_in[0];
  const float* sv  = (const float*)d_in[1];
  const int* src   = (const int*)d_in[2];
  const int* dst   = (const int*)d_in[3];
  const int N = in_sizes[0] / 128;
  const int E = in_sizes[2];

  char* wsb = (char*)d_ws;
  size_t o = 0;
  auto take = [&](size_t bytes)->size_t{
    size_t r = o;
    o = (o + bytes + 255) & ~(size_t)255;
    return r;
  };
  size_t cnt_off    = take((size_t)N * 4);
  size_t stats_off  = take(4 * 256 * 4);
  size_t rowoff_off = take((size_t)(N + 1) * 4);
  size_t cursor_off = take((size_t)N * 4);
  size_t bsum_off   = take(256 * 4);
  size_t esrc_off   = take((size_t)E * 4);
  size_t wpool_off  = take((size_t)376832 * 2);
  size_t hf_off     = take((size_t)N * 128 * 2);
  size_t svf_off    = take((size_t)N * 128 * 2);
  size_t cath_off   = take((size_t)N * 256 * 2);
  size_t catsv_off  = take((size_t)N * 256 * 2);
  size_t K81_off    = take((size_t)N * 128);
  size_t V81_off    = take((size_t)N * 128);
  size_t K82_off    = take((size_t)N * 128);
  size_t V82_off    = take((size_t)N * 128);
  size_t Q1_off     = take((size_t)N * 128 * 2);
  size_t Q2_off     = take((size_t)N * 128 * 2);
  size_t X1_off     = take((size_t)N * 128 * 2);
  size_t X2_off     = take((size_t)N * 128 * 2);
  size_t G_off      = take((size_t)N * 256 * 2);

  int*    cnt     = (int*)(wsb + cnt_off);
  float*  stats   = (float*)(wsb + stats_off);
  int*    row_off = (int*)(wsb + rowoff_off);
  int*    cursor  = (int*)(wsb + cursor_off);
  int*    bsum    = (int*)(wsb + bsum_off);
  int*    esrc    = (int*)(wsb + esrc_off);
  ushort16* wpool = (ushort16*)(wsb + wpool_off);
  ushort16* h_f   = (ushort16*)(wsb + hf_off);
  ushort16* sv_f  = (ushort16*)(wsb + svf_off);
  ushort16* cat_h = (ushort16*)(wsb + cath_off);
  ushort16* cat_sv= (ushort16*)(wsb + catsv_off);
  uchar*    K8_1  = (uchar*)(wsb + K81_off);
  uchar*    V8_1  = (uchar*)(wsb + V81_off);
  uchar*    K8_2  = (uchar*)(wsb + K82_off);
  uchar*    V8_2  = (uchar*)(wsb + V82_off);
  ushort16* Q1    = (ushort16*)(wsb + Q1_off);
  ushort16* Q2    = (ushort16*)(wsb + Q2_off);
  ushort16* Xb1   = (ushort16*)(wsb + X1_off);
  ushort16* Xb2   = (ushort16*)(wsb + X2_off);
  ushort16* Gb16  = (ushort16*)(wsb + G_off);

  ushort16* Wq_sv = wpool + 0 * 16384;
  ushort16* Wk_sv = wpool + 1 * 16384;
  ushort16* Wv_sv = wpool + 2 * 16384;
  ushort16* Wq_cv = wpool + 3 * 16384;
  ushort16* Wk_cv = wpool + 4 * 16384;
  ushort16* Wv_cv = wpool + 5 * 16384;
  ushort16* Wq_sh = wpool + 6 * 16384;
  ushort16* Wk_sh = wpool + 7 * 16384;
  ushort16* Wv_sh = wpool + 8 * 16384;
  ushort16* Wgb   = wpool + 147456;
  ushort16* Wob   = wpool + 180224;
  ushort16* Wohb  = wpool + 212992;
  ushort16* W1b   = wpool + 245760;
  ushort16* W2b   = wpool + 278528;
  ushort16* W1hb  = wpool + 311296;
  ushort16* W2hb  = wpool + 344064;

  const float* bo   = (const float*)d_in[14];
  const float* bo_h = (const float*)d_in[16];
  const float* b1   = (const float*)d_in[18];
  const float* b2   = (const float*)d_in[20];
  const float* b1h  = (const float*)d_in[22];
  const float* b2h  = (const float*)d_in[24];
  const float* bg1  = (const float*)d_in[26];
  const float* bg2  = (const float*)d_in[28];
  const float* gbn1  = (const float*)d_in[29];
  const float* bbn1  = (const float*)d_in[30];
  const float* gbn2  = (const float*)d_in[31];
  const float* bbn2  = (const float*)d_in[32];
  const float* gbn1h = (const float*)d_in[33];
  const float* bbn1h = (const float*)d_in[34];
  const float* gbn2h = (const float*)d_in[35];
  const float* bbn2h = (const float*)d_in[36];

  float* out_h  = (float*)d_out;
  float* out_sv = out_h + (size_t)N * 128;

  (void)hipMemsetAsync(wsb, 0, stats_off + 4 * 256 * 4, stream);

  WConv wc;
  {
    auto set = [&](int i, int din, int din2, size_t dstoff, int KD, int MD){
      wc.e[i].s  = (const float*)d_in[din];
      wc.e[i].s2 = (din2 >= 0) ? (const float*)d_in[din2] : nullptr;
      wc.e[i].d  = wpool + dstoff;
      wc.e[i].KD = KD; wc.e[i].MD = MD;
      wc.e[i].nfrag = KD * MD / 8;
    };
    for (int i = 0; i < 9; i++) set(i, 4 + i, -1, (size_t)i * 16384, 128, 128);
    set(9,  25, 27, 147456, 128, 256);
    set(10, 13, -1, 180224, 256, 128);
    set(11, 15, -1, 212992, 256, 128);
    set(12, 17, -1, 245760, 128, 256);
    set(13, 19, -1, 278528, 256, 128);
    set(14, 21, -1, 311296, 128, 256);
    set(15, 23, -1, 344064, 256, 128);
  }
  conv_w_k<<<dim3(16, 16), 256, 0, stream>>>(wc);

  int nelem = N * 128;
  conv2_k<<<dim3((nelem / 4 + 255) / 256, 2), 256, 0, stream>>>(h, sv, h_f, sv_f, nelem);

  const int NB = (N + 1023) / 1024;
  hist_k<<<2048, 256, 0, stream>>>(dst, cnt, E);
  scan_part_k<<<NB, 256, 0, stream>>>(cnt, bsum, N);
  scan_top_k<<<1, 64, 0, stream>>>(bsum, NB);
  scan_out_k<<<NB, 256, 0, stream>>>(cnt, bsum, row_off, cursor, N, E);
  fill_k<<<2048, 256, 0, stream>>>(src, dst, cursor, esrc, E);

  const int GB = (N + 63) / 64;
  const int AB = (N + 3) / 4;
  const int T4 = nelem / 4;
  const int APB = (T4 + 255) / 256;
  const float invN = 1.f / (float)N;

  // h-branch attention pair
  gemm_qkv_k<<<GB, 256, 0, stream>>>(h_f, h_f, Wq_sv, Wk_sv, Wv_sv, Q1, K8_1, V8_1, N);
  gemm_qkv_k<<<GB, 256, 0, stream>>>(h_f, sv_f, Wq_cv, Wk_cv, Wv_cv, Q2, K8_2, V8_2, N);
  attn2_k<<<AB, 256, 0, stream>>>(Q1, Q2, K8_1, V8_1, K8_2, V8_2, row_off, esrc, cat_h, N);
  // sv-branch attention pair
  gemm_qkv_k<<<GB, 256, 0, stream>>>(sv_f, sv_f, Wq_sh, Wk_sh, Wv_sh, Q1, K8_1, V8_1, N);
  gemm_qkv_k<<<GB, 256, 0, stream>>>(sv_f, h_f, Wq_cv, Wk_cv, Wv_cv, Q2, K8_2, V8_2, N);
  attn2_k<<<AB, 256, 0, stream>>>(Q1, Q2, K8_1, V8_1, K8_2, V8_2, row_off, esrc, cat_sv, N);

  // ---- h branch ----
  gemm_k<256,128,3,0,1,256><<<GB, 256, 0, stream>>>(cat_h, Wob, bo, nullptr, h_f, nullptr,
      nullptr, nullptr, nullptr, nullptr, nullptr, nullptr, Xb1, stats, N, invN);
  gemm_k<128,256,1,1,0,256><<<GB, 256, 0, stream>>>(Xb1, W1b, b1, nullptr, nullptr, nullptr,
      nullptr, nullptr, nullptr, stats, gbn1, bbn1, cat_h, nullptr, N, invN);
  gemm_k<256,128,5,0,1,256><<<GB, 256, 0, stream>>>(cat_h, W2b, b2, nullptr, Xb1, nullptr,
      stats, gbn1, bbn1, nullptr, nullptr, nullptr, Xb2, stats + 256, N, invN);
  bn_apply_k<<<APB, 256, 0, stream>>>(Xb2, stats + 256, gbn2, bbn2, out_h, T4, invN);

  // ---- sv branch ----
  gemm_k<128,256,2,0,0,256><<<GB, 256, 0, stream>>>(h_f, Wgb, bg1, bg2, nullptr, nullptr,
      nullptr, nullptr, nullptr, nullptr, nullptr, nullptr, Gb16, nullptr, N, invN);
  gemm_k<256,128,4,0,1,256><<<GB, 256, 0, stream>>>(cat_sv, Wohb, bo_h, nullptr, sv_f, Gb16,
      nullptr, nullptr, nullptr, nullptr, nullptr, nullptr, Xb1, stats + 512, N, invN);
  gemm_k<128,256,1,1,0,256><<<GB, 256, 0, stream>>>(Xb1, W1hb, b1h, nullptr, nullptr, nullptr,
      nullptr, nullptr, nullptr, stats + 512, gbn1h, bbn1h, cat_sv, nullptr, N, invN);
  gemm_k<256,128,6,0,1,256><<<GB, 256, 0, stream>>>(cat_sv, W2hb, b2h, nullptr, Xb1, Gb16 + 128,
      stats + 512, gbn1h, bbn1h, nullptr, nullptr, nullptr, Xb2, stats + 768, N, invN);
  bn_apply_k<<<APB, 256, 0, stream>>>(Xb2, stats + 768, gbn2h, bbn2h, out_sv, T4, invN);
}

// Round 9
// 895.721 us; speedup vs baseline: 1.8087x; 1.0408x over previous
//
#include <hip/hip_runtime.h>

typedef _Float16 f16x8 __attribute__((ext_vector_type(8)));
typedef _Float16 f16x2 __attribute__((ext_vector_type(2)));
typedef __fp16 fp16x2_raw __attribute__((ext_vector_type(2)));
typedef float f32x4 __attribute__((ext_vector_type(4)));
typedef float f32x2 __attribute__((ext_vector_type(2)));
typedef unsigned int uint32;
typedef unsigned short ushort16;
typedef unsigned char uchar;

#define EPS_BN 1e-5f

__device__ __forceinline__ uint32 pk16(float a, float b){
  fp16x2_raw h = __builtin_amdgcn_cvt_pkrtz(a, b);
  return *(uint32*)&h;
}
__device__ __forceinline__ ushort16 f2h(float f){
  _Float16 h = (_Float16)f;
  union { _Float16 h; ushort16 u; } c; c.h = h; return c.u;
}
__device__ __forceinline__ uchar f2fp8(float f){
  uint32 p = __builtin_amdgcn_cvt_pk_fp8_f32(f, f, 0, false);
  return (uchar)(p & 0xff);
}
__device__ __forceinline__ f32x2 fp8pair_lo(uint32 w){
  return __builtin_amdgcn_cvt_pk_f32_fp8(w, false);
}
__device__ __forceinline__ f32x2 fp8pair_hi(uint32 w){
  return __builtin_amdgcn_cvt_pk_f32_fp8(w, true);
}

// ---------------- weight conversion: f32 row-major -> f16 MFMA-fragment-linear ----------------
struct WEnt { const float* s; const float* s2; ushort16* d; int KD, MD, nfrag; };
struct WConv { WEnt e[16]; };

__global__ __launch_bounds__(256) void conv_w_k(WConv a){
  WEnt t = a.e[blockIdx.y];
  int fid = blockIdx.x * 256 + threadIdx.x;
  if (fid >= t.nfrag) return;
  int lane = fid & 63, sm = fid >> 6;
  int MT = t.MD >> 4;
  int s = sm / MT, m = sm - s * MT;
  int row = m * 16 + (lane & 15);
  int col = s * 32 + (lane >> 4) * 8;
  const float* sp = t.s;
  if (t.s2 && row >= 128){ sp = t.s2; row -= 128; }
  const float* p = sp + (size_t)row * t.KD + col;
  uint4 o;
  o.x = pk16(p[0], p[1]); o.y = pk16(p[2], p[3]);
  o.z = pk16(p[4], p[5]); o.w = pk16(p[6], p[7]);
  *(uint4*)(t.d + (size_t)fid * 8) = o;
}

__global__ __launch_bounds__(256) void conv2_k(const float* __restrict__ a, const float* __restrict__ b,
                                               ushort16* __restrict__ da, ushort16* __restrict__ db, int n){
  const float* s = blockIdx.y ? b : a;
  ushort16* d = blockIdx.y ? db : da;
  int i = (blockIdx.x * 256 + threadIdx.x) * 4;
  if (i >= n) return;
  float4 v = *(const float4*)(s + i);
  uint2 p;
  p.x = pk16(v.x, v.y);
  p.y = pk16(v.z, v.w);
  *(uint2*)(d + i) = p;
}

// ---------------- CSR build ----------------
__global__ void hist_k(const int* __restrict__ dst, int* __restrict__ cnt, int E){
  int i = blockIdx.x * blockDim.x + threadIdx.x;
  int stride = gridDim.x * blockDim.x;
  for (; i < E; i += stride) atomicAdd(&cnt[dst[i]], 1);
}

__global__ __launch_bounds__(256) void scan_part_k(const int* __restrict__ cnt, int* __restrict__ bsum, int N){
  int tid = threadIdx.x, lane = tid & 63, wv = tid >> 6;
  int base = blockIdx.x * 1024 + tid * 4;
  int ts = 0;
  #pragma unroll
  for (int j = 0; j < 4; j++) if (base + j < N) ts += cnt[base + j];
  #pragma unroll
  for (int d = 1; d < 64; d <<= 1) ts += __shfl_xor(ts, d);
  __shared__ int wt[4];
  if (lane == 0) wt[wv] = ts;
  __syncthreads();
  if (tid == 0) bsum[blockIdx.x] = wt[0] + wt[1] + wt[2] + wt[3];
}

__global__ __launch_bounds__(64) void scan_top_k(int* __restrict__ bsum, int nb){
  int tid = threadIdx.x;
  int v = (tid < nb) ? bsum[tid] : 0;
  int inc = v;
  #pragma unroll
  for (int d = 1; d < 64; d <<= 1){
    int t = __shfl_up(inc, d);
    if (tid >= d) inc += t;
  }
  if (tid < nb) bsum[tid] = inc - v;
}

// stage 3: write row_off/cursor (+ per-bucket cursors for the binned fill)
__global__ __launch_bounds__(256) void scan_out_k(const int* __restrict__ cnt, const int* __restrict__ bsum,
                                                  int* __restrict__ row_off, int* __restrict__ cursor,
                                                  int* __restrict__ bcur,
                                                  int N, int E, int shift){
  int tid = threadIdx.x, lane = tid & 63, wv = tid >> 6;
  int base = blockIdx.x * 1024 + tid * 4;
  int c[4]; int ts = 0;
  #pragma unroll
  for (int j = 0; j < 4; j++){ c[j] = (base + j < N) ? cnt[base + j] : 0; ts += c[j]; }
  int inc = ts;
  #pragma unroll
  for (int d = 1; d < 64; d <<= 1){
    int t = __shfl_up(inc, d);
    if (lane >= d) inc += t;
  }
  int wexcl = inc - ts;
  __shared__ int wt[4];
  if (lane == 63) wt[wv] = inc;
  __syncthreads();
  int woff = 0;
  for (int w = 0; w < 4; w++) if (w < wv) woff += wt[w];
  int off = bsum[blockIdx.x] + woff + wexcl;
  int mask = (1 << shift) - 1;
  #pragma unroll
  for (int j = 0; j < 4; j++){
    int d = base + j;
    if (d < N){
      row_off[d] = off; cursor[d] = off;
      if ((d & mask) == 0) bcur[d >> shift] = off;
      off += c[j];
    }
  }
  if (blockIdx.x == 0 && tid == 0) row_off[N] = E;
}

// ---------------- bucketed fill: pass 1, LDS-binned grouping by dst bucket ----------------
#define BIN_TB 512
#define BIN_TILE 4096
__global__ __launch_bounds__(512) void bin_k(const int* __restrict__ src, const int* __restrict__ dst,
                                             int* __restrict__ bcur, uint2* __restrict__ ebuf,
                                             int E, int shift, int B){
  __shared__ int lhist[128];
  __shared__ int lstart[128];
  __shared__ int gbase[128];
  __shared__ uint2 lpair[BIN_TILE];
  int tid = threadIdx.x;
  int base = blockIdx.x * BIN_TILE;
  int cnt = E - base; if (cnt > BIN_TILE) cnt = BIN_TILE;
  if (tid < 128) lhist[tid] = 0;
  __syncthreads();
  int myb[8], myrank[8];
  uint2 myp[8];
  int nmine = 0;
  #pragma unroll
  for (int j = 0; j < 8; j++){
    int i = tid + j * BIN_TB;
    if (i < cnt){
      int s = src[base + i], d = dst[base + i];
      int b = d >> shift;
      myp[nmine] = make_uint2((uint32)s, (uint32)d);
      myb[nmine] = b;
      myrank[nmine] = atomicAdd(&lhist[b], 1);
      nmine++;
    }
  }
  __syncthreads();
  if (tid == 0){
    int run = 0;
    for (int b = 0; b < B; b++){ lstart[b] = run; run += lhist[b]; }
  }
  __syncthreads();
  if (tid < B) gbase[tid] = atomicAdd(&bcur[tid], lhist[tid]);
  for (int j = 0; j < nmine; j++){
    lpair[lstart[myb[j]] + myrank[j]] = myp[j];
  }
  __syncthreads();
  for (int i = tid; i < cnt; i += BIN_TB){
    uint2 p = lpair[i];
    int b = (int)(p.y >> shift);
    ebuf[gbase[b] + (i - lstart[b])] = p;
  }
}

// ---------------- bucketed fill: pass 2, bucket-local cursor scatter ----------------
__global__ __launch_bounds__(512) void bfill_k(const uint2* __restrict__ ebuf, const int* __restrict__ row_off,
                                               int* __restrict__ cursor, int* __restrict__ esrc,
                                               int shift, int N){
  int b = blockIdx.x;
  int d0 = b << shift;
  int d1 = (b + 1) << shift; if (d1 > N) d1 = N;
  if (d0 >= N) return;
  int e0 = row_off[d0], e1 = row_off[d1];
  for (int i = e0 + (int)threadIdx.x; i < e1; i += 512){
    uint2 p = ebuf[i];
    int pos = atomicAdd(&cursor[p.y], 1);
    esrc[pos] = (int)p.x;
  }
}

// ---------------- fused QKV projection, LDS-staged coalesced stores ----------------
__global__ __launch_bounds__(256) void gemm_qkv_k(
    const ushort16* __restrict__ Xq, const ushort16* __restrict__ Xkv,
    const ushort16* __restrict__ Wq, const ushort16* __restrict__ Wk, const ushort16* __restrict__ Wv,
    ushort16* __restrict__ Qo, uchar* __restrict__ K8, uchar* __restrict__ V8, int N)
{
  __shared__ _Float16 Qs[4][16 * 136];
  __shared__ uchar Ks[4][16 * 136];
  __shared__ uchar Vs[4][16 * 136];
  int lane = threadIdx.x & 63, wv = threadIdx.x >> 6;
  int l15 = lane & 15, kq = lane >> 4;
  int rowbase = (blockIdx.x * 4 + wv) * 16;
  int row = rowbase + l15;
  int rc = row < N ? row : N - 1;
  const f16x8* aq = (const f16x8*)(Xq + (size_t)rc * 128 + kq * 8);
  const f16x8* ak = (const f16x8*)(Xkv + (size_t)rc * 128 + kq * 8);
  f16x8 Aq[4], Ak[4];
  #pragma unroll
  for (int s = 0; s < 4; s++){ Aq[s] = aq[s * 4]; Ak[s] = ak[s * 4]; }
  const f16x8* Wqf = (const f16x8*)Wq;
  const f16x8* Wkf = (const f16x8*)Wk;
  const f16x8* Wvf = (const f16x8*)Wv;
  f32x4 q[8], k[8], v[8];
  #pragma unroll
  for (int m = 0; m < 8; m++){ q[m] = (f32x4)(0.f); k[m] = (f32x4)(0.f); v[m] = (f32x4)(0.f); }
  #pragma unroll
  for (int s = 0; s < 4; s++){
    #pragma unroll
    for (int m = 0; m < 8; m++){
      int fi = (s * 8 + m) * 64 + lane;
      q[m] = __builtin_amdgcn_mfma_f32_16x16x32_f16(Aq[s], Wqf[fi], q[m], 0, 0, 0);
      k[m] = __builtin_amdgcn_mfma_f32_16x16x32_f16(Ak[s], Wkf[fi], k[m], 0, 0, 0);
      v[m] = __builtin_amdgcn_mfma_f32_16x16x32_f16(Ak[s], Wvf[fi], v[m], 0, 0, 0);
    }
  }
  #pragma unroll
  for (int m = 0; m < 8; m++){
    int col = m * 16 + l15;
    #pragma unroll
    for (int r = 0; r < 4; r++){
      int lrow = kq * 4 + r;
      Qs[wv][lrow * 136 + col] = (_Float16)q[m][r];
      Ks[wv][lrow * 136 + col] = f2fp8(k[m][r]);
      Vs[wv][lrow * 136 + col] = f2fp8(v[m][r]);
    }
  }
  #pragma unroll
  for (int p = 0; p < 4; p++){
    int lrow = p * 4 + (lane >> 4);
    int rr = rowbase + lrow;
    int col8 = l15 * 8;
    if (rr < N){
      uint4 qv = *(uint4*)&Qs[wv][lrow * 136 + col8];
      *(uint4*)(Qo + (size_t)rr * 128 + col8) = qv;
      uint2 kv = *(uint2*)&Ks[wv][lrow * 136 + col8];
      *(uint2*)(K8 + (size_t)rr * 128 + col8) = kv;
      uint2 vv = *(uint2*)&Vs[wv][lrow * 136 + col8];
      *(uint2*)(V8 + (size_t)rr * 128 + col8) = vv;
    }
  }
}

// ---------------- generic GEMM, swizzled W, f16 in/out, LDS-staged stores ----------------
// EPI: 1=relu, 2=sigmoid, 3=+res(f16), 4=gate w/ res(f16), 5=+BN(res), 6=gate w/ BN(res)
// ABN=1: apply BN to A on load. ST=1: accumulate column stats.
template<int KD, int MD, int EPI, int ABN, int ST, int GS>
__global__ __launch_bounds__(256) void gemm_k(
    const ushort16* __restrict__ X, const ushort16* __restrict__ W,
    const float* __restrict__ bias, const float* __restrict__ bias2,
    const ushort16* __restrict__ resb, const ushort16* __restrict__ gatep,
    const float* __restrict__ rstats, const float* __restrict__ rg, const float* __restrict__ rb,
    const float* __restrict__ astats, const float* __restrict__ ag, const float* __restrict__ ab,
    ushort16* __restrict__ outb, float* __restrict__ stats_out, int N, float invN)
{
  constexpr int KS = KD / 32;
  constexpr int MT = MD / 16;
  constexpr int LSTR = MD + 8;
  __shared__ _Float16 Os[4][16 * LSTR];
  int lane = threadIdx.x & 63, wv = threadIdx.x >> 6;
  int l15 = lane & 15, kq = lane >> 4;
  int rowbase = (blockIdx.x * 4 + wv) * 16;
  int row = rowbase + l15;
  int rc = row < N ? row : N - 1;
  const f16x8* ap = (const f16x8*)(X + (size_t)rc * KD + kq * 8);
  f16x8 a[KS];
  #pragma unroll
  for (int s = 0; s < KS; s++) a[s] = ap[s * 4];
  if constexpr (ABN){
    #pragma unroll
    for (int s = 0; s < KS; s++){
      #pragma unroll
      for (int j = 0; j < 8; j++){
        int c = s * 32 + kq * 8 + j;
        float mm = astats[c] * invN;
        float var = astats[128 + c] * invN - mm * mm;
        float rs = rsqrtf(var + EPS_BN);
        float scc = rs * ag[c];
        float shh = ab[c] - mm * scc;
        a[s][j] = (_Float16)((float)a[s][j] * scc + shh);
      }
    }
  }
  const f16x8* Wf = (const f16x8*)W;
  f32x4 acc[MT];
  #pragma unroll
  for (int m = 0; m < MT; m++) acc[m] = (f32x4)(0.f);
  #pragma unroll
  for (int s = 0; s < KS; s++){
    #pragma unroll
    for (int m = 0; m < MT; m++){
      acc[m] = __builtin_amdgcn_mfma_f32_16x16x32_f16(a[s], Wf[(s * MT + m) * 64 + lane], acc[m], 0, 0, 0);
    }
  }
  float ps[MT], ps2[MT];
  if constexpr (ST){
    #pragma unroll
    for (int m = 0; m < MT; m++){ ps[m] = 0.f; ps2[m] = 0.f; }
  }
  int r0 = rowbase + kq * 4;
  #pragma unroll
  for (int m = 0; m < MT; m++){
    int col = m * 16 + l15;
    float bv;
    if (bias2 && col >= 128) bv = bias2[col - 128];
    else bv = bias[col];
    float sc = 0.f, sh = 0.f;
    if constexpr (EPI == 5 || EPI == 6){
      float mm = rstats[col] * invN;
      float var = rstats[128 + col] * invN - mm * mm;
      float rs = rsqrtf(var + EPS_BN);
      sc = rs * rg[col]; sh = rb[col] - mm * sc;
    }
    #pragma unroll
    for (int r = 0; r < 4; r++){
      int rr = r0 + r;
      float v;
      {
        int rrc = rr < N ? rr : N - 1;
        v = acc[m][r] + bv;
        if constexpr (EPI == 1) v = fmaxf(v, 0.f);
        if constexpr (EPI == 2) v = 1.f / (1.f + __expf(-v));
        if constexpr (EPI == 3){
          union { ushort16 u; _Float16 h; } cv; cv.u = resb[(size_t)rrc * 128 + col];
          v += (float)cv.h;
        }
        if constexpr (EPI == 5){
          union { ushort16 u; _Float16 h; } cv; cv.u = resb[(size_t)rrc * 128 + col];
          v += (float)cv.h * sc + sh;
        }
        if constexpr (EPI == 4 || EPI == 6){
          union { ushort16 u; _Float16 h; } gv; gv.u = gatep[(size_t)rrc * GS + col];
          union { ushort16 u; _Float16 h; } cv; cv.u = resb[(size_t)rrc * 128 + col];
          float g = (float)gv.h;
          float rv = (float)cv.h;
          if constexpr (EPI == 6) rv = rv * sc + sh;
          v = (1.f - g) * rv + g * v;
        }
      }
      Os[wv][(kq * 4 + r) * LSTR + col] = (_Float16)v;
      if constexpr (ST){
        if (rr < N){ ps[m] += v; ps2[m] += v * v; }
      }
    }
  }
  if constexpr (MD == 128){
    #pragma unroll
    for (int p = 0; p < 4; p++){
      int lrow = p * 4 + (lane >> 4);
      int rr = rowbase + lrow;
      int col8 = l15 * 8;
      if (rr < N){
        uint4 ov = *(uint4*)&Os[wv][lrow * LSTR + col8];
        *(uint4*)(outb + (size_t)rr * MD + col8) = ov;
      }
    }
  } else {
    #pragma unroll
    for (int p = 0; p < 8; p++){
      int lrow = p * 2 + (lane >> 5);
      int rr = rowbase + lrow;
      int col8 = (lane & 31) * 8;
      if (rr < N){
        uint4 ov = *(uint4*)&Os[wv][lrow * LSTR + col8];
        *(uint4*)(outb + (size_t)rr * MD + col8) = ov;
      }
    }
  }
  if constexpr (ST){
    __shared__ float sst[4][128];
    __shared__ float sst2[4][128];
    #pragma unroll
    for (int m = 0; m < MT; m++){
      float s = ps[m], s2 = ps2[m];
      s  += __shfl_xor(s, 16);  s  += __shfl_xor(s, 32);
      s2 += __shfl_xor(s2, 16); s2 += __shfl_xor(s2, 32);
      if (lane < 16){ sst[wv][m * 16 + l15] = s; sst2[wv][m * 16 + l15] = s2; }
    }
    __syncthreads();
    int tid = threadIdx.x;
    if (tid < 128){
      atomicAdd(&stats_out[tid], sst[0][tid] + sst[1][tid] + sst[2][tid] + sst[3][tid]);
    } else {
      int c = tid - 128;
      atomicAdd(&stats_out[tid], sst2[0][c] + sst2[1][c] + sst2[2][c] + sst2[3][c]);
    }
  }
}

// ---------------- fused dual-attention (fp8 K, fp8 V) ----------------
__global__ __launch_bounds__(256) void attn2_k(
    const ushort16* __restrict__ Qa, const ushort16* __restrict__ Qb,
    const uchar* __restrict__ K8a, const uchar* __restrict__ V8a,
    const uchar* __restrict__ K8b, const uchar* __restrict__ V8b,
    const int* __restrict__ row_off, const int* __restrict__ esrc,
    ushort16* __restrict__ cat, int N)
{
  int wv = threadIdx.x >> 6, lane = threadIdx.x & 63;
  int n = blockIdx.x * 4 + wv;
  if (n >= N) return;
  int h = lane >> 5, j = lane & 31;
  uint2 qau = *(const uint2*)(Qa + (size_t)n * 128 + j * 4);
  uint2 qbu = *(const uint2*)(Qb + (size_t)n * 128 + j * 4);
  f16x2 qa01 = *(f16x2*)&qau.x, qa23 = *(f16x2*)&qau.y;
  f16x2 qb01 = *(f16x2*)&qbu.x, qb23 = *(f16x2*)&qbu.y;
  float qa0 = (float)qa01.x * 0.25f, qa1 = (float)qa01.y * 0.25f;
  float qa2 = (float)qa23.x * 0.25f, qa3 = (float)qa23.y * 0.25f;
  float qb0 = (float)qb01.x * 0.25f, qb1 = (float)qb01.y * 0.25f;
  float qb2 = (float)qb23.x * 0.25f, qb3 = (float)qb23.y * 0.25f;
  int e0 = row_off[n], e1 = row_off[n + 1];
  int deg = e1 - e0;
  int itmax = (deg + 1) >> 1;
  float a0 = 0.f, a1 = 0.f, a2 = 0.f, a3 = 0.f, za = 0.f;
  float b0 = 0.f, b1 = 0.f, b2 = 0.f, b3 = 0.f, zb = 0.f;
  int e = e0 + h;
  int s = (e < e1) ? esrc[e] : -1;
  int sc = s < 0 ? 0 : s;
  uint32 kwa = *(const uint32*)(K8a + (size_t)sc * 128 + j * 4);
  uint32 kwb = *(const uint32*)(K8b + (size_t)sc * 128 + j * 4);
  uint32 vwa = *(const uint32*)(V8a + (size_t)sc * 128 + j * 4);
  uint32 vwb = *(const uint32*)(V8b + (size_t)sc * 128 + j * 4);
  for (int it = 0; it < itmax; ++it){
    int e2 = e + 2;
    int s2 = (e2 < e1) ? esrc[e2] : -1;
    int s2c = s2 < 0 ? 0 : s2;
    uint32 kwa2 = *(const uint32*)(K8a + (size_t)s2c * 128 + j * 4);
    uint32 kwb2 = *(const uint32*)(K8b + (size_t)s2c * 128 + j * 4);
    uint32 vwa2 = *(const uint32*)(V8a + (size_t)s2c * 128 + j * 4);
    uint32 vwb2 = *(const uint32*)(V8b + (size_t)s2c * 128 + j * 4);
    if (s >= 0){
      f32x2 ka01 = fp8pair_lo(kwa), ka23 = fp8pair_hi(kwa);
      f32x2 kb01 = fp8pair_lo(kwb), kb23 = fp8pair_hi(kwb);
      float da = fmaf(ka01.x, qa0, fmaf(ka01.y, qa1, fmaf(ka23.x, qa2, ka23.y * qa3)));
      float db = fmaf(kb01.x, qb0, fmaf(kb01.y, qb1, fmaf(kb23.x, qb2, kb23.y * qb3)));
      da += __shfl_xor(da, 1); da += __shfl_xor(da, 2);
      db += __shfl_xor(db, 1); db += __shfl_xor(db, 2);
      float sa = __expf(fminf(fmaxf(da, -5.f), 5.f));
      float sb = __expf(fminf(fmaxf(db, -5.f), 5.f));
      f32x2 va01 = fp8pair_lo(vwa), va23 = fp8pair_hi(vwa);
      f32x2 vb01 = fp8pair_lo(vwb), vb23 = fp8pair_hi(vwb);
      a0 = fmaf(sa, va01.x, a0); a1 = fmaf(sa, va01.y, a1);
      a2 = fmaf(sa, va23.x, a2); a3 = fmaf(sa, va23.y, a3);
      za += sa;
      b0 = fmaf(sb, vb01.x, b0); b1 = fmaf(sb, vb01.y, b1);
      b2 = fmaf(sb, vb23.x, b2); b3 = fmaf(sb, vb23.y, b3);
      zb += sb;
    }
    e = e2; s = s2;
    kwa = kwa2; kwb = kwb2; vwa = vwa2; vwb = vwb2;
  }
  a0 += __shfl_xor(a0, 32); a1 += __shfl_xor(a1, 32);
  a2 += __shfl_xor(a2, 32); a3 += __shfl_xor(a3, 32);
  za += __shfl_xor(za, 32);
  b0 += __shfl_xor(b0, 32); b1 += __shfl_xor(b1, 32);
  b2 += __shfl_xor(b2, 32); b3 += __shfl_xor(b3, 32);
  zb += __shfl_xor(zb, 32);
  uint2 o;
  if (h == 0){
    float rz = __builtin_amdgcn_rcpf(za);
    o.x = pk16(a0 * rz, a1 * rz);
    o.y = pk16(a2 * rz, a3 * rz);
    *(uint2*)(cat + (size_t)n * 256 + j * 4) = o;
  } else {
    float rz = __builtin_amdgcn_rcpf(zb);
    o.x = pk16(b0 * rz, b1 * rz);
    o.y = pk16(b2 * rz, b3 * rz);
    *(uint2*)(cat + (size_t)n * 256 + 128 + j * 4) = o;
  }
}

// ---------------- BatchNorm apply (f16 in, f32 out) ----------------
__global__ __launch_bounds__(256) void bn_apply_k(
    const ushort16* __restrict__ x, const float* __restrict__ stats,
    const float* __restrict__ gamma, const float* __restrict__ beta,
    float* __restrict__ outf, int total4, float invN)
{
  int i = blockIdx.x * 256 + threadIdx.x;
  if (i >= total4) return;
  uint2 xp = *(const uint2*)(x + (size_t)i * 4);
  f16x2 x01 = *(f16x2*)&xp.x, x23 = *(f16x2*)&xp.y;
  float xv[4] = {(float)x01.x, (float)x01.y, (float)x23.x, (float)x23.y};
  int c0 = (i * 4) & 127;
  float o[4];
  #pragma unroll
  for (int j = 0; j < 4; j++){
    int c = c0 + j;
    float m = stats[c] * invN;
    float var = stats[128 + c] * invN - m * m;
    float rstd = rsqrtf(var + EPS_BN);
    o[j] = (xv[j] - m) * rstd * gamma[c] + beta[c];
  }
  *(float4*)(outf + (size_t)i * 4) = make_float4(o[0], o[1], o[2], o[3]);
}

// ---------------- host ----------------
extern "C" void kernel_launch(void* const* d_in, const int* in_sizes, int n_in,
                              void* d_out, int out_size, void* d_ws, size_t ws_size,
                              hipStream_t stream) {
  const float* h   = (const float*)d_in[0];
  const float* sv  = (const float*)d_in[1];
  const int* src   = (const int*)d_in[2];
  const int* dst   = (const int*)d_in[3];
  const int N = in_sizes[0] / 128;
  const int E = in_sizes[2];

  char* wsb = (char*)d_ws;
  size_t o = 0;
  auto take = [&](size_t bytes)->size_t{
    size_t r = o;
    o = (o + bytes + 255) & ~(size_t)255;
    return r;
  };
  size_t cnt_off    = take((size_t)N * 4);
  size_t stats_off  = take(4 * 256 * 4);
  size_t rowoff_off = take((size_t)(N + 1) * 4);
  size_t cursor_off = take((size_t)N * 4);
  size_t bsum_off   = take(256 * 4);
  size_t bcur_off   = take(128 * 4);
  size_t esrc_off   = take((size_t)E * 4);
  size_t ebuf_off   = take((size_t)E * 8);
  size_t wpool_off  = take((size_t)376832 * 2);
  size_t hf_off     = take((size_t)N * 128 * 2);
  size_t svf_off    = take((size_t)N * 128 * 2);
  size_t cath_off   = take((size_t)N * 256 * 2);
  size_t catsv_off  = take((size_t)N * 256 * 2);
  size_t K81_off    = take((size_t)N * 128);
  size_t V81_off    = take((size_t)N * 128);
  size_t K82_off    = take((size_t)N * 128);
  size_t V82_off    = take((size_t)N * 128);
  size_t Q1_off     = take((size_t)N * 128 * 2);
  size_t Q2_off     = take((size_t)N * 128 * 2);
  size_t X1_off     = take((size_t)N * 128 * 2);
  size_t X2_off     = take((size_t)N * 128 * 2);
  size_t G_off      = take((size_t)N * 256 * 2);

  int*    cnt     = (int*)(wsb + cnt_off);
  float*  stats   = (float*)(wsb + stats_off);
  int*    row_off = (int*)(wsb + rowoff_off);
  int*    cursor  = (int*)(wsb + cursor_off);
  int*    bsum    = (int*)(wsb + bsum_off);
  int*    bcur    = (int*)(wsb + bcur_off);
  int*    esrc    = (int*)(wsb + esrc_off);
  uint2*  ebuf    = (uint2*)(wsb + ebuf_off);
  ushort16* wpool = (ushort16*)(wsb + wpool_off);
  ushort16* h_f   = (ushort16*)(wsb + hf_off);
  ushort16* sv_f  = (ushort16*)(wsb + svf_off);
  ushort16* cat_h = (ushort16*)(wsb + cath_off);
  ushort16* cat_sv= (ushort16*)(wsb + catsv_off);
  uchar*    K8_1  = (uchar*)(wsb + K81_off);
  uchar*    V8_1  = (uchar*)(wsb + V81_off);
  uchar*    K8_2  = (uchar*)(wsb + K82_off);
  uchar*    V8_2  = (uchar*)(wsb + V82_off);
  ushort16* Q1    = (ushort16*)(wsb + Q1_off);
  ushort16* Q2    = (ushort16*)(wsb + Q2_off);
  ushort16* Xb1   = (ushort16*)(wsb + X1_off);
  ushort16* Xb2   = (ushort16*)(wsb + X2_off);
  ushort16* Gb16  = (ushort16*)(wsb + G_off);

  ushort16* Wq_sv = wpool + 0 * 16384;
  ushort16* Wk_sv = wpool + 1 * 16384;
  ushort16* Wv_sv = wpool + 2 * 16384;
  ushort16* Wq_cv = wpool + 3 * 16384;
  ushort16* Wk_cv = wpool + 4 * 16384;
  ushort16* Wv_cv = wpool + 5 * 16384;
  ushort16* Wq_sh = wpool + 6 * 16384;
  ushort16* Wk_sh = wpool + 7 * 16384;
  ushort16* Wv_sh = wpool + 8 * 16384;
  ushort16* Wgb   = wpool + 147456;
  ushort16* Wob   = wpool + 180224;
  ushort16* Wohb  = wpool + 212992;
  ushort16* W1b   = wpool + 245760;
  ushort16* W2b   = wpool + 278528;
  ushort16* W1hb  = wpool + 311296;
  ushort16* W2hb  = wpool + 344064;

  const float* bo   = (const float*)d_in[14];
  const float* bo_h = (const float*)d_in[16];
  const float* b1   = (const float*)d_in[18];
  const float* b2   = (const float*)d_in[20];
  const float* b1h  = (const float*)d_in[22];
  const float* b2h  = (const float*)d_in[24];
  const float* bg1  = (const float*)d_in[26];
  const float* bg2  = (const float*)d_in[28];
  const float* gbn1  = (const float*)d_in[29];
  const float* bbn1  = (const float*)d_in[30];
  const float* gbn2  = (const float*)d_in[31];
  const float* bbn2  = (const float*)d_in[32];
  const float* gbn1h = (const float*)d_in[33];
  const float* bbn1h = (const float*)d_in[34];
  const float* gbn2h = (const float*)d_in[35];
  const float* bbn2h = (const float*)d_in[36];

  float* out_h  = (float*)d_out;
  float* out_sv = out_h + (size_t)N * 128;

  (void)hipMemsetAsync(wsb, 0, stats_off + 4 * 256 * 4, stream);

  WConv wc;
  {
    auto set = [&](int i, int din, int din2, size_t dstoff, int KD, int MD){
      wc.e[i].s  = (const float*)d_in[din];
      wc.e[i].s2 = (din2 >= 0) ? (const float*)d_in[din2] : nullptr;
      wc.e[i].d  = wpool + dstoff;
      wc.e[i].KD = KD; wc.e[i].MD = MD;
      wc.e[i].nfrag = KD * MD / 8;
    };
    for (int i = 0; i < 9; i++) set(i, 4 + i, -1, (size_t)i * 16384, 128, 128);
    set(9,  25, 27, 147456, 128, 256);
    set(10, 13, -1, 180224, 256, 128);
    set(11, 15, -1, 212992, 256, 128);
    set(12, 17, -1, 245760, 128, 256);
    set(13, 19, -1, 278528, 256, 128);
    set(14, 21, -1, 311296, 128, 256);
    set(15, 23, -1, 344064, 256, 128);
  }
  conv_w_k<<<dim3(16, 16), 256, 0, stream>>>(wc);

  int nelem = N * 128;
  conv2_k<<<dim3((nelem / 4 + 255) / 256, 2), 256, 0, stream>>>(h, sv, h_f, sv_f, nelem);

  // bucket params: B <= 128 buckets of 2^shift dst values
  int shift = 9;
  while ((((N - 1) >> shift) + 1) > 128) shift++;
  const int B = ((N - 1) >> shift) + 1;

  const int NB = (N + 1023) / 1024;
  hist_k<<<2048, 256, 0, stream>>>(dst, cnt, E);
  scan_part_k<<<NB, 256, 0, stream>>>(cnt, bsum, N);
  scan_top_k<<<1, 64, 0, stream>>>(bsum, NB);
  scan_out_k<<<NB, 256, 0, stream>>>(cnt, bsum, row_off, cursor, bcur, N, E, shift);
  bin_k<<<(E + BIN_TILE - 1) / BIN_TILE, BIN_TB, 0, stream>>>(src, dst, bcur, ebuf, E, shift, B);
  bfill_k<<<B, 512, 0, stream>>>(ebuf, row_off, cursor, esrc, shift, N);

  const int GB = (N + 63) / 64;
  const int AB = (N + 3) / 4;
  const int T4 = nelem / 4;
  const int APB = (T4 + 255) / 256;
  const float invN = 1.f / (float)N;

  // h-branch attention pair
  gemm_qkv_k<<<GB, 256, 0, stream>>>(h_f, h_f, Wq_sv, Wk_sv, Wv_sv, Q1, K8_1, V8_1, N);
  gemm_qkv_k<<<GB, 256, 0, stream>>>(h_f, sv_f, Wq_cv, Wk_cv, Wv_cv, Q2, K8_2, V8_2, N);
  attn2_k<<<AB, 256, 0, stream>>>(Q1, Q2, K8_1, V8_1, K8_2, V8_2, row_off, esrc, cat_h, N);
  // sv-branch attention pair
  gemm_qkv_k<<<GB, 256, 0, stream>>>(sv_f, sv_f, Wq_sh, Wk_sh, Wv_sh, Q1, K8_1, V8_1, N);
  gemm_qkv_k<<<GB, 256, 0, stream>>>(sv_f, h_f, Wq_cv, Wk_cv, Wv_cv, Q2, K8_2, V8_2, N);
  attn2_k<<<AB, 256, 0, stream>>>(Q1, Q2, K8_1, V8_1, K8_2, V8_2, row_off, esrc, cat_sv, N);

  // ---- h branch ----
  gemm_k<256,128,3,0,1,256><<<GB, 256, 0, stream>>>(cat_h, Wob, bo, nullptr, h_f, nullptr,
      nullptr, nullptr, nullptr, nullptr, nullptr, nullptr, Xb1, stats, N, invN);
  gemm_k<128,256,1,1,0,256><<<GB, 256, 0, stream>>>(Xb1, W1b, b1, nullptr, nullptr, nullptr,
      nullptr, nullptr, nullptr, stats, gbn1, bbn1, cat_h, nullptr, N, invN);
  gemm_k<256,128,5,0,1,256><<<GB, 256, 0, stream>>>(cat_h, W2b, b2, nullptr, Xb1, nullptr,
      stats, gbn1, bbn1, nullptr, nullptr, nullptr, Xb2, stats + 256, N, invN);
  bn_apply_k<<<APB, 256, 0, stream>>>(Xb2, stats + 256, gbn2, bbn2, out_h, T4, invN);

  // ---- sv branch ----
  gemm_k<128,256,2,0,0,256><<<GB, 256, 0, stream>>>(h_f, Wgb, bg1, bg2, nullptr, nullptr,
      nullptr, nullptr, nullptr, nullptr, nullptr, nullptr, Gb16, nullptr, N, invN);
  gemm_k<256,128,4,0,1,256><<<GB, 256, 0, stream>>>(cat_sv, Wohb, bo_h, nullptr, sv_f, Gb16,
      nullptr, nullptr, nullptr, nullptr, nullptr, nullptr, Xb1, stats + 512, N, invN);
  gemm_k<128,256,1,1,0,256><<<GB, 256, 0, stream>>>(Xb1, W1hb, b1h, nullptr, nullptr, nullptr,
      nullptr, nullptr, nullptr, stats + 512, gbn1h, bbn1h, cat_sv, nullptr, N, invN);
  gemm_k<256,128,6,0,1,256><<<GB, 256, 0, stream>>>(cat_sv, W2hb, b2h, nullptr, Xb1, Gb16 + 128,
      stats + 512, gbn1h, bbn1h, nullptr, nullptr, nullptr, Xb2, stats + 768, N, invN);
  bn_apply_k<<<APB, 256, 0, stream>>>(Xb2, stats + 768, gbn2h, bbn2h, out_sv, T4, invN);
}